// Round 4
// baseline (1058.029 us; speedup 1.0000x reference)
//
#include <hip/hip_runtime.h>
#include <stdint.h>

#define N3i 25600
#define N4i 6400
#define N5i 1600
#define NNi 33600
#define ECi 260000
#define EHi 120000

typedef unsigned short u16;
typedef __bf16 bf16x8 __attribute__((ext_vector_type(8)));
typedef float f32x4 __attribute__((ext_vector_type(4)));
typedef unsigned short u16x8 __attribute__((ext_vector_type(8)));

__device__ __forceinline__ float b2f(u16 u) {
    union { float f; uint32_t i; } v; v.i = ((uint32_t)u) << 16; return v.f;
}
__device__ __forceinline__ u16 f2b(float f) {
    union { float f; uint32_t i; } v; v.f = f;
    uint32_t x = v.i;
    uint32_t r = (x + 0x7FFFu + ((x >> 16) & 1u)) >> 16;  // RNE
    return (u16)r;
}

// async global->LDS, 16B per lane. LDS dest must be wave-uniform base (+lane*16 by HW);
// global source is per-lane (rule #21: swizzle via source address, keep LDS linear).
__device__ __forceinline__ void gll16(const u16* g, u16* l) {
    __builtin_amdgcn_global_load_lds((const __attribute__((address_space(1))) void*)g,
                                     (__attribute__((address_space(3))) void*)l, 16, 0, 0);
}

// ---------------- dtype detection: flag=1 if inputs are bf16, 0 if fp32 ----------------
// also zeroes the 256B zero-pad region used by masked GEMM staging
__global__ void detect_kernel(const void* __restrict__ c3raw, int* __restrict__ flag,
                              uint32_t* __restrict__ zp) {
    const uint32_t* p = (const uint32_t*)c3raw;
    int t = threadIdx.x;
    zp[t] = 0;  // 64 * 4B = 256B zero pad
    int vote = 0;
    for (int i = t; i < 256; i += 64) {
        uint32_t w = p[i];
        uint32_t lo = w & 0xFFFFu;
        uint32_t e = (lo >> 7) & 0xFFu;
        if (lo == 0u || (e >= 100u && e <= 127u)) vote++;
    }
#pragma unroll
    for (int d = 32; d >= 1; d >>= 1) vote += __shfl_down(vote, d, 64);
    if (t == 0) flag[0] = (vote >= 192) ? 1 : 0;
}

// ---------------- utility kernels ----------------
__global__ void zero_i32(int* p, int n) {
    int i = blockIdx.x * 256 + threadIdx.x;
    if (i < n) p[i] = 0;
}

__global__ void hist2_kernel(const int* __restrict__ dst_c, const int* __restrict__ dst_h,
                             int* __restrict__ cnt_c, int* __restrict__ cnt_h) {
    int i = blockIdx.x * 256 + threadIdx.x;
    if (i < ECi) {
        int d = dst_c[i];
        if ((unsigned)d < (unsigned)NNi) atomicAdd(&cnt_c[d], 1);
    } else {
        int j = i - ECi;
        if (j < EHi) {
            int d = dst_h[j];
            if ((unsigned)d < (unsigned)NNi) atomicAdd(&cnt_h[d], 1);
        }
    }
}

// wave-shuffle scan; blockIdx.x==0 -> contextual, ==1 -> hierarchical (concurrent)
__global__ __launch_bounds__(1024) void scan2_kernel(
    const int* __restrict__ cnt_c, int* __restrict__ rs_c, int* __restrict__ cur_c,
    float* __restrict__ inv_c,
    const int* __restrict__ cnt_h, int* __restrict__ rs_h, int* __restrict__ cur_h,
    float* __restrict__ inv_h, int n) {
    const int* cnt = blockIdx.x ? cnt_h : cnt_c;
    int* rs = blockIdx.x ? rs_h : rs_c;
    int* cur = blockIdx.x ? cur_h : cur_c;
    float* inv = blockIdx.x ? inv_h : inv_c;
    __shared__ int ws[16];
    __shared__ int base;
    int t = threadIdx.x, wid = t >> 6, lane = t & 63;
    if (t == 0) { base = 0; rs[0] = 0; }
    __syncthreads();
    for (int i0 = 0; i0 < n; i0 += 1024) {
        int i = i0 + t;
        int v = (i < n) ? cnt[i] : 0;
        int x = v;
#pragma unroll
        for (int d = 1; d < 64; d <<= 1) {
            int y = __shfl_up(x, d, 64);
            if (lane >= d) x += y;
        }
        if (lane == 63) ws[wid] = x;
        __syncthreads();
        if (wid == 0) {
            int s = (lane < 16) ? ws[lane] : 0;
#pragma unroll
            for (int d = 1; d < 16; d <<= 1) {
                int y = __shfl_up(s, d, 64);
                if (lane >= d) s += y;
            }
            if (lane < 16) ws[lane] = s;
        }
        __syncthreads();
        int b = base;
        int incl = x + (wid ? ws[wid - 1] : 0);
        if (i < n) {
            rs[i + 1] = b + incl;
            cur[i] = b + incl - v;
            int dv = v < 1 ? 1 : v;
            inv[i] = 1.0f / (float)dv;
        }
        int tot = ws[15];
        __syncthreads();
        if (t == 1023) base = b + tot;
        __syncthreads();
    }
}

__global__ void fill2_kernel(const int* __restrict__ src_c, const int* __restrict__ dst_c,
                             int* __restrict__ cur_c, int* __restrict__ csr_c,
                             const int* __restrict__ src_h, const int* __restrict__ dst_h,
                             int* __restrict__ cur_h, int* __restrict__ csr_h) {
    int i = blockIdx.x * 256 + threadIdx.x;
    if (i < ECi) {
        int d = dst_c[i];
        if ((unsigned)d < (unsigned)NNi) {
            int p = atomicAdd(&cur_c[d], 1);
            if ((unsigned)p < (unsigned)ECi) csr_c[p] = src_c[i];
        }
    } else {
        int j = i - ECi;
        if (j < EHi) {
            int d = dst_h[j];
            if ((unsigned)d < (unsigned)NNi) {
                int p = atomicAdd(&cur_h[d], 1);
                if ((unsigned)p < (unsigned)EHi) csr_h[p] = src_h[j];
            }
        }
    }
}

// all 11 small conversions in one launch (grid.y = job id)
struct CvtJobs { const void* src[11]; u16* dst[11]; int n[11]; };

__global__ void cvt_all_kernel(CvtJobs j, const int* __restrict__ flag) {
    int job = blockIdx.y;
    int i = blockIdx.x * 256 + threadIdx.x;
    if (i >= j.n[job]) return;
    const void* s = j.src[job];
    j.dst[job][i] = flag[0] ? ((const u16*)s)[i] : f2b(((const float*)s)[i]);
}

// ---------------- transposes ----------------
__device__ __forceinline__ void tin_body(const void* in, size_t ioff, u16* outp, int R, int C,
                                         int isb, int c0, int r0, u16 (*tile)[33]) {
    const u16* inb = (const u16*)in + ioff;
    const float* inf_ = (const float*)in + ioff;
    int tx = threadIdx.x, ty = threadIdx.y;  // block (32,8)
#pragma unroll
    for (int i = 0; i < 4; i++) {
        int r = r0 + ty + i * 8, c = c0 + tx;
        if (r < R && c < C) {
            size_t idx = (size_t)r * C + c;
            tile[ty + i * 8][tx] = isb ? inb[idx] : f2b(inf_[idx]);
        }
    }
    __syncthreads();
#pragma unroll
    for (int i = 0; i < 4; i++) {
        int c = c0 + ty + i * 8, r = r0 + tx;
        if (c < C && r < R) outp[(size_t)c * R + r] = tile[tx][ty + i * 8];
    }
}

__global__ void transpose_in3(const void* __restrict__ c3, const void* __restrict__ c4,
                              const void* __restrict__ c5, u16* __restrict__ Xt3,
                              u16* __restrict__ Xt4, u16* __restrict__ Xt5,
                              const int* __restrict__ flag) {
    __shared__ u16 tile[32][33];
    int bx = blockIdx.x;
    const void* in; u16* outb; int R, C, xb;
    if (bx < 200)      { in = c3; outb = Xt3; R = 256; C = 6400; xb = bx; }
    else if (bx < 250) { in = c4; outb = Xt4; R = 512; C = 1600; xb = bx - 200; }
    else               { in = c5; outb = Xt5; R = 512; C = 400;  xb = bx - 250; }
    int r0 = blockIdx.y * 32;
    if (r0 >= R) return;
    size_t boff = (size_t)blockIdx.z * R * C;
    tin_body(in, boff, outb + boff, R, C, flag[0], xb * 32, r0, tile);
}

__global__ void transpose_w(const void* __restrict__ Wc, const void* __restrict__ Wh,
                            u16* __restrict__ WtG, const int* __restrict__ flag) {
    __shared__ u16 tile[32][33];
    int z = blockIdx.z;
    const void* in = (z < 6) ? Wc : Wh;
    int zi = (z < 6) ? z : z - 6;
    tin_body(in, (size_t)zi * 65536, WtG + (size_t)z * 65536, 256, 256, flag[0],
             blockIdx.x * 32, blockIdx.y * 32, tile);
}

__global__ void transpose_out3(const u16* __restrict__ OutT, void* __restrict__ outv,
                               const int* __restrict__ flag) {
    __shared__ u16 tile[32][33];
    int by = blockIdx.y;
    const u16* inb; size_t out_off; int R, yb;
    if (by < 200)      { inb = OutT; out_off = 0; R = 6400; yb = by; }
    else if (by < 250) { inb = OutT + (size_t)N3i * 256; out_off = (size_t)4 * 256 * 6400; R = 1600; yb = by - 200; }
    else               { inb = OutT + (size_t)(N3i + N4i) * 256; out_off = (size_t)4 * 256 * 8000; R = 400; yb = by - 250; }
    int r0 = yb * 32;
    if (r0 >= R) return;
    const int C = 256;
    int isb = flag[0];
    int c0 = blockIdx.x * 32;
    size_t boff = (size_t)blockIdx.z * R * C;
    const u16* inp = inb + boff;
    int tx = threadIdx.x, ty = threadIdx.y;
#pragma unroll
    for (int i = 0; i < 4; i++) {
        int r = r0 + ty + i * 8, c = c0 + tx;
        if (r < R && c < C) tile[ty + i * 8][tx] = inp[(size_t)r * C + c];
    }
    __syncthreads();
#pragma unroll
    for (int i = 0; i < 4; i++) {
        int c = c0 + ty + i * 8, r = r0 + tx;
        if (c < C && r < R) {
            size_t o = out_off + boff + (size_t)c * R + r;
            u16 v = tile[tx][ty + i * 8];
            if (isb) ((u16*)outv)[o] = v;
            else ((float*)outv)[o] = b2f(v);
        }
    }
}

// conv weight transform for all 3 levels: wt[n][tap*256+ci] = w[n][ci*9+tap]
__global__ void convw3_kernel(const void* __restrict__ w0, const void* __restrict__ w1,
                              const void* __restrict__ w2, u16* __restrict__ WtC,
                              const int* __restrict__ flag) {
    int lvl = blockIdx.y;
    const void* w = (lvl == 0) ? w0 : (lvl == 1) ? w1 : w2;
    u16* wt = WtC + (size_t)lvl * 256 * 2304;
    int i = blockIdx.x * 256 + threadIdx.x;
    if (i >= 256 * 2304) return;
    int n = i / 2304;
    int k = i - n * 2304;
    int tap = k >> 8, ci = k & 255;
    int si = n * 2304 + ci * 9 + tap;
    wt[i] = flag[0] ? ((const u16*)w)[si] : f2b(((const float*)w)[si]);
}

// ---------------- fused GNN layer: gather -> LDS -> GEMM(256 wide) + relu ----------------
// Block = 64 output rows x 256 cols. Phase 1: gather 64 nodes' aggregated features
// into LDS Tl (slab-major [8 slabs][64 rows][32 elems], chunk-XOR swizzled like the
// GEMM A-tile -> conflict-free ds_read_b128 in phase 2). Phase 2: round-2-proven
// 2-buffer k-loop staging ONLY B via global_load_lds; A comes from Tl.
// Removes per layer: T global write + 2x T read + 1 launch + 1 full drain.
#define TSLAB 2064  // u16 per slab: 64*32 + 16 pad -> slab bank-offset 8 (write conflicts 8->2-way)
__global__ __launch_bounds__(256) void gnn_fused_kernel(
    const u16* __restrict__ H, const int* __restrict__ csr, const int* __restrict__ rs,
    const float* __restrict__ invdeg, const u16* __restrict__ Bt,
    const u16* __restrict__ bias, u16* __restrict__ out, int ecap) {
    __shared__ __align__(16) u16 Tl[8 * TSLAB];
    __shared__ __align__(16) u16 LB[2][8192];
    int t = threadIdx.x;
    int w = t >> 6, lane = t & 63;
    int m0 = blockIdx.x * 64;

    // ---- B staging: wave w covers B rows w*64..w*64+63 (4 issues of 16 rows) ----
    int l2 = lane >> 2;          // row-within-16
    int q = lane & 3;            // chunk within 32-k slab
    int srb = (l2 >> 1) & 3;     // (row>>1)&3 (w*64, j*16 are 0 mod 8)
    auto stageB = [&](int bf, int ks) {
        int k0 = ks << 5;
#pragma unroll
        for (int j = 0; j < 4; j++) {
            int row = w * 64 + j * 16 + l2;
            const u16* src = Bt + (size_t)row * 256 + k0 + ((q ^ srb) << 3);
            gll16(src, &LB[bf][(w * 64 + j * 16) * 32]);
        }
    };
    stageB(0, 0);  // pre-issue; latency hides under the whole gather phase

    // ---- gather phase: wave w handles nodes m0 + w*16 .. +15 ----
    int half = lane >> 5;
    int ch = (lane & 31) * 8;  // channel base
    for (int ni = 0; ni < 16; ni++) {
        int node = m0 + w * 16 + ni;
        int e0 = rs[node], e1 = rs[node + 1];
        e0 = e0 < 0 ? 0 : e0;
        e1 = e1 > ecap ? ecap : e1;
        u16x8 self = *(const u16x8*)(H + (size_t)node * 256 + ch);
        float a0 = 0.f, a1 = 0.f, a2 = 0.f, a3 = 0.f, a4 = 0.f, a5 = 0.f, a6 = 0.f, a7 = 0.f;
        float c0 = 0.f, c1 = 0.f, c2 = 0.f, c3 = 0.f, c4 = 0.f, c5 = 0.f, c6 = 0.f, c7 = 0.f;
        int e = e0 + half;
        while (e + 6 < e1) {  // 4 row-loads in flight per half (8 per wave)
            int i0 = csr[e], i1 = csr[e + 2], i2 = csr[e + 4], i3 = csr[e + 6];
            i0 = ((unsigned)i0 < (unsigned)NNi) ? i0 : 0;
            i1 = ((unsigned)i1 < (unsigned)NNi) ? i1 : 0;
            i2 = ((unsigned)i2 < (unsigned)NNi) ? i2 : 0;
            i3 = ((unsigned)i3 < (unsigned)NNi) ? i3 : 0;
            u16x8 h0 = *(const u16x8*)(H + (size_t)i0 * 256 + ch);
            u16x8 h1 = *(const u16x8*)(H + (size_t)i1 * 256 + ch);
            u16x8 h2 = *(const u16x8*)(H + (size_t)i2 * 256 + ch);
            u16x8 h3 = *(const u16x8*)(H + (size_t)i3 * 256 + ch);
            a0 += b2f(h0[0]); a1 += b2f(h0[1]); a2 += b2f(h0[2]); a3 += b2f(h0[3]);
            a4 += b2f(h0[4]); a5 += b2f(h0[5]); a6 += b2f(h0[6]); a7 += b2f(h0[7]);
            c0 += b2f(h1[0]); c1 += b2f(h1[1]); c2 += b2f(h1[2]); c3 += b2f(h1[3]);
            c4 += b2f(h1[4]); c5 += b2f(h1[5]); c6 += b2f(h1[6]); c7 += b2f(h1[7]);
            a0 += b2f(h2[0]); a1 += b2f(h2[1]); a2 += b2f(h2[2]); a3 += b2f(h2[3]);
            a4 += b2f(h2[4]); a5 += b2f(h2[5]); a6 += b2f(h2[6]); a7 += b2f(h2[7]);
            c0 += b2f(h3[0]); c1 += b2f(h3[1]); c2 += b2f(h3[2]); c3 += b2f(h3[3]);
            c4 += b2f(h3[4]); c5 += b2f(h3[5]); c6 += b2f(h3[6]); c7 += b2f(h3[7]);
            e += 8;
        }
        while (e < e1) {
            int i0 = csr[e];
            i0 = ((unsigned)i0 < (unsigned)NNi) ? i0 : 0;
            u16x8 h0 = *(const u16x8*)(H + (size_t)i0 * 256 + ch);
            a0 += b2f(h0[0]); a1 += b2f(h0[1]); a2 += b2f(h0[2]); a3 += b2f(h0[3]);
            a4 += b2f(h0[4]); a5 += b2f(h0[5]); a6 += b2f(h0[6]); a7 += b2f(h0[7]);
            e += 2;
        }
        a0 += c0; a1 += c1; a2 += c2; a3 += c3; a4 += c4; a5 += c5; a6 += c6; a7 += c7;
        a0 += __shfl_xor(a0, 32, 64); a1 += __shfl_xor(a1, 32, 64);
        a2 += __shfl_xor(a2, 32, 64); a3 += __shfl_xor(a3, 32, 64);
        a4 += __shfl_xor(a4, 32, 64); a5 += __shfl_xor(a5, 32, 64);
        a6 += __shfl_xor(a6, 32, 64); a7 += __shfl_xor(a7, 32, 64);
        if (half == 0) {
            float inv = invdeg[node];
            u16x8 o;
            o[0] = f2b(b2f(self[0]) + a0 * inv); o[1] = f2b(b2f(self[1]) + a1 * inv);
            o[2] = f2b(b2f(self[2]) + a2 * inv); o[3] = f2b(b2f(self[3]) + a3 * inv);
            o[4] = f2b(b2f(self[4]) + a4 * inv); o[5] = f2b(b2f(self[5]) + a5 * inv);
            o[6] = f2b(b2f(self[6]) + a6 * inv); o[7] = f2b(b2f(self[7]) + a7 * inv);
            int r = w * 16 + ni;
            int slab = (lane & 31) >> 2;
            int qq = lane & 3;
            int sr = (r >> 1) & 3;
            *(u16x8*)(&Tl[slab * TSLAB + r * 32 + ((qq ^ sr) << 3)]) = o;
        }
    }
    __syncthreads();  // T complete; drains pre-issued B stage (implicit vmcnt(0))

    // ---- GEMM phase: out[64 x 256] = Tl @ Bt^T + bias, relu ----
    f32x4 acc[4][4] = {};
    int fm = lane & 15;
    int kq = lane >> 4;
    int co = ((kq ^ ((fm >> 1) & 3)) << 3);
    for (int s = 0; s < 8; s++) {
        int bf = s & 1;
        if (s + 1 < 8) stageB(bf ^ 1, s + 1);
        bf16x8 af[4], bfv[4];
#pragma unroll
        for (int i = 0; i < 4; i++)
            af[i] = *(const bf16x8*)&Tl[s * TSLAB + (i * 16 + fm) * 32 + co];
#pragma unroll
        for (int j = 0; j < 4; j++)
            bfv[j] = *(const bf16x8*)&LB[bf][(w * 64 + j * 16 + fm) * 32 + co];
#pragma unroll
        for (int i = 0; i < 4; i++)
#pragma unroll
            for (int j = 0; j < 4; j++)
                acc[i][j] = __builtin_amdgcn_mfma_f32_16x16x32_bf16(af[i], bfv[j], acc[i][j], 0, 0, 0);
        __syncthreads();
    }

    int qd = lane >> 4, nl = lane & 15;
#pragma unroll
    for (int j = 0; j < 4; j++) {
        int n = w * 64 + j * 16 + nl;
        float bv = b2f(bias[n]);
#pragma unroll
        for (int i = 0; i < 4; i++) {
            int mbase = i * 16 + qd * 4;
#pragma unroll
            for (int rg = 0; rg < 4; rg++) {
                int m = mbase + rg;
                float v = acc[i][j][rg] + bv;
                v = fmaxf(v, 0.f);
                out[(size_t)(m0 + m) * 256 + n] = f2b(v);
            }
        }
    }
}

// ---------------- MFMA GEMM body (round-2 proven): gll + 2-buffer, 1 drain/K-step ----
template <bool CONV, bool RELU>
__device__ __forceinline__ void gemm_body(
    u16 (* __restrict__ lds)[4096],
    const u16* __restrict__ A, int lda,
    const u16* __restrict__ Bt, int ldb,
    const u16* __restrict__ bias,
    const u16* __restrict__ zp,
    u16* __restrict__ out, u16* __restrict__ out2,
    int M, int K, int H, int W, int m0, int n0) {
    int t = threadIdx.x;
    int w = t >> 6, lane = t & 63;
    int wm = w & 1, wn = w >> 1;
    f32x4 acc[4][4] = {};

    int g0 = w * 128 + lane;
    int g1 = g0 + 64;
    int row0 = g0 >> 2, c0 = g0 & 3;
    int row1 = g1 >> 2, c1 = g1 & 3;
    int ss0 = ((c0 ^ ((row0 >> 1) & 3)) << 3);
    int ss1 = ((c1 ^ ((row1 >> 1) & 3)) << 3);

    int ar0 = m0 + row0, ar1 = m0 + row1;
    bool aok0 = ar0 < M, aok1 = ar1 < M;
    int y0_ = 0, x0_ = 0, y1_ = 0, x1_ = 0;
    if (CONV) {
        int HW = H * W;
        if (aok0) { int b = ar0 / HW; int rem = ar0 - b * HW; y0_ = rem / W; x0_ = rem - y0_ * W; }
        if (aok1) { int b = ar1 / HW; int rem = ar1 - b * HW; y1_ = rem / W; x1_ = rem - y1_ * W; }
    }
    const u16* aP0 = A + (size_t)ar0 * lda + ss0;
    const u16* aP1 = A + (size_t)ar1 * lda + ss1;
    const u16* bP0 = Bt + (size_t)(n0 + row0) * ldb + ss0;
    const u16* bP1 = Bt + (size_t)(n0 + row1) * ldb + ss1;

    int lbase = w * 1024;

    auto stage = [&](int bf, int k0) {
        u16* LA = lds[bf * 2];
        u16* LB = lds[bf * 2 + 1];
        const u16* sa0;
        const u16* sa1;
        if (!CONV) {
            sa0 = aok0 ? aP0 + k0 : zp;
            sa1 = aok1 ? aP1 + k0 : zp;
        } else {
            int tap = k0 >> 8;
            int t3 = tap / 3;
            int dy = t3 - 1, dx = tap - t3 * 3 - 1;
            int off = (dy * W + dx) * lda + (k0 & 255);
            int yy0 = y0_ + dy, xx0 = x0_ + dx;
            int yy1 = y1_ + dy, xx1 = x1_ + dx;
            sa0 = (aok0 && (unsigned)yy0 < (unsigned)H && (unsigned)xx0 < (unsigned)W) ? aP0 + off : zp;
            sa1 = (aok1 && (unsigned)yy1 < (unsigned)H && (unsigned)xx1 < (unsigned)W) ? aP1 + off : zp;
        }
        gll16(sa0, LA + lbase);
        gll16(sa1, LA + lbase + 512);
        gll16(bP0 + k0, LB + lbase);
        gll16(bP1 + k0, LB + lbase + 512);
    };

    int nst = K >> 5;
    int fm = lane & 15;
    int co = (((lane >> 4) ^ ((fm >> 1) & 3)) << 3);

    stage(0, 0);
    __syncthreads();  // implicit vmcnt(0) drain -> buf0 ready
    for (int s = 0; s < nst; s++) {
        int bf = s & 1;
        if (s + 1 < nst) stage(bf ^ 1, (s + 1) << 5);  // in flight during compute
        const u16* LA = lds[bf * 2];
        const u16* LB = lds[bf * 2 + 1];
        bf16x8 af[4], bfv[4];
#pragma unroll
        for (int i = 0; i < 4; i++) af[i] = *(const bf16x8*)&LA[(wm * 64 + i * 16 + fm) * 32 + co];
#pragma unroll
        for (int j = 0; j < 4; j++) bfv[j] = *(const bf16x8*)&LB[(wn * 64 + j * 16 + fm) * 32 + co];
#pragma unroll
        for (int i = 0; i < 4; i++)
#pragma unroll
            for (int j = 0; j < 4; j++)
                acc[i][j] = __builtin_amdgcn_mfma_f32_16x16x32_bf16(af[i], bfv[j], acc[i][j], 0, 0, 0);
        __syncthreads();  // drains stage loads (next buf ready) + guards buf reuse
    }

    int q = lane >> 4, nl = lane & 15;
#pragma unroll
    for (int j = 0; j < 4; j++) {
        int n = n0 + wn * 64 + j * 16 + nl;
        float bv = b2f(bias[n]);
#pragma unroll
        for (int i = 0; i < 4; i++) {
            int mbase = m0 + wm * 64 + i * 16 + q * 4;
#pragma unroll
            for (int rg = 0; rg < 4; rg++) {
                int m = mbase + rg;
                if (m < M) {
                    float v = acc[i][j][rg] + bv;
                    if (RELU) v = fmaxf(v, 0.f);
                    u16 bs = f2b(v);
                    out[(size_t)m * 256 + n] = bs;
                    if (out2) out2[(size_t)m * 256 + n] = bs;
                }
            }
        }
    }
}

// all 3 lateral 1x1 GEMMs, one launch; y-range selects level (K differs per level)
__global__ __launch_bounds__(256) void lat_all_kernel(
    const u16* __restrict__ Xt3, const u16* __restrict__ Xt4, const u16* __restrict__ Xt5,
    const u16* __restrict__ W1, const u16* __restrict__ BB, const u16* __restrict__ zp,
    u16* __restrict__ P, u16* __restrict__ Ha) {
    __shared__ __align__(16) u16 lds[4][4096];
    int by = blockIdx.y;
    const u16* A; const u16* Bt; const u16* bias;
    int K, Ml, m0; size_t off;
    if (by < 200)      { A = Xt3; Bt = W1;          bias = BB;       K = 256; Ml = N3i; off = 0;                          m0 = by * 128; }
    else if (by < 250) { A = Xt4; Bt = W1 + 65536;  bias = BB + 256; K = 512; Ml = N4i; off = (size_t)N3i * 256;          m0 = (by - 200) * 128; }
    else               { A = Xt5; Bt = W1 + 196608; bias = BB + 512; K = 512; Ml = N5i; off = (size_t)(N3i + N4i) * 256;  m0 = (by - 250) * 128; }
    gemm_body<false, false>(lds, A, K, Bt, K, bias, zp, P + off, Ha + off, Ml, K, 0, 0,
                            m0, blockIdx.x * 128);
}

// all 3 output 3x3 convs, one launch (526 equal-cost blocks)
__global__ __launch_bounds__(256) void conv_gemm_all(
    const u16* __restrict__ Pc, const u16* __restrict__ WtC,
    const u16* __restrict__ BB, const u16* __restrict__ zp, u16* __restrict__ OutT) {
    __shared__ __align__(16) u16 lds[4][4096];
    int by = blockIdx.y;
    int lvl, yl, Hd, Ml; size_t base;
    if (by < 200)      { lvl = 0; yl = by;       Hd = 80; Ml = N3i; base = 0; }
    else if (by < 250) { lvl = 1; yl = by - 200; Hd = 40; Ml = N4i; base = (size_t)N3i * 256; }
    else               { lvl = 2; yl = by - 250; Hd = 20; Ml = N5i; base = (size_t)(N3i + N4i) * 256; }
    gemm_body<true, false>(lds, Pc + base, 256, WtC + (size_t)lvl * 256 * 2304, 2304,
                           BB + 3072 + lvl * 256, zp, OutT + base, nullptr,
                           Ml, 2304, Hd, Hd, yl * 128, blockIdx.x * 128);
}

// ---------------- fused pyramid composition: Pc = compose(P, Hf) ----------------
__global__ void pyr_kernel(const u16* __restrict__ P, const u16* __restrict__ Hf,
                           u16* __restrict__ Pc) {
    int i = blockIdx.x * 256 + threadIdx.x;
    if (i >= NNi * 64) return;
    int node = i >> 6, c = (i & 63) * 4;
    size_t bi = (size_t)node * 256 + c;
    ushort4 pv = *(const ushort4*)(P + bi);
    ushort4 hv = *(const ushort4*)(Hf + bi);
    float v0 = b2f(pv.x) + b2f(hv.x);
    float v1 = b2f(pv.y) + b2f(hv.y);
    float v2 = b2f(pv.z) + b2f(hv.z);
    float v3 = b2f(pv.w) + b2f(hv.w);
    if (node < N3i) {
        int b = node / 6400, rem = node - b * 6400;
        int y = rem / 80, x = rem - y * 80;
        size_t s4 = ((size_t)N3i + b * 1600 + (y >> 1) * 40 + (x >> 1)) * 256 + c;
        size_t s5 = ((size_t)(N3i + N4i) + b * 400 + (y >> 2) * 20 + (x >> 2)) * 256 + c;
        ushort4 p4 = *(const ushort4*)(P + s4), h4 = *(const ushort4*)(Hf + s4);
        ushort4 p5 = *(const ushort4*)(P + s5), h5 = *(const ushort4*)(Hf + s5);
        v0 += b2f(p4.x) + b2f(h4.x) + b2f(p5.x) + b2f(h5.x);
        v1 += b2f(p4.y) + b2f(h4.y) + b2f(p5.y) + b2f(h5.y);
        v2 += b2f(p4.z) + b2f(h4.z) + b2f(p5.z) + b2f(h5.z);
        v3 += b2f(p4.w) + b2f(h4.w) + b2f(p5.w) + b2f(h5.w);
    } else if (node < N3i + N4i) {
        int n4 = node - N3i;
        int b = n4 / 1600, rem = n4 - b * 1600;
        int y = rem / 40, x = rem - y * 40;
        size_t s5 = ((size_t)(N3i + N4i) + b * 400 + (y >> 1) * 20 + (x >> 1)) * 256 + c;
        ushort4 p5 = *(const ushort4*)(P + s5), h5 = *(const ushort4*)(Hf + s5);
        v0 += b2f(p5.x) + b2f(h5.x);
        v1 += b2f(p5.y) + b2f(h5.y);
        v2 += b2f(p5.z) + b2f(h5.z);
        v3 += b2f(p5.w) + b2f(h5.w);
    }
    ushort4 o;
    o.x = f2b(v0); o.y = f2b(v1); o.z = f2b(v2); o.w = f2b(v3);
    *(ushort4*)(Pc + bi) = o;
}

// ---------------- host ----------------
extern "C" void kernel_launch(void* const* d_in, const int* in_sizes, int n_in,
                              void* d_out, int out_size, void* d_ws, size_t ws_size,
                              hipStream_t stream) {
    (void)in_sizes; (void)n_in; (void)out_size; (void)ws_size;
    const void* c3 = d_in[0];
    const void* c4 = d_in[1];
    const void* c5 = d_in[2];
    const void* w3_1 = d_in[3];
    const void* b3_1 = d_in[4];
    const void* w4_1 = d_in[5];
    const void* b4_1 = d_in[6];
    const void* w5_1 = d_in[7];
    const void* b5_1 = d_in[8];
    const void* w3_3 = d_in[9];
    const void* b3_3 = d_in[10];
    const void* w4_3 = d_in[11];
    const void* b4_3 = d_in[12];
    const void* w5_3 = d_in[13];
    const void* b5_3 = d_in[14];
    const void* Wc = d_in[15];
    const void* bc = d_in[16];
    const void* Wh = d_in[17];
    const void* bh = d_in[18];
    const int* src_c = (const int*)d_in[19];
    const int* dst_c = (const int*)d_in[20];
    const int* src_h = (const int*)d_in[21];
    const int* dst_h = (const int*)d_in[22];

    char* w = (char*)d_ws;
    auto alloc = [&](size_t bytes) -> void* {
        void* p = (void*)w;
        w += (bytes + 255) & ~(size_t)255;
        return p;
    };
    u16* XT  = (u16*)alloc(((size_t)N3i * 256 + (size_t)N4i * 512 + (size_t)N5i * 512) * 2);
    u16* Xt3 = XT;
    u16* Xt4 = XT + (size_t)N3i * 256;
    u16* Xt5 = Xt4 + (size_t)N4i * 512;
    u16* Pc  = XT;                          // pyramid output aliases XT (free after laterals)
    u16* WtC = XT + (size_t)NNi * 256;      // alias, starts right after Pc region (3.54 MB fits)
    u16* WtG = (u16*)alloc((size_t)9 * 65536 * 2);
    u16* W1  = (u16*)alloc((size_t)(65536 + 131072 + 131072) * 2);
    u16* BB  = (u16*)alloc((size_t)3840 * 2);
    u16* P   = (u16*)alloc((size_t)NNi * 256 * 2);
    u16* Ha  = (u16*)alloc((size_t)NNi * 256 * 2);
    u16* Hb  = (u16*)d_out;                 // alias d_out as scratch
    int* csr_c = (int*)alloc((size_t)ECi * 4);
    int* csr_h = (int*)alloc((size_t)EHi * 4);
    int* cnt2  = (int*)alloc((size_t)2 * NNi * 4);
    int* cnt_c = cnt2;
    int* cnt_h = cnt2 + NNi;
    int* rs_c  = (int*)alloc((size_t)(NNi + 1) * 4);
    int* rs_h  = (int*)alloc((size_t)(NNi + 1) * 4);
    int* cur_c = (int*)alloc((size_t)NNi * 4);
    int* cur_h = (int*)alloc((size_t)NNi * 4);
    float* inv_c = (float*)alloc((size_t)NNi * 4);
    float* inv_h = (float*)alloc((size_t)NNi * 4);
    int* flag  = (int*)alloc(256);
    u16* zp    = (u16*)alloc(256);          // zero page for masked GEMM staging

    // ---- dtype detection + zero-pad init ----
    detect_kernel<<<1, 64, 0, stream>>>(c3, flag, (uint32_t*)zp);

    // ---- CSR build ----
    zero_i32<<<(2 * NNi + 255) / 256, 256, 0, stream>>>(cnt2, 2 * NNi);
    hist2_kernel<<<(ECi + EHi + 255) / 256, 256, 0, stream>>>(dst_c, dst_h, cnt_c, cnt_h);
    scan2_kernel<<<2, 1024, 0, stream>>>(cnt_c, rs_c, cur_c, inv_c,
                                         cnt_h, rs_h, cur_h, inv_h, NNi);
    fill2_kernel<<<(ECi + EHi + 255) / 256, 256, 0, stream>>>(
        src_c, dst_c, cur_c, csr_c, src_h, dst_h, cur_h, csr_h);

    // ---- convert small tensors (one launch) ----
    CvtJobs cj;
    cj.src[0] = w3_1; cj.dst[0] = W1;          cj.n[0] = 65536;
    cj.src[1] = w4_1; cj.dst[1] = W1 + 65536;  cj.n[1] = 131072;
    cj.src[2] = w5_1; cj.dst[2] = W1 + 196608; cj.n[2] = 131072;
    cj.src[3] = b3_1; cj.dst[3] = BB;          cj.n[3] = 256;
    cj.src[4] = b4_1; cj.dst[4] = BB + 256;    cj.n[4] = 256;
    cj.src[5] = b5_1; cj.dst[5] = BB + 512;    cj.n[5] = 256;
    cj.src[6] = bc;   cj.dst[6] = BB + 768;    cj.n[6] = 1536;
    cj.src[7] = bh;   cj.dst[7] = BB + 2304;   cj.n[7] = 768;
    cj.src[8] = b3_3; cj.dst[8] = BB + 3072;   cj.n[8] = 256;
    cj.src[9] = b4_3; cj.dst[9] = BB + 3328;   cj.n[9] = 256;
    cj.src[10] = b5_3; cj.dst[10] = BB + 3584; cj.n[10] = 256;
    cvt_all_kernel<<<dim3(512, 11), 256, 0, stream>>>(cj, flag);

    // ---- input transposes + GNN weight transposes ----
    transpose_in3<<<dim3(263, 16, 4), dim3(32, 8), 0, stream>>>(c3, c4, c5, Xt3, Xt4, Xt5, flag);
    transpose_w<<<dim3(8, 8, 9), dim3(32, 8), 0, stream>>>(Wc, Wh, WtG, flag);

    // ---- lateral 1x1 convs -> P (and H0 = Ha), one launch ----
    lat_all_kernel<<<dim3(2, 263), 256, 0, stream>>>(Xt3, Xt4, Xt5, W1, BB, zp, P, Ha);

    // ---- conv weights AFTER laterals (WtC aliases Xt4/Xt5 tail) ----
    convw3_kernel<<<dim3(2304, 3), 256, 0, stream>>>(w3_3, w4_3, w5_3, WtC, flag);

    // ---- 9 GNN layers, one fused kernel each (gather->LDS->GEMM) ----
    u16* Hcur = Ha;
    u16* Hnxt = Hb;
    for (int l = 0; l < 9; l++) {
        bool ctx = (l < 3) || (l >= 6);
        const int* csr = ctx ? csr_c : csr_h;
        const int* rs = ctx ? rs_c : rs_h;
        const float* inv = ctx ? inv_c : inv_h;
        int ecap = ctx ? ECi : EHi;
        int wi = (l < 3) ? l : (l < 6 ? 6 + (l - 3) : l - 3);
        const u16* bias = (l < 3) ? BB + 768 + l * 256
                        : (l < 6 ? BB + 2304 + (l - 3) * 256 : BB + 768 + (l - 3) * 256);
        gnn_fused_kernel<<<NNi / 64, 256, 0, stream>>>(
            Hcur, csr, rs, inv, WtG + (size_t)wi * 65536, bias, Hnxt, ecap);
        u16* tmp = Hcur; Hcur = Hnxt; Hnxt = tmp;
    }
    u16* OutT = Hnxt;  // = Ha

    // ---- fused pyramid composition -> Pc ----
    pyr_kernel<<<(NNi * 64 + 255) / 256, 256, 0, stream>>>(P, Hcur, Pc);

    // ---- 3x3 convs (9-tap gathered GEMM), one launch ----
    conv_gemm_all<<<dim3(2, 263), 256, 0, stream>>>(Pc, WtC, BB, zp, OutT);

    // ---- node-major -> NCHW output (one launch) ----
    transpose_out3<<<dim3(8, 263, 4), dim3(32, 8), 0, stream>>>(OutT, d_out, flag);
}

// Round 5
// 670.370 us; speedup vs baseline: 1.5783x; 1.5783x over previous
//
#include <hip/hip_runtime.h>
#include <stdint.h>

#define N3i 25600
#define N4i 6400
#define N5i 1600
#define NNi 33600
#define ECi 260000
#define EHi 120000

typedef unsigned short u16;
typedef __bf16 bf16x8 __attribute__((ext_vector_type(8)));
typedef float f32x4 __attribute__((ext_vector_type(4)));
typedef unsigned short u16x8 __attribute__((ext_vector_type(8)));

__device__ __forceinline__ float b2f(u16 u) {
    union { float f; uint32_t i; } v; v.i = ((uint32_t)u) << 16; return v.f;
}
__device__ __forceinline__ u16 f2b(float f) {
    union { float f; uint32_t i; } v; v.f = f;
    uint32_t x = v.i;
    uint32_t r = (x + 0x7FFFu + ((x >> 16) & 1u)) >> 16;  // RNE
    return (u16)r;
}

// async global->LDS, 16B per lane. LDS dest must be wave-uniform base (+lane*16 by HW);
// global source is per-lane (rule #21: swizzle via source address, keep LDS linear).
__device__ __forceinline__ void gll16(const u16* g, u16* l) {
    __builtin_amdgcn_global_load_lds((const __attribute__((address_space(1))) void*)g,
                                     (__attribute__((address_space(3))) void*)l, 16, 0, 0);
}

// ---------------- dtype detection: flag=1 if inputs are bf16, 0 if fp32 ----------------
// also zeroes the 256B zero-pad region used by masked GEMM staging
__global__ void detect_kernel(const void* __restrict__ c3raw, int* __restrict__ flag,
                              uint32_t* __restrict__ zp) {
    const uint32_t* p = (const uint32_t*)c3raw;
    int t = threadIdx.x;
    zp[t] = 0;  // 64 * 4B = 256B zero pad
    int vote = 0;
    for (int i = t; i < 256; i += 64) {
        uint32_t w = p[i];
        uint32_t lo = w & 0xFFFFu;
        uint32_t e = (lo >> 7) & 0xFFu;
        if (lo == 0u || (e >= 100u && e <= 127u)) vote++;
    }
#pragma unroll
    for (int d = 32; d >= 1; d >>= 1) vote += __shfl_down(vote, d, 64);
    if (t == 0) flag[0] = (vote >= 192) ? 1 : 0;
}

// ---------------- utility kernels ----------------
__global__ void zero_i32(int* p, int n) {
    int i = blockIdx.x * 256 + threadIdx.x;
    if (i < n) p[i] = 0;
}

__global__ void hist2_kernel(const int* __restrict__ dst_c, const int* __restrict__ dst_h,
                             int* __restrict__ cnt_c, int* __restrict__ cnt_h) {
    int i = blockIdx.x * 256 + threadIdx.x;
    if (i < ECi) {
        int d = dst_c[i];
        if ((unsigned)d < (unsigned)NNi) atomicAdd(&cnt_c[d], 1);
    } else {
        int j = i - ECi;
        if (j < EHi) {
            int d = dst_h[j];
            if ((unsigned)d < (unsigned)NNi) atomicAdd(&cnt_h[d], 1);
        }
    }
}

// wave-shuffle scan; blockIdx.x==0 -> contextual, ==1 -> hierarchical (concurrent)
__global__ __launch_bounds__(1024) void scan2_kernel(
    const int* __restrict__ cnt_c, int* __restrict__ rs_c, int* __restrict__ cur_c,
    float* __restrict__ inv_c,
    const int* __restrict__ cnt_h, int* __restrict__ rs_h, int* __restrict__ cur_h,
    float* __restrict__ inv_h, int n) {
    const int* cnt = blockIdx.x ? cnt_h : cnt_c;
    int* rs = blockIdx.x ? rs_h : rs_c;
    int* cur = blockIdx.x ? cur_h : cur_c;
    float* inv = blockIdx.x ? inv_h : inv_c;
    __shared__ int ws[16];
    __shared__ int base;
    int t = threadIdx.x, wid = t >> 6, lane = t & 63;
    if (t == 0) { base = 0; rs[0] = 0; }
    __syncthreads();
    for (int i0 = 0; i0 < n; i0 += 1024) {
        int i = i0 + t;
        int v = (i < n) ? cnt[i] : 0;
        int x = v;
#pragma unroll
        for (int d = 1; d < 64; d <<= 1) {
            int y = __shfl_up(x, d, 64);
            if (lane >= d) x += y;
        }
        if (lane == 63) ws[wid] = x;
        __syncthreads();
        if (wid == 0) {
            int s = (lane < 16) ? ws[lane] : 0;
#pragma unroll
            for (int d = 1; d < 16; d <<= 1) {
                int y = __shfl_up(s, d, 64);
                if (lane >= d) s += y;
            }
            if (lane < 16) ws[lane] = s;
        }
        __syncthreads();
        int b = base;
        int incl = x + (wid ? ws[wid - 1] : 0);
        if (i < n) {
            rs[i + 1] = b + incl;
            cur[i] = b + incl - v;
            int dv = v < 1 ? 1 : v;
            inv[i] = 1.0f / (float)dv;
        }
        int tot = ws[15];
        __syncthreads();
        if (t == 1023) base = b + tot;
        __syncthreads();
    }
}

__global__ void fill2_kernel(const int* __restrict__ src_c, const int* __restrict__ dst_c,
                             int* __restrict__ cur_c, int* __restrict__ csr_c,
                             const int* __restrict__ src_h, const int* __restrict__ dst_h,
                             int* __restrict__ cur_h, int* __restrict__ csr_h) {
    int i = blockIdx.x * 256 + threadIdx.x;
    if (i < ECi) {
        int d = dst_c[i];
        if ((unsigned)d < (unsigned)NNi) {
            int p = atomicAdd(&cur_c[d], 1);
            if ((unsigned)p < (unsigned)ECi) csr_c[p] = src_c[i];
        }
    } else {
        int j = i - ECi;
        if (j < EHi) {
            int d = dst_h[j];
            if ((unsigned)d < (unsigned)NNi) {
                int p = atomicAdd(&cur_h[d], 1);
                if ((unsigned)p < (unsigned)EHi) csr_h[p] = src_h[j];
            }
        }
    }
}

// all 11 small conversions in one launch (grid.y = job id)
struct CvtJobs { const void* src[11]; u16* dst[11]; int n[11]; };

__global__ void cvt_all_kernel(CvtJobs j, const int* __restrict__ flag) {
    int job = blockIdx.y;
    int i = blockIdx.x * 256 + threadIdx.x;
    if (i >= j.n[job]) return;
    const void* s = j.src[job];
    j.dst[job][i] = flag[0] ? ((const u16*)s)[i] : f2b(((const float*)s)[i]);
}

// ---------------- transposes ----------------
__device__ __forceinline__ void tin_body(const void* in, size_t ioff, u16* outp, int R, int C,
                                         int isb, int c0, int r0, u16 (*tile)[33]) {
    const u16* inb = (const u16*)in + ioff;
    const float* inf_ = (const float*)in + ioff;
    int tx = threadIdx.x, ty = threadIdx.y;  // block (32,8)
#pragma unroll
    for (int i = 0; i < 4; i++) {
        int r = r0 + ty + i * 8, c = c0 + tx;
        if (r < R && c < C) {
            size_t idx = (size_t)r * C + c;
            tile[ty + i * 8][tx] = isb ? inb[idx] : f2b(inf_[idx]);
        }
    }
    __syncthreads();
#pragma unroll
    for (int i = 0; i < 4; i++) {
        int c = c0 + ty + i * 8, r = r0 + tx;
        if (c < C && r < R) outp[(size_t)c * R + r] = tile[tx][ty + i * 8];
    }
}

__global__ void transpose_in3(const void* __restrict__ c3, const void* __restrict__ c4,
                              const void* __restrict__ c5, u16* __restrict__ Xt3,
                              u16* __restrict__ Xt4, u16* __restrict__ Xt5,
                              const int* __restrict__ flag) {
    __shared__ u16 tile[32][33];
    int bx = blockIdx.x;
    const void* in; u16* outb; int R, C, xb;
    if (bx < 200)      { in = c3; outb = Xt3; R = 256; C = 6400; xb = bx; }
    else if (bx < 250) { in = c4; outb = Xt4; R = 512; C = 1600; xb = bx - 200; }
    else               { in = c5; outb = Xt5; R = 512; C = 400;  xb = bx - 250; }
    int r0 = blockIdx.y * 32;
    if (r0 >= R) return;
    size_t boff = (size_t)blockIdx.z * R * C;
    tin_body(in, boff, outb + boff, R, C, flag[0], xb * 32, r0, tile);
}

__global__ void transpose_w(const void* __restrict__ Wc, const void* __restrict__ Wh,
                            u16* __restrict__ WtG, const int* __restrict__ flag) {
    __shared__ u16 tile[32][33];
    int z = blockIdx.z;
    const void* in = (z < 6) ? Wc : Wh;
    int zi = (z < 6) ? z : z - 6;
    tin_body(in, (size_t)zi * 65536, WtG + (size_t)z * 65536, 256, 256, flag[0],
             blockIdx.x * 32, blockIdx.y * 32, tile);
}

__global__ void transpose_out3(const u16* __restrict__ OutT, void* __restrict__ outv,
                               const int* __restrict__ flag) {
    __shared__ u16 tile[32][33];
    int by = blockIdx.y;
    const u16* inb; size_t out_off; int R, yb;
    if (by < 200)      { inb = OutT; out_off = 0; R = 6400; yb = by; }
    else if (by < 250) { inb = OutT + (size_t)N3i * 256; out_off = (size_t)4 * 256 * 6400; R = 1600; yb = by - 200; }
    else               { inb = OutT + (size_t)(N3i + N4i) * 256; out_off = (size_t)4 * 256 * 8000; R = 400; yb = by - 250; }
    int r0 = yb * 32;
    if (r0 >= R) return;
    const int C = 256;
    int isb = flag[0];
    int c0 = blockIdx.x * 32;
    size_t boff = (size_t)blockIdx.z * R * C;
    const u16* inp = inb + boff;
    int tx = threadIdx.x, ty = threadIdx.y;
#pragma unroll
    for (int i = 0; i < 4; i++) {
        int r = r0 + ty + i * 8, c = c0 + tx;
        if (r < R && c < C) tile[ty + i * 8][tx] = inp[(size_t)r * C + c];
    }
    __syncthreads();
#pragma unroll
    for (int i = 0; i < 4; i++) {
        int c = c0 + ty + i * 8, r = r0 + tx;
        if (c < C && r < R) {
            size_t o = out_off + boff + (size_t)c * R + r;
            u16 v = tile[tx][ty + i * 8];
            if (isb) ((u16*)outv)[o] = v;
            else ((float*)outv)[o] = b2f(v);
        }
    }
}

// conv weight transform for all 3 levels: wt[n][tap*256+ci] = w[n][ci*9+tap]
__global__ void convw3_kernel(const void* __restrict__ w0, const void* __restrict__ w1,
                              const void* __restrict__ w2, u16* __restrict__ WtC,
                              const int* __restrict__ flag) {
    int lvl = blockIdx.y;
    const void* w = (lvl == 0) ? w0 : (lvl == 1) ? w1 : w2;
    u16* wt = WtC + (size_t)lvl * 256 * 2304;
    int i = blockIdx.x * 256 + threadIdx.x;
    if (i >= 256 * 2304) return;
    int n = i / 2304;
    int k = i - n * 2304;
    int tap = k >> 8, ci = k & 255;
    int si = n * 2304 + ci * 9 + tap;
    wt[i] = flag[0] ? ((const u16*)w)[si] : f2b(((const float*)w)[si]);
}

// ---------------- GNN gather: T = bf16(H + segsum(H[src]) * invdeg) ----------------
// Half-wave (32 lanes x 16B) owns one FULL node row. Up to 32 edge indices are
// prefetched in ONE coalesced load (csr[e0+lane]) and broadcast via shfl -- removes
// the per-edge index-load from the dependent chain. Row loads issue in 4/2/1 batches
// with dual accumulators. 8 nodes/block, grid 4200 -> ~16 blocks/CU (full TLP).
__global__ __launch_bounds__(256) void gather_kernel(
    const u16* __restrict__ H, const int* __restrict__ csr, const int* __restrict__ rs,
    const float* __restrict__ invdeg, u16* __restrict__ T, int ecap) {
    int node = blockIdx.x * 8 + (threadIdx.x >> 5);
    if (node >= NNi) return;
    int L = threadIdx.x & 31;
    int c = L * 8;
    int e0 = rs[node], e1 = rs[node + 1];
    e0 = e0 < 0 ? 0 : e0;
    e1 = e1 > ecap ? ecap : e1;
    u16x8 self = *(const u16x8*)(H + (size_t)node * 256 + c);  // issued early
    float a0 = 0.f, a1 = 0.f, a2 = 0.f, a3 = 0.f, a4 = 0.f, a5 = 0.f, a6 = 0.f, a7 = 0.f;
    float b0 = 0.f, b1 = 0.f, b2 = 0.f, b3 = 0.f, b4 = 0.f, b5 = 0.f, b6 = 0.f, b7 = 0.f;
    for (int base = e0; base < e1; base += 32) {
        int ee = base + L;
        int iv = 0;
        if (ee < e1) {
            iv = csr[ee];                     // one coalesced 128B load per half-wave
            iv = ((unsigned)iv < (unsigned)NNi) ? iv : 0;
        }
        int cnt = e1 - base;
        cnt = cnt > 32 ? 32 : cnt;
        int k = 0;
        for (; k + 3 < cnt; k += 4) {         // 4 row loads in flight
            int j0 = __shfl(iv, k, 32), j1 = __shfl(iv, k + 1, 32);
            int j2 = __shfl(iv, k + 2, 32), j3 = __shfl(iv, k + 3, 32);
            u16x8 h0 = *(const u16x8*)(H + (size_t)j0 * 256 + c);
            u16x8 h1 = *(const u16x8*)(H + (size_t)j1 * 256 + c);
            u16x8 h2 = *(const u16x8*)(H + (size_t)j2 * 256 + c);
            u16x8 h3 = *(const u16x8*)(H + (size_t)j3 * 256 + c);
            a0 += b2f(h0[0]); a1 += b2f(h0[1]); a2 += b2f(h0[2]); a3 += b2f(h0[3]);
            a4 += b2f(h0[4]); a5 += b2f(h0[5]); a6 += b2f(h0[6]); a7 += b2f(h0[7]);
            b0 += b2f(h1[0]); b1 += b2f(h1[1]); b2 += b2f(h1[2]); b3 += b2f(h1[3]);
            b4 += b2f(h1[4]); b5 += b2f(h1[5]); b6 += b2f(h1[6]); b7 += b2f(h1[7]);
            a0 += b2f(h2[0]); a1 += b2f(h2[1]); a2 += b2f(h2[2]); a3 += b2f(h2[3]);
            a4 += b2f(h2[4]); a5 += b2f(h2[5]); a6 += b2f(h2[6]); a7 += b2f(h2[7]);
            b0 += b2f(h3[0]); b1 += b2f(h3[1]); b2 += b2f(h3[2]); b3 += b2f(h3[3]);
            b4 += b2f(h3[4]); b5 += b2f(h3[5]); b6 += b2f(h3[6]); b7 += b2f(h3[7]);
        }
        if (k + 1 < cnt) {                    // 2 in flight
            int j0 = __shfl(iv, k, 32), j1 = __shfl(iv, k + 1, 32);
            u16x8 h0 = *(const u16x8*)(H + (size_t)j0 * 256 + c);
            u16x8 h1 = *(const u16x8*)(H + (size_t)j1 * 256 + c);
            a0 += b2f(h0[0]); a1 += b2f(h0[1]); a2 += b2f(h0[2]); a3 += b2f(h0[3]);
            a4 += b2f(h0[4]); a5 += b2f(h0[5]); a6 += b2f(h0[6]); a7 += b2f(h0[7]);
            b0 += b2f(h1[0]); b1 += b2f(h1[1]); b2 += b2f(h1[2]); b3 += b2f(h1[3]);
            b4 += b2f(h1[4]); b5 += b2f(h1[5]); b6 += b2f(h1[6]); b7 += b2f(h1[7]);
            k += 2;
        }
        if (k < cnt) {
            int j0 = __shfl(iv, k, 32);
            u16x8 h0 = *(const u16x8*)(H + (size_t)j0 * 256 + c);
            a0 += b2f(h0[0]); a1 += b2f(h0[1]); a2 += b2f(h0[2]); a3 += b2f(h0[3]);
            a4 += b2f(h0[4]); a5 += b2f(h0[5]); a6 += b2f(h0[6]); a7 += b2f(h0[7]);
        }
    }
    a0 += b0; a1 += b1; a2 += b2; a3 += b3; a4 += b4; a5 += b5; a6 += b6; a7 += b7;
    float inv = invdeg[node];
    u16x8 o;
    o[0] = f2b(b2f(self[0]) + a0 * inv); o[1] = f2b(b2f(self[1]) + a1 * inv);
    o[2] = f2b(b2f(self[2]) + a2 * inv); o[3] = f2b(b2f(self[3]) + a3 * inv);
    o[4] = f2b(b2f(self[4]) + a4 * inv); o[5] = f2b(b2f(self[5]) + a5 * inv);
    o[6] = f2b(b2f(self[6]) + a6 * inv); o[7] = f2b(b2f(self[7]) + a7 * inv);
    *(u16x8*)(T + (size_t)node * 256 + c) = o;
}

// ---------------- MFMA GEMM body (round-2 proven): gll + 2-buffer, 1 drain/K-step ----
// Chunk XOR-swizzle on BOTH global source and ds_read address (rule #21) -> conflict-free.
template <bool CONV, bool RELU>
__device__ __forceinline__ void gemm_body(
    u16 (* __restrict__ lds)[4096],
    const u16* __restrict__ A, int lda,
    const u16* __restrict__ Bt, int ldb,
    const u16* __restrict__ bias,
    const u16* __restrict__ zp,
    u16* __restrict__ out, u16* __restrict__ out2,
    int M, int K, int H, int W, int m0, int n0) {
    int t = threadIdx.x;
    int w = t >> 6, lane = t & 63;
    int wm = w & 1, wn = w >> 1;
    f32x4 acc[4][4] = {};

    int g0 = w * 128 + lane;
    int g1 = g0 + 64;
    int row0 = g0 >> 2, c0 = g0 & 3;
    int row1 = g1 >> 2, c1 = g1 & 3;
    int ss0 = ((c0 ^ ((row0 >> 1) & 3)) << 3);
    int ss1 = ((c1 ^ ((row1 >> 1) & 3)) << 3);

    int ar0 = m0 + row0, ar1 = m0 + row1;
    bool aok0 = ar0 < M, aok1 = ar1 < M;
    int y0_ = 0, x0_ = 0, y1_ = 0, x1_ = 0;
    if (CONV) {
        int HW = H * W;
        if (aok0) { int b = ar0 / HW; int rem = ar0 - b * HW; y0_ = rem / W; x0_ = rem - y0_ * W; }
        if (aok1) { int b = ar1 / HW; int rem = ar1 - b * HW; y1_ = rem / W; x1_ = rem - y1_ * W; }
    }
    const u16* aP0 = A + (size_t)ar0 * lda + ss0;
    const u16* aP1 = A + (size_t)ar1 * lda + ss1;
    const u16* bP0 = Bt + (size_t)(n0 + row0) * ldb + ss0;
    const u16* bP1 = Bt + (size_t)(n0 + row1) * ldb + ss1;

    int lbase = w * 1024;

    auto stage = [&](int bf, int k0) {
        u16* LA = lds[bf * 2];
        u16* LB = lds[bf * 2 + 1];
        const u16* sa0;
        const u16* sa1;
        if (!CONV) {
            sa0 = aok0 ? aP0 + k0 : zp;
            sa1 = aok1 ? aP1 + k0 : zp;
        } else {
            int tap = k0 >> 8;
            int t3 = tap / 3;
            int dy = t3 - 1, dx = tap - t3 * 3 - 1;
            int off = (dy * W + dx) * lda + (k0 & 255);
            int yy0 = y0_ + dy, xx0 = x0_ + dx;
            int yy1 = y1_ + dy, xx1 = x1_ + dx;
            sa0 = (aok0 && (unsigned)yy0 < (unsigned)H && (unsigned)xx0 < (unsigned)W) ? aP0 + off : zp;
            sa1 = (aok1 && (unsigned)yy1 < (unsigned)H && (unsigned)xx1 < (unsigned)W) ? aP1 + off : zp;
        }
        gll16(sa0, LA + lbase);
        gll16(sa1, LA + lbase + 512);
        gll16(bP0 + k0, LB + lbase);
        gll16(bP1 + k0, LB + lbase + 512);
    };

    int nst = K >> 5;
    int fm = lane & 15;
    int co = (((lane >> 4) ^ ((fm >> 1) & 3)) << 3);

    stage(0, 0);
    __syncthreads();  // implicit vmcnt(0) drain -> buf0 ready
    for (int s = 0; s < nst; s++) {
        int bf = s & 1;
        if (s + 1 < nst) stage(bf ^ 1, (s + 1) << 5);  // in flight during compute
        const u16* LA = lds[bf * 2];
        const u16* LB = lds[bf * 2 + 1];
        bf16x8 af[4], bfv[4];
#pragma unroll
        for (int i = 0; i < 4; i++) af[i] = *(const bf16x8*)&LA[(wm * 64 + i * 16 + fm) * 32 + co];
#pragma unroll
        for (int j = 0; j < 4; j++) bfv[j] = *(const bf16x8*)&LB[(wn * 64 + j * 16 + fm) * 32 + co];
#pragma unroll
        for (int i = 0; i < 4; i++)
#pragma unroll
            for (int j = 0; j < 4; j++)
                acc[i][j] = __builtin_amdgcn_mfma_f32_16x16x32_bf16(af[i], bfv[j], acc[i][j], 0, 0, 0);
        __syncthreads();  // drains stage loads (next buf ready) + guards buf reuse
    }

    int q = lane >> 4, nl = lane & 15;
#pragma unroll
    for (int j = 0; j < 4; j++) {
        int n = n0 + wn * 64 + j * 16 + nl;
        float bv = b2f(bias[n]);
#pragma unroll
        for (int i = 0; i < 4; i++) {
            int mbase = m0 + wm * 64 + i * 16 + q * 4;
#pragma unroll
            for (int rg = 0; rg < 4; rg++) {
                int m = mbase + rg;
                if (m < M) {
                    float v = acc[i][j][rg] + bv;
                    if (RELU) v = fmaxf(v, 0.f);
                    u16 bs = f2b(v);
                    out[(size_t)m * 256 + n] = bs;
                    if (out2) out2[(size_t)m * 256 + n] = bs;
                }
            }
        }
    }
}

// generic wrapper (GNN layers)
template <bool CONV, bool RELU>
__global__ __launch_bounds__(256) void gemm_kernel(
    const u16* __restrict__ A, int lda,
    const u16* __restrict__ Bt, int ldb,
    const u16* __restrict__ bias,
    const u16* __restrict__ zp,
    u16* __restrict__ out, u16* __restrict__ out2,
    int M, int K, int H, int W) {
    __shared__ __align__(16) u16 lds[4][4096];
    gemm_body<CONV, RELU>(lds, A, lda, Bt, ldb, bias, zp, out, out2, M, K, H, W,
                          blockIdx.y * 128, blockIdx.x * 128);
}

// all 3 lateral 1x1 GEMMs, one launch; y-range selects level (K differs per level)
__global__ __launch_bounds__(256) void lat_all_kernel(
    const u16* __restrict__ Xt3, const u16* __restrict__ Xt4, const u16* __restrict__ Xt5,
    const u16* __restrict__ W1, const u16* __restrict__ BB, const u16* __restrict__ zp,
    u16* __restrict__ P, u16* __restrict__ Ha) {
    __shared__ __align__(16) u16 lds[4][4096];
    int by = blockIdx.y;
    const u16* A; const u16* Bt; const u16* bias;
    int K, Ml, m0; size_t off;
    if (by < 200)      { A = Xt3; Bt = W1;          bias = BB;       K = 256; Ml = N3i; off = 0;                          m0 = by * 128; }
    else if (by < 250) { A = Xt4; Bt = W1 + 65536;  bias = BB + 256; K = 512; Ml = N4i; off = (size_t)N3i * 256;          m0 = (by - 200) * 128; }
    else               { A = Xt5; Bt = W1 + 196608; bias = BB + 512; K = 512; Ml = N5i; off = (size_t)(N3i + N4i) * 256;  m0 = (by - 250) * 128; }
    gemm_body<false, false>(lds, A, K, Bt, K, bias, zp, P + off, Ha + off, Ml, K, 0, 0,
                            m0, blockIdx.x * 128);
}

// all 3 output 3x3 convs, one launch (526 equal-cost blocks)
__global__ __launch_bounds__(256) void conv_gemm_all(
    const u16* __restrict__ Pc, const u16* __restrict__ WtC,
    const u16* __restrict__ BB, const u16* __restrict__ zp, u16* __restrict__ OutT) {
    __shared__ __align__(16) u16 lds[4][4096];
    int by = blockIdx.y;
    int lvl, yl, Hd, Ml; size_t base;
    if (by < 200)      { lvl = 0; yl = by;       Hd = 80; Ml = N3i; base = 0; }
    else if (by < 250) { lvl = 1; yl = by - 200; Hd = 40; Ml = N4i; base = (size_t)N3i * 256; }
    else               { lvl = 2; yl = by - 250; Hd = 20; Ml = N5i; base = (size_t)(N3i + N4i) * 256; }
    gemm_body<true, false>(lds, Pc + base, 256, WtC + (size_t)lvl * 256 * 2304, 2304,
                           BB + 3072 + lvl * 256, zp, OutT + base, nullptr,
                           Ml, 2304, Hd, Hd, yl * 128, blockIdx.x * 128);
}

// ---------------- fused pyramid composition: Pc = compose(P, Hf) ----------------
__global__ void pyr_kernel(const u16* __restrict__ P, const u16* __restrict__ Hf,
                           u16* __restrict__ Pc) {
    int i = blockIdx.x * 256 + threadIdx.x;
    if (i >= NNi * 64) return;
    int node = i >> 6, c = (i & 63) * 4;
    size_t bi = (size_t)node * 256 + c;
    ushort4 pv = *(const ushort4*)(P + bi);
    ushort4 hv = *(const ushort4*)(Hf + bi);
    float v0 = b2f(pv.x) + b2f(hv.x);
    float v1 = b2f(pv.y) + b2f(hv.y);
    float v2 = b2f(pv.z) + b2f(hv.z);
    float v3 = b2f(pv.w) + b2f(hv.w);
    if (node < N3i) {
        int b = node / 6400, rem = node - b * 6400;
        int y = rem / 80, x = rem - y * 80;
        size_t s4 = ((size_t)N3i + b * 1600 + (y >> 1) * 40 + (x >> 1)) * 256 + c;
        size_t s5 = ((size_t)(N3i + N4i) + b * 400 + (y >> 2) * 20 + (x >> 2)) * 256 + c;
        ushort4 p4 = *(const ushort4*)(P + s4), h4 = *(const ushort4*)(Hf + s4);
        ushort4 p5 = *(const ushort4*)(P + s5), h5 = *(const ushort4*)(Hf + s5);
        v0 += b2f(p4.x) + b2f(h4.x) + b2f(p5.x) + b2f(h5.x);
        v1 += b2f(p4.y) + b2f(h4.y) + b2f(p5.y) + b2f(h5.y);
        v2 += b2f(p4.z) + b2f(h4.z) + b2f(p5.z) + b2f(h5.z);
        v3 += b2f(p4.w) + b2f(h4.w) + b2f(p5.w) + b2f(h5.w);
    } else if (node < N3i + N4i) {
        int n4 = node - N3i;
        int b = n4 / 1600, rem = n4 - b * 1600;
        int y = rem / 40, x = rem - y * 40;
        size_t s5 = ((size_t)(N3i + N4i) + b * 400 + (y >> 1) * 20 + (x >> 1)) * 256 + c;
        ushort4 p5 = *(const ushort4*)(P + s5), h5 = *(const ushort4*)(Hf + s5);
        v0 += b2f(p5.x) + b2f(h5.x);
        v1 += b2f(p5.y) + b2f(h5.y);
        v2 += b2f(p5.z) + b2f(h5.z);
        v3 += b2f(p5.w) + b2f(h5.w);
    }
    ushort4 o;
    o.x = f2b(v0); o.y = f2b(v1); o.z = f2b(v2); o.w = f2b(v3);
    *(ushort4*)(Pc + bi) = o;
}

// ---------------- host ----------------
extern "C" void kernel_launch(void* const* d_in, const int* in_sizes, int n_in,
                              void* d_out, int out_size, void* d_ws, size_t ws_size,
                              hipStream_t stream) {
    (void)in_sizes; (void)n_in; (void)out_size; (void)ws_size;
    const void* c3 = d_in[0];
    const void* c4 = d_in[1];
    const void* c5 = d_in[2];
    const void* w3_1 = d_in[3];
    const void* b3_1 = d_in[4];
    const void* w4_1 = d_in[5];
    const void* b4_1 = d_in[6];
    const void* w5_1 = d_in[7];
    const void* b5_1 = d_in[8];
    const void* w3_3 = d_in[9];
    const void* b3_3 = d_in[10];
    const void* w4_3 = d_in[11];
    const void* b4_3 = d_in[12];
    const void* w5_3 = d_in[13];
    const void* b5_3 = d_in[14];
    const void* Wc = d_in[15];
    const void* bc = d_in[16];
    const void* Wh = d_in[17];
    const void* bh = d_in[18];
    const int* src_c = (const int*)d_in[19];
    const int* dst_c = (const int*)d_in[20];
    const int* src_h = (const int*)d_in[21];
    const int* dst_h = (const int*)d_in[22];

    char* w = (char*)d_ws;
    auto alloc = [&](size_t bytes) -> void* {
        void* p = (void*)w;
        w += (bytes + 255) & ~(size_t)255;
        return p;
    };
    u16* XT  = (u16*)alloc(((size_t)N3i * 256 + (size_t)N4i * 512 + (size_t)N5i * 512) * 2);
    u16* Xt3 = XT;
    u16* Xt4 = XT + (size_t)N3i * 256;
    u16* Xt5 = Xt4 + (size_t)N4i * 512;
    u16* T   = XT;                          // alias (17.2 MB <= 21.3 MB region)
    u16* Pc  = XT;                          // pyramid output aliases T (free after GNN)
    u16* WtC = XT + (size_t)NNi * 256;      // alias, starts right after T (3.54 MB fits)
    u16* WtG = (u16*)alloc((size_t)9 * 65536 * 2);
    u16* W1  = (u16*)alloc((size_t)(65536 + 131072 + 131072) * 2);
    u16* BB  = (u16*)alloc((size_t)3840 * 2);
    u16* P   = (u16*)alloc((size_t)NNi * 256 * 2);
    u16* Ha  = (u16*)alloc((size_t)NNi * 256 * 2);
    u16* Hb  = (u16*)d_out;                 // alias d_out as scratch
    int* csr_c = (int*)alloc((size_t)ECi * 4);
    int* csr_h = (int*)alloc((size_t)EHi * 4);
    int* cnt2  = (int*)alloc((size_t)2 * NNi * 4);
    int* cnt_c = cnt2;
    int* cnt_h = cnt2 + NNi;
    int* rs_c  = (int*)alloc((size_t)(NNi + 1) * 4);
    int* rs_h  = (int*)alloc((size_t)(NNi + 1) * 4);
    int* cur_c = (int*)alloc((size_t)NNi * 4);
    int* cur_h = (int*)alloc((size_t)NNi * 4);
    float* inv_c = (float*)alloc((size_t)NNi * 4);
    float* inv_h = (float*)alloc((size_t)NNi * 4);
    int* flag  = (int*)alloc(256);
    u16* zp    = (u16*)alloc(256);          // zero page for masked GEMM staging

    // ---- dtype detection + zero-pad init ----
    detect_kernel<<<1, 64, 0, stream>>>(c3, flag, (uint32_t*)zp);

    // ---- CSR build ----
    zero_i32<<<(2 * NNi + 255) / 256, 256, 0, stream>>>(cnt2, 2 * NNi);
    hist2_kernel<<<(ECi + EHi + 255) / 256, 256, 0, stream>>>(dst_c, dst_h, cnt_c, cnt_h);
    scan2_kernel<<<2, 1024, 0, stream>>>(cnt_c, rs_c, cur_c, inv_c,
                                         cnt_h, rs_h, cur_h, inv_h, NNi);
    fill2_kernel<<<(ECi + EHi + 255) / 256, 256, 0, stream>>>(
        src_c, dst_c, cur_c, csr_c, src_h, dst_h, cur_h, csr_h);

    // ---- convert small tensors (one launch) ----
    CvtJobs cj;
    cj.src[0] = w3_1; cj.dst[0] = W1;          cj.n[0] = 65536;
    cj.src[1] = w4_1; cj.dst[1] = W1 + 65536;  cj.n[1] = 131072;
    cj.src[2] = w5_1; cj.dst[2] = W1 + 196608; cj.n[2] = 131072;
    cj.src[3] = b3_1; cj.dst[3] = BB;          cj.n[3] = 256;
    cj.src[4] = b4_1; cj.dst[4] = BB + 256;    cj.n[4] = 256;
    cj.src[5] = b5_1; cj.dst[5] = BB + 512;    cj.n[5] = 256;
    cj.src[6] = bc;   cj.dst[6] = BB + 768;    cj.n[6] = 1536;
    cj.src[7] = bh;   cj.dst[7] = BB + 2304;   cj.n[7] = 768;
    cj.src[8] = b3_3; cj.dst[8] = BB + 3072;   cj.n[8] = 256;
    cj.src[9] = b4_3; cj.dst[9] = BB + 3328;   cj.n[9] = 256;
    cj.src[10] = b5_3; cj.dst[10] = BB + 3584; cj.n[10] = 256;
    cvt_all_kernel<<<dim3(512, 11), 256, 0, stream>>>(cj, flag);

    // ---- input transposes + GNN weight transposes ----
    transpose_in3<<<dim3(263, 16, 4), dim3(32, 8), 0, stream>>>(c3, c4, c5, Xt3, Xt4, Xt5, flag);
    transpose_w<<<dim3(8, 8, 9), dim3(32, 8), 0, stream>>>(Wc, Wh, WtG, flag);

    // ---- lateral 1x1 convs -> P (and H0 = Ha), one launch ----
    lat_all_kernel<<<dim3(2, 263), 256, 0, stream>>>(Xt3, Xt4, Xt5, W1, BB, zp, P, Ha);

    // ---- conv weights AFTER laterals (WtC aliases Xt4/Xt5 tail) ----
    convw3_kernel<<<dim3(2304, 3), 256, 0, stream>>>(w3_3, w4_3, w5_3, WtC, flag);

    // ---- 9 GNN layers ----
    u16* Hcur = Ha;
    u16* Hnxt = Hb;
    for (int l = 0; l < 9; l++) {
        bool ctx = (l < 3) || (l >= 6);
        const int* csr = ctx ? csr_c : csr_h;
        const int* rs = ctx ? rs_c : rs_h;
        const float* inv = ctx ? inv_c : inv_h;
        int ecap = ctx ? ECi : EHi;
        int wi = (l < 3) ? l : (l < 6 ? 6 + (l - 3) : l - 3);
        const u16* bias = (l < 3) ? BB + 768 + l * 256
                        : (l < 6 ? BB + 2304 + (l - 3) * 256 : BB + 768 + (l - 3) * 256);
        gather_kernel<<<NNi / 8, 256, 0, stream>>>(Hcur, csr, rs, inv, T, ecap);
        gemm_kernel<false, true><<<dim3(2, 263), 256, 0, stream>>>(
            T, 256, WtG + (size_t)wi * 65536, 256, bias, zp, Hnxt, nullptr, NNi, 256, 0, 0);
        u16* tmp = Hcur; Hcur = Hnxt; Hnxt = tmp;
    }
    u16* OutT = Hnxt;  // = Ha

    // ---- fused pyramid composition -> Pc ----
    pyr_kernel<<<(NNi * 64 + 255) / 256, 256, 0, stream>>>(P, Hcur, Pc);

    // ---- 3x3 convs (9-tap gathered GEMM), one launch ----
    conv_gemm_all<<<dim3(2, 263), 256, 0, stream>>>(Pc, WtC, BB, zp, OutT);

    // ---- node-major -> NCHW output (one launch) ----
    transpose_out3<<<dim3(8, 263, 4), dim3(32, 8), 0, stream>>>(OutT, d_out, flag);
}

// Round 6
// 654.606 us; speedup vs baseline: 1.6163x; 1.0241x over previous
//
#include <hip/hip_runtime.h>
#include <stdint.h>

#define N3i 25600
#define N4i 6400
#define N5i 1600
#define NNi 33600
#define ECi 260000
#define EHi 120000

typedef unsigned short u16;
typedef __bf16 bf16x8 __attribute__((ext_vector_type(8)));
typedef float f32x4 __attribute__((ext_vector_type(4)));
typedef unsigned short u16x8 __attribute__((ext_vector_type(8)));

__device__ __forceinline__ float b2f(u16 u) {
    union { float f; uint32_t i; } v; v.i = ((uint32_t)u) << 16; return v.f;
}
__device__ __forceinline__ u16 f2b(float f) {
    union { float f; uint32_t i; } v; v.f = f;
    uint32_t x = v.i;
    uint32_t r = (x + 0x7FFFu + ((x >> 16) & 1u)) >> 16;  // RNE
    return (u16)r;
}

// async global->LDS, 16B per lane. LDS dest must be wave-uniform base (+lane*16 by HW);
// global source is per-lane (rule #21: swizzle via source address, keep LDS linear).
__device__ __forceinline__ void gll16(const u16* g, u16* l) {
    __builtin_amdgcn_global_load_lds((const __attribute__((address_space(1))) void*)g,
                                     (__attribute__((address_space(3))) void*)l, 16, 0, 0);
}

// XCD pair-affinity decode: 528-block 1-D grid -> (p: row-tile 0..262, x: col-half 0..1)
// with both members of a pair on the SAME XCD (assuming xcd = bid % 8 round-robin).
// Pair members are 8 ids apart -> dispatched near-simultaneously; each XCD owns a
// contiguous band of row-tiles (tap-overlap locality). If the mapping assumption is
// wrong this is a benign permutation (correctness unaffected).
__device__ __forceinline__ bool xcd_pair_decode(int pid, int& p, int& x) {
    int g = pid & 7;
    int s = pid >> 3;
    x = s & 1;
    p = g * 33 + (s >> 1);
    return p < 263;
}

// ---------------- dtype detection: flag=1 if inputs are bf16, 0 if fp32 ----------------
// also zeroes the 256B zero-pad region used by masked GEMM staging
__global__ void detect_kernel(const void* __restrict__ c3raw, int* __restrict__ flag,
                              uint32_t* __restrict__ zp) {
    const uint32_t* p = (const uint32_t*)c3raw;
    int t = threadIdx.x;
    zp[t] = 0;  // 64 * 4B = 256B zero pad
    int vote = 0;
    for (int i = t; i < 256; i += 64) {
        uint32_t w = p[i];
        uint32_t lo = w & 0xFFFFu;
        uint32_t e = (lo >> 7) & 0xFFu;
        if (lo == 0u || (e >= 100u && e <= 127u)) vote++;
    }
#pragma unroll
    for (int d = 32; d >= 1; d >>= 1) vote += __shfl_down(vote, d, 64);
    if (t == 0) flag[0] = (vote >= 192) ? 1 : 0;
}

// ---------------- utility kernels ----------------
__global__ void zero_i32(int* p, int n) {
    int i = blockIdx.x * 256 + threadIdx.x;
    if (i < n) p[i] = 0;
}

__global__ void hist2_kernel(const int* __restrict__ dst_c, const int* __restrict__ dst_h,
                             int* __restrict__ cnt_c, int* __restrict__ cnt_h) {
    int i = blockIdx.x * 256 + threadIdx.x;
    if (i < ECi) {
        int d = dst_c[i];
        if ((unsigned)d < (unsigned)NNi) atomicAdd(&cnt_c[d], 1);
    } else {
        int j = i - ECi;
        if (j < EHi) {
            int d = dst_h[j];
            if ((unsigned)d < (unsigned)NNi) atomicAdd(&cnt_h[d], 1);
        }
    }
}

// wave-shuffle scan; blockIdx.x==0 -> contextual, ==1 -> hierarchical (concurrent)
__global__ __launch_bounds__(1024) void scan2_kernel(
    const int* __restrict__ cnt_c, int* __restrict__ rs_c, int* __restrict__ cur_c,
    float* __restrict__ inv_c,
    const int* __restrict__ cnt_h, int* __restrict__ rs_h, int* __restrict__ cur_h,
    float* __restrict__ inv_h, int n) {
    const int* cnt = blockIdx.x ? cnt_h : cnt_c;
    int* rs = blockIdx.x ? rs_h : rs_c;
    int* cur = blockIdx.x ? cur_h : cur_c;
    float* inv = blockIdx.x ? inv_h : inv_c;
    __shared__ int ws[16];
    __shared__ int base;
    int t = threadIdx.x, wid = t >> 6, lane = t & 63;
    if (t == 0) { base = 0; rs[0] = 0; }
    __syncthreads();
    for (int i0 = 0; i0 < n; i0 += 1024) {
        int i = i0 + t;
        int v = (i < n) ? cnt[i] : 0;
        int x = v;
#pragma unroll
        for (int d = 1; d < 64; d <<= 1) {
            int y = __shfl_up(x, d, 64);
            if (lane >= d) x += y;
        }
        if (lane == 63) ws[wid] = x;
        __syncthreads();
        if (wid == 0) {
            int s = (lane < 16) ? ws[lane] : 0;
#pragma unroll
            for (int d = 1; d < 16; d <<= 1) {
                int y = __shfl_up(s, d, 64);
                if (lane >= d) s += y;
            }
            if (lane < 16) ws[lane] = s;
        }
        __syncthreads();
        int b = base;
        int incl = x + (wid ? ws[wid - 1] : 0);
        if (i < n) {
            rs[i + 1] = b + incl;
            cur[i] = b + incl - v;
            int dv = v < 1 ? 1 : v;
            inv[i] = 1.0f / (float)dv;
        }
        int tot = ws[15];
        __syncthreads();
        if (t == 1023) base = b + tot;
        __syncthreads();
    }
}

__global__ void fill2_kernel(const int* __restrict__ src_c, const int* __restrict__ dst_c,
                             int* __restrict__ cur_c, int* __restrict__ csr_c,
                             const int* __restrict__ src_h, const int* __restrict__ dst_h,
                             int* __restrict__ cur_h, int* __restrict__ csr_h) {
    int i = blockIdx.x * 256 + threadIdx.x;
    if (i < ECi) {
        int d = dst_c[i];
        if ((unsigned)d < (unsigned)NNi) {
            int p = atomicAdd(&cur_c[d], 1);
            if ((unsigned)p < (unsigned)ECi) csr_c[p] = src_c[i];
        }
    } else {
        int j = i - ECi;
        if (j < EHi) {
            int d = dst_h[j];
            if ((unsigned)d < (unsigned)NNi) {
                int p = atomicAdd(&cur_h[d], 1);
                if ((unsigned)p < (unsigned)EHi) csr_h[p] = src_h[j];
            }
        }
    }
}

// all 11 small conversions in one launch (grid.y = job id)
struct CvtJobs { const void* src[11]; u16* dst[11]; int n[11]; };

__global__ void cvt_all_kernel(CvtJobs j, const int* __restrict__ flag) {
    int job = blockIdx.y;
    int i = blockIdx.x * 256 + threadIdx.x;
    if (i >= j.n[job]) return;
    const void* s = j.src[job];
    j.dst[job][i] = flag[0] ? ((const u16*)s)[i] : f2b(((const float*)s)[i]);
}

// ---------------- transposes ----------------
__device__ __forceinline__ void tin_body(const void* in, size_t ioff, u16* outp, int R, int C,
                                         int isb, int c0, int r0, u16 (*tile)[33]) {
    const u16* inb = (const u16*)in + ioff;
    const float* inf_ = (const float*)in + ioff;
    int tx = threadIdx.x, ty = threadIdx.y;  // block (32,8)
#pragma unroll
    for (int i = 0; i < 4; i++) {
        int r = r0 + ty + i * 8, c = c0 + tx;
        if (r < R && c < C) {
            size_t idx = (size_t)r * C + c;
            tile[ty + i * 8][tx] = isb ? inb[idx] : f2b(inf_[idx]);
        }
    }
    __syncthreads();
#pragma unroll
    for (int i = 0; i < 4; i++) {
        int c = c0 + ty + i * 8, r = r0 + tx;
        if (c < C && r < R) outp[(size_t)c * R + r] = tile[tx][ty + i * 8];
    }
}

__global__ void transpose_in3(const void* __restrict__ c3, const void* __restrict__ c4,
                              const void* __restrict__ c5, u16* __restrict__ Xt3,
                              u16* __restrict__ Xt4, u16* __restrict__ Xt5,
                              const int* __restrict__ flag) {
    __shared__ u16 tile[32][33];
    int bx = blockIdx.x;
    const void* in; u16* outb; int R, C, xb;
    if (bx < 200)      { in = c3; outb = Xt3; R = 256; C = 6400; xb = bx; }
    else if (bx < 250) { in = c4; outb = Xt4; R = 512; C = 1600; xb = bx - 200; }
    else               { in = c5; outb = Xt5; R = 512; C = 400;  xb = bx - 250; }
    int r0 = blockIdx.y * 32;
    if (r0 >= R) return;
    size_t boff = (size_t)blockIdx.z * R * C;
    tin_body(in, boff, outb + boff, R, C, flag[0], xb * 32, r0, tile);
}

__global__ void transpose_w(const void* __restrict__ Wc, const void* __restrict__ Wh,
                            u16* __restrict__ WtG, const int* __restrict__ flag) {
    __shared__ u16 tile[32][33];
    int z = blockIdx.z;
    const void* in = (z < 6) ? Wc : Wh;
    int zi = (z < 6) ? z : z - 6;
    tin_body(in, (size_t)zi * 65536, WtG + (size_t)z * 65536, 256, 256, flag[0],
             blockIdx.x * 32, blockIdx.y * 32, tile);
}

__global__ void transpose_out3(const u16* __restrict__ OutT, void* __restrict__ outv,
                               const int* __restrict__ flag) {
    __shared__ u16 tile[32][33];
    int by = blockIdx.y;
    const u16* inb; size_t out_off; int R, yb;
    if (by < 200)      { inb = OutT; out_off = 0; R = 6400; yb = by; }
    else if (by < 250) { inb = OutT + (size_t)N3i * 256; out_off = (size_t)4 * 256 * 6400; R = 1600; yb = by - 200; }
    else               { inb = OutT + (size_t)(N3i + N4i) * 256; out_off = (size_t)4 * 256 * 8000; R = 400; yb = by - 250; }
    int r0 = yb * 32;
    if (r0 >= R) return;
    const int C = 256;
    int isb = flag[0];
    int c0 = blockIdx.x * 32;
    size_t boff = (size_t)blockIdx.z * R * C;
    const u16* inp = inb + boff;
    int tx = threadIdx.x, ty = threadIdx.y;
#pragma unroll
    for (int i = 0; i < 4; i++) {
        int r = r0 + ty + i * 8, c = c0 + tx;
        if (r < R && c < C) tile[ty + i * 8][tx] = inp[(size_t)r * C + c];
    }
    __syncthreads();
#pragma unroll
    for (int i = 0; i < 4; i++) {
        int c = c0 + ty + i * 8, r = r0 + tx;
        if (c < C && r < R) {
            size_t o = out_off + boff + (size_t)c * R + r;
            u16 v = tile[tx][ty + i * 8];
            if (isb) ((u16*)outv)[o] = v;
            else ((float*)outv)[o] = b2f(v);
        }
    }
}

// conv weight transform for all 3 levels: wt[n][tap*256+ci] = w[n][ci*9+tap]
__global__ void convw3_kernel(const void* __restrict__ w0, const void* __restrict__ w1,
                              const void* __restrict__ w2, u16* __restrict__ WtC,
                              const int* __restrict__ flag) {
    int lvl = blockIdx.y;
    const void* w = (lvl == 0) ? w0 : (lvl == 1) ? w1 : w2;
    u16* wt = WtC + (size_t)lvl * 256 * 2304;
    int i = blockIdx.x * 256 + threadIdx.x;
    if (i >= 256 * 2304) return;
    int n = i / 2304;
    int k = i - n * 2304;
    int tap = k >> 8, ci = k & 255;
    int si = n * 2304 + ci * 9 + tap;
    wt[i] = flag[0] ? ((const u16*)w)[si] : f2b(((const float*)w)[si]);
}

// ---------------- GNN gather: T = bf16(H + segsum(H[src]) * invdeg) ----------------
// Half-wave (32 lanes x 16B) owns one FULL node row. Up to 32 edge indices are
// prefetched in ONE coalesced load (csr[e0+lane]) and broadcast via shfl -- removes
// the per-edge index-load from the dependent chain. Row loads issue in 4/2/1 batches
// with dual accumulators. 8 nodes/block, grid 4200 -> ~16 blocks/CU (full TLP).
__global__ __launch_bounds__(256) void gather_kernel(
    const u16* __restrict__ H, const int* __restrict__ csr, const int* __restrict__ rs,
    const float* __restrict__ invdeg, u16* __restrict__ T, int ecap) {
    int node = blockIdx.x * 8 + (threadIdx.x >> 5);
    if (node >= NNi) return;
    int L = threadIdx.x & 31;
    int c = L * 8;
    int e0 = rs[node], e1 = rs[node + 1];
    e0 = e0 < 0 ? 0 : e0;
    e1 = e1 > ecap ? ecap : e1;
    u16x8 self = *(const u16x8*)(H + (size_t)node * 256 + c);  // issued early
    float a0 = 0.f, a1 = 0.f, a2 = 0.f, a3 = 0.f, a4 = 0.f, a5 = 0.f, a6 = 0.f, a7 = 0.f;
    float b0 = 0.f, b1 = 0.f, b2 = 0.f, b3 = 0.f, b4 = 0.f, b5 = 0.f, b6 = 0.f, b7 = 0.f;
    for (int base = e0; base < e1; base += 32) {
        int ee = base + L;
        int iv = 0;
        if (ee < e1) {
            iv = csr[ee];                     // one coalesced 128B load per half-wave
            iv = ((unsigned)iv < (unsigned)NNi) ? iv : 0;
        }
        int cnt = e1 - base;
        cnt = cnt > 32 ? 32 : cnt;
        int k = 0;
        for (; k + 3 < cnt; k += 4) {         // 4 row loads in flight
            int j0 = __shfl(iv, k, 32), j1 = __shfl(iv, k + 1, 32);
            int j2 = __shfl(iv, k + 2, 32), j3 = __shfl(iv, k + 3, 32);
            u16x8 h0 = *(const u16x8*)(H + (size_t)j0 * 256 + c);
            u16x8 h1 = *(const u16x8*)(H + (size_t)j1 * 256 + c);
            u16x8 h2 = *(const u16x8*)(H + (size_t)j2 * 256 + c);
            u16x8 h3 = *(const u16x8*)(H + (size_t)j3 * 256 + c);
            a0 += b2f(h0[0]); a1 += b2f(h0[1]); a2 += b2f(h0[2]); a3 += b2f(h0[3]);
            a4 += b2f(h0[4]); a5 += b2f(h0[5]); a6 += b2f(h0[6]); a7 += b2f(h0[7]);
            b0 += b2f(h1[0]); b1 += b2f(h1[1]); b2 += b2f(h1[2]); b3 += b2f(h1[3]);
            b4 += b2f(h1[4]); b5 += b2f(h1[5]); b6 += b2f(h1[6]); b7 += b2f(h1[7]);
            a0 += b2f(h2[0]); a1 += b2f(h2[1]); a2 += b2f(h2[2]); a3 += b2f(h2[3]);
            a4 += b2f(h2[4]); a5 += b2f(h2[5]); a6 += b2f(h2[6]); a7 += b2f(h2[7]);
            b0 += b2f(h3[0]); b1 += b2f(h3[1]); b2 += b2f(h3[2]); b3 += b2f(h3[3]);
            b4 += b2f(h3[4]); b5 += b2f(h3[5]); b6 += b2f(h3[6]); b7 += b2f(h3[7]);
        }
        if (k + 1 < cnt) {                    // 2 in flight
            int j0 = __shfl(iv, k, 32), j1 = __shfl(iv, k + 1, 32);
            u16x8 h0 = *(const u16x8*)(H + (size_t)j0 * 256 + c);
            u16x8 h1 = *(const u16x8*)(H + (size_t)j1 * 256 + c);
            a0 += b2f(h0[0]); a1 += b2f(h0[1]); a2 += b2f(h0[2]); a3 += b2f(h0[3]);
            a4 += b2f(h0[4]); a5 += b2f(h0[5]); a6 += b2f(h0[6]); a7 += b2f(h0[7]);
            b0 += b2f(h1[0]); b1 += b2f(h1[1]); b2 += b2f(h1[2]); b3 += b2f(h1[3]);
            b4 += b2f(h1[4]); b5 += b2f(h1[5]); b6 += b2f(h1[6]); b7 += b2f(h1[7]);
            k += 2;
        }
        if (k < cnt) {
            int j0 = __shfl(iv, k, 32);
            u16x8 h0 = *(const u16x8*)(H + (size_t)j0 * 256 + c);
            a0 += b2f(h0[0]); a1 += b2f(h0[1]); a2 += b2f(h0[2]); a3 += b2f(h0[3]);
            a4 += b2f(h0[4]); a5 += b2f(h0[5]); a6 += b2f(h0[6]); a7 += b2f(h0[7]);
        }
    }
    a0 += b0; a1 += b1; a2 += b2; a3 += b3; a4 += b4; a5 += b5; a6 += b6; a7 += b7;
    float inv = invdeg[node];
    u16x8 o;
    o[0] = f2b(b2f(self[0]) + a0 * inv); o[1] = f2b(b2f(self[1]) + a1 * inv);
    o[2] = f2b(b2f(self[2]) + a2 * inv); o[3] = f2b(b2f(self[3]) + a3 * inv);
    o[4] = f2b(b2f(self[4]) + a4 * inv); o[5] = f2b(b2f(self[5]) + a5 * inv);
    o[6] = f2b(b2f(self[6]) + a6 * inv); o[7] = f2b(b2f(self[7]) + a7 * inv);
    *(u16x8*)(T + (size_t)node * 256 + c) = o;
}

// ---------------- MFMA GEMM body (round-2 proven): gll + 2-buffer, 1 drain/K-step ----
// Chunk XOR-swizzle on BOTH global source and ds_read address (rule #21) -> conflict-free.
template <bool CONV, bool RELU>
__device__ __forceinline__ void gemm_body(
    u16 (* __restrict__ lds)[4096],
    const u16* __restrict__ A, int lda,
    const u16* __restrict__ Bt, int ldb,
    const u16* __restrict__ bias,
    const u16* __restrict__ zp,
    u16* __restrict__ out, u16* __restrict__ out2,
    int M, int K, int H, int W, int m0, int n0) {
    int t = threadIdx.x;
    int w = t >> 6, lane = t & 63;
    int wm = w & 1, wn = w >> 1;
    f32x4 acc[4][4] = {};

    int g0 = w * 128 + lane;
    int g1 = g0 + 64;
    int row0 = g0 >> 2, c0 = g0 & 3;
    int row1 = g1 >> 2, c1 = g1 & 3;
    int ss0 = ((c0 ^ ((row0 >> 1) & 3)) << 3);
    int ss1 = ((c1 ^ ((row1 >> 1) & 3)) << 3);

    int ar0 = m0 + row0, ar1 = m0 + row1;
    bool aok0 = ar0 < M, aok1 = ar1 < M;
    int y0_ = 0, x0_ = 0, y1_ = 0, x1_ = 0;
    if (CONV) {
        int HW = H * W;
        if (aok0) { int b = ar0 / HW; int rem = ar0 - b * HW; y0_ = rem / W; x0_ = rem - y0_ * W; }
        if (aok1) { int b = ar1 / HW; int rem = ar1 - b * HW; y1_ = rem / W; x1_ = rem - y1_ * W; }
    }
    const u16* aP0 = A + (size_t)ar0 * lda + ss0;
    const u16* aP1 = A + (size_t)ar1 * lda + ss1;
    const u16* bP0 = Bt + (size_t)(n0 + row0) * ldb + ss0;
    const u16* bP1 = Bt + (size_t)(n0 + row1) * ldb + ss1;

    int lbase = w * 1024;

    auto stage = [&](int bf, int k0) {
        u16* LA = lds[bf * 2];
        u16* LB = lds[bf * 2 + 1];
        const u16* sa0;
        const u16* sa1;
        if (!CONV) {
            sa0 = aok0 ? aP0 + k0 : zp;
            sa1 = aok1 ? aP1 + k0 : zp;
        } else {
            int tap = k0 >> 8;
            int t3 = tap / 3;
            int dy = t3 - 1, dx = tap - t3 * 3 - 1;
            int off = (dy * W + dx) * lda + (k0 & 255);
            int yy0 = y0_ + dy, xx0 = x0_ + dx;
            int yy1 = y1_ + dy, xx1 = x1_ + dx;
            sa0 = (aok0 && (unsigned)yy0 < (unsigned)H && (unsigned)xx0 < (unsigned)W) ? aP0 + off : zp;
            sa1 = (aok1 && (unsigned)yy1 < (unsigned)H && (unsigned)xx1 < (unsigned)W) ? aP1 + off : zp;
        }
        gll16(sa0, LA + lbase);
        gll16(sa1, LA + lbase + 512);
        gll16(bP0 + k0, LB + lbase);
        gll16(bP1 + k0, LB + lbase + 512);
    };

    int nst = K >> 5;
    int fm = lane & 15;
    int co = (((lane >> 4) ^ ((fm >> 1) & 3)) << 3);

    stage(0, 0);
    __syncthreads();  // implicit vmcnt(0) drain -> buf0 ready
    for (int s = 0; s < nst; s++) {
        int bf = s & 1;
        if (s + 1 < nst) stage(bf ^ 1, (s + 1) << 5);  // in flight during compute
        const u16* LA = lds[bf * 2];
        const u16* LB = lds[bf * 2 + 1];
        bf16x8 af[4], bfv[4];
#pragma unroll
        for (int i = 0; i < 4; i++) af[i] = *(const bf16x8*)&LA[(wm * 64 + i * 16 + fm) * 32 + co];
#pragma unroll
        for (int j = 0; j < 4; j++) bfv[j] = *(const bf16x8*)&LB[(wn * 64 + j * 16 + fm) * 32 + co];
#pragma unroll
        for (int i = 0; i < 4; i++)
#pragma unroll
            for (int j = 0; j < 4; j++)
                acc[i][j] = __builtin_amdgcn_mfma_f32_16x16x32_bf16(af[i], bfv[j], acc[i][j], 0, 0, 0);
        __syncthreads();  // drains stage loads (next buf ready) + guards buf reuse
    }

    int q = lane >> 4, nl = lane & 15;
#pragma unroll
    for (int j = 0; j < 4; j++) {
        int n = n0 + wn * 64 + j * 16 + nl;
        float bv = b2f(bias[n]);
#pragma unroll
        for (int i = 0; i < 4; i++) {
            int mbase = m0 + wm * 64 + i * 16 + q * 4;
#pragma unroll
            for (int rg = 0; rg < 4; rg++) {
                int m = mbase + rg;
                if (m < M) {
                    float v = acc[i][j][rg] + bv;
                    if (RELU) v = fmaxf(v, 0.f);
                    u16 bs = f2b(v);
                    out[(size_t)m * 256 + n] = bs;
                    if (out2) out2[(size_t)m * 256 + n] = bs;
                }
            }
        }
    }
}

// generic wrapper (GNN layers), 528-block 1-D grid with XCD pair affinity
template <bool CONV, bool RELU>
__global__ __launch_bounds__(256) void gemm_kernel(
    const u16* __restrict__ A, int lda,
    const u16* __restrict__ Bt, int ldb,
    const u16* __restrict__ bias,
    const u16* __restrict__ zp,
    u16* __restrict__ out, u16* __restrict__ out2,
    int M, int K, int H, int W) {
    __shared__ __align__(16) u16 lds[4][4096];
    int p, x;
    if (!xcd_pair_decode(blockIdx.x, p, x)) return;
    gemm_body<CONV, RELU>(lds, A, lda, Bt, ldb, bias, zp, out, out2, M, K, H, W,
                          p * 128, x * 128);
}

// all 3 lateral 1x1 GEMMs, one launch; p-range selects level (K differs per level)
__global__ __launch_bounds__(256) void lat_all_kernel(
    const u16* __restrict__ Xt3, const u16* __restrict__ Xt4, const u16* __restrict__ Xt5,
    const u16* __restrict__ W1, const u16* __restrict__ BB, const u16* __restrict__ zp,
    u16* __restrict__ P, u16* __restrict__ Ha) {
    __shared__ __align__(16) u16 lds[4][4096];
    int p, x;
    if (!xcd_pair_decode(blockIdx.x, p, x)) return;
    const u16* A; const u16* Bt; const u16* bias;
    int K, Ml, m0; size_t off;
    if (p < 200)      { A = Xt3; Bt = W1;          bias = BB;       K = 256; Ml = N3i; off = 0;                          m0 = p * 128; }
    else if (p < 250) { A = Xt4; Bt = W1 + 65536;  bias = BB + 256; K = 512; Ml = N4i; off = (size_t)N3i * 256;          m0 = (p - 200) * 128; }
    else              { A = Xt5; Bt = W1 + 196608; bias = BB + 512; K = 512; Ml = N5i; off = (size_t)(N3i + N4i) * 256;  m0 = (p - 250) * 128; }
    gemm_body<false, false>(lds, A, K, Bt, K, bias, zp, P + off, Ha + off, Ml, K, 0, 0,
                            m0, x * 128);
}

// all 3 output 3x3 convs, one launch (526 equal-cost blocks, XCD pair affinity)
__global__ __launch_bounds__(256) void conv_gemm_all(
    const u16* __restrict__ Pc, const u16* __restrict__ WtC,
    const u16* __restrict__ BB, const u16* __restrict__ zp, u16* __restrict__ OutT) {
    __shared__ __align__(16) u16 lds[4][4096];
    int p, x;
    if (!xcd_pair_decode(blockIdx.x, p, x)) return;
    int lvl, yl, Hd, Ml; size_t base;
    if (p < 200)      { lvl = 0; yl = p;       Hd = 80; Ml = N3i; base = 0; }
    else if (p < 250) { lvl = 1; yl = p - 200; Hd = 40; Ml = N4i; base = (size_t)N3i * 256; }
    else              { lvl = 2; yl = p - 250; Hd = 20; Ml = N5i; base = (size_t)(N3i + N4i) * 256; }
    gemm_body<true, false>(lds, Pc + base, 256, WtC + (size_t)lvl * 256 * 2304, 2304,
                           BB + 3072 + lvl * 256, zp, OutT + base, nullptr,
                           Ml, 2304, Hd, Hd, yl * 128, x * 128);
}

// ---------------- fused pyramid composition: Pc = compose(P, Hf) ----------------
__global__ void pyr_kernel(const u16* __restrict__ P, const u16* __restrict__ Hf,
                           u16* __restrict__ Pc) {
    int i = blockIdx.x * 256 + threadIdx.x;
    if (i >= NNi * 64) return;
    int node = i >> 6, c = (i & 63) * 4;
    size_t bi = (size_t)node * 256 + c;
    ushort4 pv = *(const ushort4*)(P + bi);
    ushort4 hv = *(const ushort4*)(Hf + bi);
    float v0 = b2f(pv.x) + b2f(hv.x);
    float v1 = b2f(pv.y) + b2f(hv.y);
    float v2 = b2f(pv.z) + b2f(hv.z);
    float v3 = b2f(pv.w) + b2f(hv.w);
    if (node < N3i) {
        int b = node / 6400, rem = node - b * 6400;
        int y = rem / 80, x = rem - y * 80;
        size_t s4 = ((size_t)N3i + b * 1600 + (y >> 1) * 40 + (x >> 1)) * 256 + c;
        size_t s5 = ((size_t)(N3i + N4i) + b * 400 + (y >> 2) * 20 + (x >> 2)) * 256 + c;
        ushort4 p4 = *(const ushort4*)(P + s4), h4 = *(const ushort4*)(Hf + s4);
        ushort4 p5 = *(const ushort4*)(P + s5), h5 = *(const ushort4*)(Hf + s5);
        v0 += b2f(p4.x) + b2f(h4.x) + b2f(p5.x) + b2f(h5.x);
        v1 += b2f(p4.y) + b2f(h4.y) + b2f(p5.y) + b2f(h5.y);
        v2 += b2f(p4.z) + b2f(h4.z) + b2f(p5.z) + b2f(h5.z);
        v3 += b2f(p4.w) + b2f(h4.w) + b2f(p5.w) + b2f(h5.w);
    } else if (node < N3i + N4i) {
        int n4 = node - N3i;
        int b = n4 / 1600, rem = n4 - b * 1600;
        int y = rem / 40, x = rem - y * 40;
        size_t s5 = ((size_t)(N3i + N4i) + b * 400 + (y >> 1) * 20 + (x >> 1)) * 256 + c;
        ushort4 p5 = *(const ushort4*)(P + s5), h5 = *(const ushort4*)(Hf + s5);
        v0 += b2f(p5.x) + b2f(h5.x);
        v1 += b2f(p5.y) + b2f(h5.y);
        v2 += b2f(p5.z) + b2f(h5.z);
        v3 += b2f(p5.w) + b2f(h5.w);
    }
    ushort4 o;
    o.x = f2b(v0); o.y = f2b(v1); o.z = f2b(v2); o.w = f2b(v3);
    *(ushort4*)(Pc + bi) = o;
}

// ---------------- host ----------------
extern "C" void kernel_launch(void* const* d_in, const int* in_sizes, int n_in,
                              void* d_out, int out_size, void* d_ws, size_t ws_size,
                              hipStream_t stream) {
    (void)in_sizes; (void)n_in; (void)out_size; (void)ws_size;
    const void* c3 = d_in[0];
    const void* c4 = d_in[1];
    const void* c5 = d_in[2];
    const void* w3_1 = d_in[3];
    const void* b3_1 = d_in[4];
    const void* w4_1 = d_in[5];
    const void* b4_1 = d_in[6];
    const void* w5_1 = d_in[7];
    const void* b5_1 = d_in[8];
    const void* w3_3 = d_in[9];
    const void* b3_3 = d_in[10];
    const void* w4_3 = d_in[11];
    const void* b4_3 = d_in[12];
    const void* w5_3 = d_in[13];
    const void* b5_3 = d_in[14];
    const void* Wc = d_in[15];
    const void* bc = d_in[16];
    const void* Wh = d_in[17];
    const void* bh = d_in[18];
    const int* src_c = (const int*)d_in[19];
    const int* dst_c = (const int*)d_in[20];
    const int* src_h = (const int*)d_in[21];
    const int* dst_h = (const int*)d_in[22];

    char* w = (char*)d_ws;
    auto alloc = [&](size_t bytes) -> void* {
        void* p = (void*)w;
        w += (bytes + 255) & ~(size_t)255;
        return p;
    };
    u16* XT  = (u16*)alloc(((size_t)N3i * 256 + (size_t)N4i * 512 + (size_t)N5i * 512) * 2);
    u16* Xt3 = XT;
    u16* Xt4 = XT + (size_t)N3i * 256;
    u16* Xt5 = Xt4 + (size_t)N4i * 512;
    u16* T   = XT;                          // alias (17.2 MB <= 21.3 MB region)
    u16* Pc  = XT;                          // pyramid output aliases T (free after GNN)
    u16* WtC = XT + (size_t)NNi * 256;      // alias, starts right after T (3.54 MB fits)
    u16* WtG = (u16*)alloc((size_t)9 * 65536 * 2);
    u16* W1  = (u16*)alloc((size_t)(65536 + 131072 + 131072) * 2);
    u16* BB  = (u16*)alloc((size_t)3840 * 2);
    u16* P   = (u16*)alloc((size_t)NNi * 256 * 2);
    u16* Ha  = (u16*)alloc((size_t)NNi * 256 * 2);
    u16* Hb  = (u16*)d_out;                 // alias d_out as scratch
    int* csr_c = (int*)alloc((size_t)ECi * 4);
    int* csr_h = (int*)alloc((size_t)EHi * 4);
    int* cnt2  = (int*)alloc((size_t)2 * NNi * 4);
    int* cnt_c = cnt2;
    int* cnt_h = cnt2 + NNi;
    int* rs_c  = (int*)alloc((size_t)(NNi + 1) * 4);
    int* rs_h  = (int*)alloc((size_t)(NNi + 1) * 4);
    int* cur_c = (int*)alloc((size_t)NNi * 4);
    int* cur_h = (int*)alloc((size_t)NNi * 4);
    float* inv_c = (float*)alloc((size_t)NNi * 4);
    float* inv_h = (float*)alloc((size_t)NNi * 4);
    int* flag  = (int*)alloc(256);
    u16* zp    = (u16*)alloc(256);          // zero page for masked GEMM staging

    // ---- dtype detection + zero-pad init ----
    detect_kernel<<<1, 64, 0, stream>>>(c3, flag, (uint32_t*)zp);

    // ---- CSR build ----
    zero_i32<<<(2 * NNi + 255) / 256, 256, 0, stream>>>(cnt2, 2 * NNi);
    hist2_kernel<<<(ECi + EHi + 255) / 256, 256, 0, stream>>>(dst_c, dst_h, cnt_c, cnt_h);
    scan2_kernel<<<2, 1024, 0, stream>>>(cnt_c, rs_c, cur_c, inv_c,
                                         cnt_h, rs_h, cur_h, inv_h, NNi);
    fill2_kernel<<<(ECi + EHi + 255) / 256, 256, 0, stream>>>(
        src_c, dst_c, cur_c, csr_c, src_h, dst_h, cur_h, csr_h);

    // ---- convert small tensors (one launch) ----
    CvtJobs cj;
    cj.src[0] = w3_1; cj.dst[0] = W1;          cj.n[0] = 65536;
    cj.src[1] = w4_1; cj.dst[1] = W1 + 65536;  cj.n[1] = 131072;
    cj.src[2] = w5_1; cj.dst[2] = W1 + 196608; cj.n[2] = 131072;
    cj.src[3] = b3_1; cj.dst[3] = BB;          cj.n[3] = 256;
    cj.src[4] = b4_1; cj.dst[4] = BB + 256;    cj.n[4] = 256;
    cj.src[5] = b5_1; cj.dst[5] = BB + 512;    cj.n[5] = 256;
    cj.src[6] = bc;   cj.dst[6] = BB + 768;    cj.n[6] = 1536;
    cj.src[7] = bh;   cj.dst[7] = BB + 2304;   cj.n[7] = 768;
    cj.src[8] = b3_3; cj.dst[8] = BB + 3072;   cj.n[8] = 256;
    cj.src[9] = b4_3; cj.dst[9] = BB + 3328;   cj.n[9] = 256;
    cj.src[10] = b5_3; cj.dst[10] = BB + 3584; cj.n[10] = 256;
    cvt_all_kernel<<<dim3(512, 11), 256, 0, stream>>>(cj, flag);

    // ---- input transposes + GNN weight transposes ----
    transpose_in3<<<dim3(263, 16, 4), dim3(32, 8), 0, stream>>>(c3, c4, c5, Xt3, Xt4, Xt5, flag);
    transpose_w<<<dim3(8, 8, 9), dim3(32, 8), 0, stream>>>(Wc, Wh, WtG, flag);

    // ---- lateral 1x1 convs -> P (and H0 = Ha), one launch ----
    lat_all_kernel<<<528, 256, 0, stream>>>(Xt3, Xt4, Xt5, W1, BB, zp, P, Ha);

    // ---- conv weights AFTER laterals (WtC aliases Xt4/Xt5 tail) ----
    convw3_kernel<<<dim3(2304, 3), 256, 0, stream>>>(w3_3, w4_3, w5_3, WtC, flag);

    // ---- 9 GNN layers ----
    u16* Hcur = Ha;
    u16* Hnxt = Hb;
    for (int l = 0; l < 9; l++) {
        bool ctx = (l < 3) || (l >= 6);
        const int* csr = ctx ? csr_c : csr_h;
        const int* rs = ctx ? rs_c : rs_h;
        const float* inv = ctx ? inv_c : inv_h;
        int ecap = ctx ? ECi : EHi;
        int wi = (l < 3) ? l : (l < 6 ? 6 + (l - 3) : l - 3);
        const u16* bias = (l < 3) ? BB + 768 + l * 256
                        : (l < 6 ? BB + 2304 + (l - 3) * 256 : BB + 768 + (l - 3) * 256);
        gather_kernel<<<NNi / 8, 256, 0, stream>>>(Hcur, csr, rs, inv, T, ecap);
        gemm_kernel<false, true><<<528, 256, 0, stream>>>(
            T, 256, WtG + (size_t)wi * 65536, 256, bias, zp, Hnxt, nullptr, NNi, 256, 0, 0);
        u16* tmp = Hcur; Hcur = Hnxt; Hnxt = tmp;
    }
    u16* OutT = Hnxt;  // = Ha

    // ---- fused pyramid composition -> Pc ----
    pyr_kernel<<<(NNi * 64 + 255) / 256, 256, 0, stream>>>(P, Hcur, Pc);

    // ---- 3x3 convs (9-tap gathered GEMM), one launch ----
    conv_gemm_all<<<528, 256, 0, stream>>>(Pc, WtC, BB, zp, OutT);

    // ---- node-major -> NCHW output (one launch) ----
    transpose_out3<<<dim3(8, 263, 4), dim3(32, 8), 0, stream>>>(OutT, d_out, flag);
}

// Round 7
// 622.778 us; speedup vs baseline: 1.6989x; 1.0511x over previous
//
#include <hip/hip_runtime.h>
#include <stdint.h>

#define N3i 25600
#define N4i 6400
#define N5i 1600
#define NNi 33600
#define ECi 260000
#define EHi 120000

typedef unsigned short u16;
typedef __bf16 bf16x8 __attribute__((ext_vector_type(8)));
typedef float f32x4 __attribute__((ext_vector_type(4)));
typedef unsigned short u16x8 __attribute__((ext_vector_type(8)));

__device__ __forceinline__ float b2f(u16 u) {
    union { float f; uint32_t i; } v; v.i = ((uint32_t)u) << 16; return v.f;
}
__device__ __forceinline__ u16 f2b(float f) {
    union { float f; uint32_t i; } v; v.f = f;
    uint32_t x = v.i;
    uint32_t r = (x + 0x7FFFu + ((x >> 16) & 1u)) >> 16;  // RNE
    return (u16)r;
}

// async global->LDS, 16B per lane. LDS dest must be wave-uniform base (+lane*16 by HW);
// global source is per-lane (rule #21: swizzle via source address, keep LDS linear).
__device__ __forceinline__ void gll16(const u16* g, u16* l) {
    __builtin_amdgcn_global_load_lds((const __attribute__((address_space(1))) void*)g,
                                     (__attribute__((address_space(3))) void*)l, 16, 0, 0);
}

// XCD pair-affinity decode: 528-block 1-D grid -> (p: row-tile 0..262, x: col-half 0..1)
// with both members of a pair on the SAME XCD (xcd = bid % 8 round-robin -- CONFIRMED
// round 6: conv FETCH 110MB -> 14.5MB). Pair members are 8 ids apart; each XCD owns a
// contiguous band of row-tiles (tap-overlap locality).
__device__ __forceinline__ bool xcd_pair_decode(int pid, int& p, int& x) {
    int g = pid & 7;
    int s = pid >> 3;
    x = s & 1;
    p = g * 33 + (s >> 1);
    return p < 263;
}

// ---------------- dtype detection: flag=1 if inputs are bf16, 0 if fp32 ----------------
// also zeroes the 256B zero-pad region used by masked GEMM staging
__global__ void detect_kernel(const void* __restrict__ c3raw, int* __restrict__ flag,
                              uint32_t* __restrict__ zp) {
    const uint32_t* p = (const uint32_t*)c3raw;
    int t = threadIdx.x;
    zp[t] = 0;  // 64 * 4B = 256B zero pad
    int vote = 0;
    for (int i = t; i < 256; i += 64) {
        uint32_t w = p[i];
        uint32_t lo = w & 0xFFFFu;
        uint32_t e = (lo >> 7) & 0xFFu;
        if (lo == 0u || (e >= 100u && e <= 127u)) vote++;
    }
#pragma unroll
    for (int d = 32; d >= 1; d >>= 1) vote += __shfl_down(vote, d, 64);
    if (t == 0) flag[0] = (vote >= 192) ? 1 : 0;
}

// ---------------- utility kernels ----------------
__global__ void zero_i32(int* p, int n) {
    int i = blockIdx.x * 256 + threadIdx.x;
    if (i < n) p[i] = 0;
}

__global__ void hist2_kernel(const int* __restrict__ dst_c, const int* __restrict__ dst_h,
                             int* __restrict__ cnt_c, int* __restrict__ cnt_h) {
    int i = blockIdx.x * 256 + threadIdx.x;
    if (i < ECi) {
        int d = dst_c[i];
        if ((unsigned)d < (unsigned)NNi) atomicAdd(&cnt_c[d], 1);
    } else {
        int j = i - ECi;
        if (j < EHi) {
            int d = dst_h[j];
            if ((unsigned)d < (unsigned)NNi) atomicAdd(&cnt_h[d], 1);
        }
    }
}

// ---------------- 3-pass parallel scan (replaces 2-block serial scan2) ----------------
// pass 1: 132 blocks (0..65 ctx, 66..131 hier), 512 elems/block: block-local inclusive
// scan -> ps, block total -> bsum[b]
__global__ __launch_bounds__(256) void scan_part(
    const int* __restrict__ cnt_c, const int* __restrict__ cnt_h,
    int* __restrict__ ps_c, int* __restrict__ ps_h, int* __restrict__ bsum) {
    int b = blockIdx.x;
    bool hier = b >= 66;
    const int* cnt = hier ? cnt_h : cnt_c;
    int* ps = hier ? ps_h : ps_c;
    int base = (hier ? b - 66 : b) * 512;
    int t = threadIdx.x, lane = t & 63, wid = t >> 6;
    int i0 = base + 2 * t;
    int v0 = (i0 < NNi) ? cnt[i0] : 0;
    int v1 = (i0 + 1 < NNi) ? cnt[i0 + 1] : 0;
    int s = v0 + v1;
    int x = s;
#pragma unroll
    for (int d = 1; d < 64; d <<= 1) {
        int y = __shfl_up(x, d, 64);
        if (lane >= d) x += y;
    }
    __shared__ int ws[4];
    if (lane == 63) ws[wid] = x;
    __syncthreads();
    int w0 = ws[0], w1 = ws[1], w2 = ws[2], w3 = ws[3];
    int woff = (wid == 1) ? w0 : (wid == 2) ? (w0 + w1) : (wid == 3) ? (w0 + w1 + w2) : 0;
    int incl = x + woff;       // inclusive pair-sum through this thread
    int excl = incl - s;       // exclusive before this pair
    if (i0 < NNi) ps[i0] = excl + v0;
    if (i0 + 1 < NNi) ps[i0 + 1] = excl + v0 + v1;
    if (t == 0) bsum[b] = w0 + w1 + w2 + w3;
}

// pass 2: one block scans the two 66-entry bsum segments -> exclusive offsets (in place)
__global__ __launch_bounds__(256) void scan_sums(int* __restrict__ bsum) {
    __shared__ int s[132];
    int t = threadIdx.x;
    int orig = 0;
    if (t < 132) { orig = bsum[t]; s[t] = orig; }
    __syncthreads();
    for (int d = 1; d < 66; d <<= 1) {
        int v = 0;
        if (t < 132) {
            int seg = (t < 66) ? 0 : 1;
            int loc = t - seg * 66;
            if (loc >= d) v = s[t - d];
        }
        __syncthreads();
        if (t < 132) s[t] += v;
        __syncthreads();
    }
    if (t < 132) bsum[t] = s[t] - orig;  // exclusive segment offset
}

// pass 3: add offsets, emit rs/cur/inv
__global__ __launch_bounds__(256) void scan_final(
    const int* __restrict__ ps_c, const int* __restrict__ ps_h, const int* __restrict__ bsum,
    const int* __restrict__ cnt_c, const int* __restrict__ cnt_h,
    int* __restrict__ rs_c, int* __restrict__ cur_c, float* __restrict__ inv_c,
    int* __restrict__ rs_h, int* __restrict__ cur_h, float* __restrict__ inv_h) {
    int b = blockIdx.x;
    bool hier = b >= 66;
    int lb = hier ? b - 66 : b;
    const int* ps = hier ? ps_h : ps_c;
    const int* cnt = hier ? cnt_h : cnt_c;
    int* rs = hier ? rs_h : rs_c;
    int* cur = hier ? cur_h : cur_c;
    float* inv = hier ? inv_h : inv_c;
    int off = bsum[b];
    int t = threadIdx.x;
#pragma unroll
    for (int k = 0; k < 2; k++) {
        int i = lb * 512 + t + k * 256;
        if (i < NNi) {
            int incl = ps[i] + off;
            int v = cnt[i];
            rs[i + 1] = incl;
            cur[i] = incl - v;
            inv[i] = 1.0f / (float)(v < 1 ? 1 : v);
        }
    }
    if (b == 0 && t == 0) rs_c[0] = 0;
    if (b == 66 && t == 0) rs_h[0] = 0;
}

__global__ void fill2_kernel(const int* __restrict__ src_c, const int* __restrict__ dst_c,
                             int* __restrict__ cur_c, int* __restrict__ csr_c,
                             const int* __restrict__ src_h, const int* __restrict__ dst_h,
                             int* __restrict__ cur_h, int* __restrict__ csr_h) {
    int i = blockIdx.x * 256 + threadIdx.x;
    if (i < ECi) {
        int d = dst_c[i];
        if ((unsigned)d < (unsigned)NNi) {
            int p = atomicAdd(&cur_c[d], 1);
            if ((unsigned)p < (unsigned)ECi) csr_c[p] = src_c[i];
        }
    } else {
        int j = i - ECi;
        if (j < EHi) {
            int d = dst_h[j];
            if ((unsigned)d < (unsigned)NNi) {
                int p = atomicAdd(&cur_h[d], 1);
                if ((unsigned)p < (unsigned)EHi) csr_h[p] = src_h[j];
            }
        }
    }
}

// all 11 small conversions in one launch (grid.y = job id)
struct CvtJobs { const void* src[11]; u16* dst[11]; int n[11]; };

__global__ void cvt_all_kernel(CvtJobs j, const int* __restrict__ flag) {
    int job = blockIdx.y;
    int i = blockIdx.x * 256 + threadIdx.x;
    if (i >= j.n[job]) return;
    const void* s = j.src[job];
    j.dst[job][i] = flag[0] ? ((const u16*)s)[i] : f2b(((const float*)s)[i]);
}

// ---------------- transposes ----------------
__device__ __forceinline__ void tin_body(const void* in, size_t ioff, u16* outp, int R, int C,
                                         int isb, int c0, int r0, u16 (*tile)[33]) {
    const u16* inb = (const u16*)in + ioff;
    const float* inf_ = (const float*)in + ioff;
    int tx = threadIdx.x, ty = threadIdx.y;  // block (32,8)
#pragma unroll
    for (int i = 0; i < 4; i++) {
        int r = r0 + ty + i * 8, c = c0 + tx;
        if (r < R && c < C) {
            size_t idx = (size_t)r * C + c;
            tile[ty + i * 8][tx] = isb ? inb[idx] : f2b(inf_[idx]);
        }
    }
    __syncthreads();
#pragma unroll
    for (int i = 0; i < 4; i++) {
        int c = c0 + ty + i * 8, r = r0 + tx;
        if (c < C && r < R) outp[(size_t)c * R + r] = tile[tx][ty + i * 8];
    }
}

__global__ void transpose_in3(const void* __restrict__ c3, const void* __restrict__ c4,
                              const void* __restrict__ c5, u16* __restrict__ Xt3,
                              u16* __restrict__ Xt4, u16* __restrict__ Xt5,
                              const int* __restrict__ flag) {
    __shared__ u16 tile[32][33];
    int bx = blockIdx.x;
    const void* in; u16* outb; int R, C, xb;
    if (bx < 200)      { in = c3; outb = Xt3; R = 256; C = 6400; xb = bx; }
    else if (bx < 250) { in = c4; outb = Xt4; R = 512; C = 1600; xb = bx - 200; }
    else               { in = c5; outb = Xt5; R = 512; C = 400;  xb = bx - 250; }
    int r0 = blockIdx.y * 32;
    if (r0 >= R) return;
    size_t boff = (size_t)blockIdx.z * R * C;
    tin_body(in, boff, outb + boff, R, C, flag[0], xb * 32, r0, tile);
}

__global__ void transpose_w(const void* __restrict__ Wc, const void* __restrict__ Wh,
                            u16* __restrict__ WtG, const int* __restrict__ flag) {
    __shared__ u16 tile[32][33];
    int z = blockIdx.z;
    const void* in = (z < 6) ? Wc : Wh;
    int zi = (z < 6) ? z : z - 6;
    tin_body(in, (size_t)zi * 65536, WtG + (size_t)z * 65536, 256, 256, flag[0],
             blockIdx.x * 32, blockIdx.y * 32, tile);
}

__global__ void transpose_out3(const u16* __restrict__ OutT, void* __restrict__ outv,
                               const int* __restrict__ flag) {
    __shared__ u16 tile[32][33];
    int by = blockIdx.y;
    const u16* inb; size_t out_off; int R, yb;
    if (by < 200)      { inb = OutT; out_off = 0; R = 6400; yb = by; }
    else if (by < 250) { inb = OutT + (size_t)N3i * 256; out_off = (size_t)4 * 256 * 6400; R = 1600; yb = by - 200; }
    else               { inb = OutT + (size_t)(N3i + N4i) * 256; out_off = (size_t)4 * 256 * 8000; R = 400; yb = by - 250; }
    int r0 = yb * 32;
    if (r0 >= R) return;
    const int C = 256;
    int isb = flag[0];
    int c0 = blockIdx.x * 32;
    size_t boff = (size_t)blockIdx.z * R * C;
    const u16* inp = inb + boff;
    int tx = threadIdx.x, ty = threadIdx.y;
#pragma unroll
    for (int i = 0; i < 4; i++) {
        int r = r0 + ty + i * 8, c = c0 + tx;
        if (r < R && c < C) tile[ty + i * 8][tx] = inp[(size_t)r * C + c];
    }
    __syncthreads();
#pragma unroll
    for (int i = 0; i < 4; i++) {
        int c = c0 + ty + i * 8, r = r0 + tx;
        if (c < C && r < R) {
            size_t o = out_off + boff + (size_t)c * R + r;
            u16 v = tile[tx][ty + i * 8];
            if (isb) ((u16*)outv)[o] = v;
            else ((float*)outv)[o] = b2f(v);
        }
    }
}

// conv weight transform for all 3 levels: wt[n][tap*256+ci] = w[n][ci*9+tap]
__global__ void convw3_kernel(const void* __restrict__ w0, const void* __restrict__ w1,
                              const void* __restrict__ w2, u16* __restrict__ WtC,
                              const int* __restrict__ flag) {
    int lvl = blockIdx.y;
    const void* w = (lvl == 0) ? w0 : (lvl == 1) ? w1 : w2;
    u16* wt = WtC + (size_t)lvl * 256 * 2304;
    int i = blockIdx.x * 256 + threadIdx.x;
    if (i >= 256 * 2304) return;
    int n = i / 2304;
    int k = i - n * 2304;
    int tap = k >> 8, ci = k & 255;
    int si = n * 2304 + ci * 9 + tap;
    wt[i] = flag[0] ? ((const u16*)w)[si] : f2b(((const float*)w)[si]);
}

// ---------------- GNN gather: T = bf16(H + segsum(H[src]) * invdeg) ----------------
// Half-wave (32 lanes x 16B) owns one FULL node row; 32 edge indices prefetched in one
// coalesced load and shfl-broadcast; 4/2/1 row-load batches with dual accumulators.
// XCD-chunked block remap (grid 4200 = 8*525, bijective): each XCD owns a contiguous
// 4200-node band whose H-slice (~2.2MB + lattice halo) fits its 4MB L2 -- same
// mechanism that cut conv FETCH 7.5x in round 6.
__global__ __launch_bounds__(256) void gather_kernel(
    const u16* __restrict__ H, const int* __restrict__ csr, const int* __restrict__ rs,
    const float* __restrict__ invdeg, u16* __restrict__ T, int ecap) {
    int bid = blockIdx.x;                       // 4200 blocks
    int nb = (bid & 7) * 525 + (bid >> 3);      // XCD-chunked remap
    int node = nb * 8 + (threadIdx.x >> 5);
    if (node >= NNi) return;
    int L = threadIdx.x & 31;
    int c = L * 8;
    int e0 = rs[node], e1 = rs[node + 1];
    e0 = e0 < 0 ? 0 : e0;
    e1 = e1 > ecap ? ecap : e1;
    u16x8 self = *(const u16x8*)(H + (size_t)node * 256 + c);  // issued early
    float a0 = 0.f, a1 = 0.f, a2 = 0.f, a3 = 0.f, a4 = 0.f, a5 = 0.f, a6 = 0.f, a7 = 0.f;
    float b0 = 0.f, b1 = 0.f, b2 = 0.f, b3 = 0.f, b4 = 0.f, b5 = 0.f, b6 = 0.f, b7 = 0.f;
    for (int base = e0; base < e1; base += 32) {
        int ee = base + L;
        int iv = 0;
        if (ee < e1) {
            iv = csr[ee];                     // one coalesced 128B load per half-wave
            iv = ((unsigned)iv < (unsigned)NNi) ? iv : 0;
        }
        int cnt = e1 - base;
        cnt = cnt > 32 ? 32 : cnt;
        int k = 0;
        for (; k + 3 < cnt; k += 4) {         // 4 row loads in flight
            int j0 = __shfl(iv, k, 32), j1 = __shfl(iv, k + 1, 32);
            int j2 = __shfl(iv, k + 2, 32), j3 = __shfl(iv, k + 3, 32);
            u16x8 h0 = *(const u16x8*)(H + (size_t)j0 * 256 + c);
            u16x8 h1 = *(const u16x8*)(H + (size_t)j1 * 256 + c);
            u16x8 h2 = *(const u16x8*)(H + (size_t)j2 * 256 + c);
            u16x8 h3 = *(const u16x8*)(H + (size_t)j3 * 256 + c);
            a0 += b2f(h0[0]); a1 += b2f(h0[1]); a2 += b2f(h0[2]); a3 += b2f(h0[3]);
            a4 += b2f(h0[4]); a5 += b2f(h0[5]); a6 += b2f(h0[6]); a7 += b2f(h0[7]);
            b0 += b2f(h1[0]); b1 += b2f(h1[1]); b2 += b2f(h1[2]); b3 += b2f(h1[3]);
            b4 += b2f(h1[4]); b5 += b2f(h1[5]); b6 += b2f(h1[6]); b7 += b2f(h1[7]);
            a0 += b2f(h2[0]); a1 += b2f(h2[1]); a2 += b2f(h2[2]); a3 += b2f(h2[3]);
            a4 += b2f(h2[4]); a5 += b2f(h2[5]); a6 += b2f(h2[6]); a7 += b2f(h2[7]);
            b0 += b2f(h3[0]); b1 += b2f(h3[1]); b2 += b2f(h3[2]); b3 += b2f(h3[3]);
            b4 += b2f(h3[4]); b5 += b2f(h3[5]); b6 += b2f(h3[6]); b7 += b2f(h3[7]);
        }
        if (k + 1 < cnt) {                    // 2 in flight
            int j0 = __shfl(iv, k, 32), j1 = __shfl(iv, k + 1, 32);
            u16x8 h0 = *(const u16x8*)(H + (size_t)j0 * 256 + c);
            u16x8 h1 = *(const u16x8*)(H + (size_t)j1 * 256 + c);
            a0 += b2f(h0[0]); a1 += b2f(h0[1]); a2 += b2f(h0[2]); a3 += b2f(h0[3]);
            a4 += b2f(h0[4]); a5 += b2f(h0[5]); a6 += b2f(h0[6]); a7 += b2f(h0[7]);
            b0 += b2f(h1[0]); b1 += b2f(h1[1]); b2 += b2f(h1[2]); b3 += b2f(h1[3]);
            b4 += b2f(h1[4]); b5 += b2f(h1[5]); b6 += b2f(h1[6]); b7 += b2f(h1[7]);
            k += 2;
        }
        if (k < cnt) {
            int j0 = __shfl(iv, k, 32);
            u16x8 h0 = *(const u16x8*)(H + (size_t)j0 * 256 + c);
            a0 += b2f(h0[0]); a1 += b2f(h0[1]); a2 += b2f(h0[2]); a3 += b2f(h0[3]);
            a4 += b2f(h0[4]); a5 += b2f(h0[5]); a6 += b2f(h0[6]); a7 += b2f(h0[7]);
        }
    }
    a0 += b0; a1 += b1; a2 += b2; a3 += b3; a4 += b4; a5 += b5; a6 += b6; a7 += b7;
    float inv = invdeg[node];
    u16x8 o;
    o[0] = f2b(b2f(self[0]) + a0 * inv); o[1] = f2b(b2f(self[1]) + a1 * inv);
    o[2] = f2b(b2f(self[2]) + a2 * inv); o[3] = f2b(b2f(self[3]) + a3 * inv);
    o[4] = f2b(b2f(self[4]) + a4 * inv); o[5] = f2b(b2f(self[5]) + a5 * inv);
    o[6] = f2b(b2f(self[6]) + a6 * inv); o[7] = f2b(b2f(self[7]) + a7 * inv);
    *(u16x8*)(T + (size_t)node * 256 + c) = o;
}

// ---------------- MFMA GEMM body (round-2 proven): gll + 2-buffer, 1 drain/K-step ----
// Chunk XOR-swizzle on BOTH global source and ds_read address (rule #21) -> conflict-free.
template <bool CONV, bool RELU>
__device__ __forceinline__ void gemm_body(
    u16 (* __restrict__ lds)[4096],
    const u16* __restrict__ A, int lda,
    const u16* __restrict__ Bt, int ldb,
    const u16* __restrict__ bias,
    const u16* __restrict__ zp,
    u16* __restrict__ out, u16* __restrict__ out2,
    int M, int K, int H, int W, int m0, int n0) {
    int t = threadIdx.x;
    int w = t >> 6, lane = t & 63;
    int wm = w & 1, wn = w >> 1;
    f32x4 acc[4][4] = {};

    int g0 = w * 128 + lane;
    int g1 = g0 + 64;
    int row0 = g0 >> 2, c0 = g0 & 3;
    int row1 = g1 >> 2, c1 = g1 & 3;
    int ss0 = ((c0 ^ ((row0 >> 1) & 3)) << 3);
    int ss1 = ((c1 ^ ((row1 >> 1) & 3)) << 3);

    int ar0 = m0 + row0, ar1 = m0 + row1;
    bool aok0 = ar0 < M, aok1 = ar1 < M;
    int y0_ = 0, x0_ = 0, y1_ = 0, x1_ = 0;
    if (CONV) {
        int HW = H * W;
        if (aok0) { int b = ar0 / HW; int rem = ar0 - b * HW; y0_ = rem / W; x0_ = rem - y0_ * W; }
        if (aok1) { int b = ar1 / HW; int rem = ar1 - b * HW; y1_ = rem / W; x1_ = rem - y1_ * W; }
    }
    const u16* aP0 = A + (size_t)ar0 * lda + ss0;
    const u16* aP1 = A + (size_t)ar1 * lda + ss1;
    const u16* bP0 = Bt + (size_t)(n0 + row0) * ldb + ss0;
    const u16* bP1 = Bt + (size_t)(n0 + row1) * ldb + ss1;

    int lbase = w * 1024;

    auto stage = [&](int bf, int k0) {
        u16* LA = lds[bf * 2];
        u16* LB = lds[bf * 2 + 1];
        const u16* sa0;
        const u16* sa1;
        if (!CONV) {
            sa0 = aok0 ? aP0 + k0 : zp;
            sa1 = aok1 ? aP1 + k0 : zp;
        } else {
            int tap = k0 >> 8;
            int t3 = tap / 3;
            int dy = t3 - 1, dx = tap - t3 * 3 - 1;
            int off = (dy * W + dx) * lda + (k0 & 255);
            int yy0 = y0_ + dy, xx0 = x0_ + dx;
            int yy1 = y1_ + dy, xx1 = x1_ + dx;
            sa0 = (aok0 && (unsigned)yy0 < (unsigned)H && (unsigned)xx0 < (unsigned)W) ? aP0 + off : zp;
            sa1 = (aok1 && (unsigned)yy1 < (unsigned)H && (unsigned)xx1 < (unsigned)W) ? aP1 + off : zp;
        }
        gll16(sa0, LA + lbase);
        gll16(sa1, LA + lbase + 512);
        gll16(bP0 + k0, LB + lbase);
        gll16(bP1 + k0, LB + lbase + 512);
    };

    int nst = K >> 5;
    int fm = lane & 15;
    int co = (((lane >> 4) ^ ((fm >> 1) & 3)) << 3);

    stage(0, 0);
    __syncthreads();  // implicit vmcnt(0) drain -> buf0 ready
    for (int s = 0; s < nst; s++) {
        int bf = s & 1;
        if (s + 1 < nst) stage(bf ^ 1, (s + 1) << 5);  // in flight during compute
        const u16* LA = lds[bf * 2];
        const u16* LB = lds[bf * 2 + 1];
        bf16x8 af[4], bfv[4];
#pragma unroll
        for (int i = 0; i < 4; i++) af[i] = *(const bf16x8*)&LA[(wm * 64 + i * 16 + fm) * 32 + co];
#pragma unroll
        for (int j = 0; j < 4; j++) bfv[j] = *(const bf16x8*)&LB[(wn * 64 + j * 16 + fm) * 32 + co];
#pragma unroll
        for (int i = 0; i < 4; i++)
#pragma unroll
            for (int j = 0; j < 4; j++)
                acc[i][j] = __builtin_amdgcn_mfma_f32_16x16x32_bf16(af[i], bfv[j], acc[i][j], 0, 0, 0);
        __syncthreads();  // drains stage loads (next buf ready) + guards buf reuse
    }

    int q = lane >> 4, nl = lane & 15;
#pragma unroll
    for (int j = 0; j < 4; j++) {
        int n = n0 + wn * 64 + j * 16 + nl;
        float bv = b2f(bias[n]);
#pragma unroll
        for (int i = 0; i < 4; i++) {
            int mbase = m0 + wm * 64 + i * 16 + q * 4;
#pragma unroll
            for (int rg = 0; rg < 4; rg++) {
                int m = mbase + rg;
                if (m < M) {
                    float v = acc[i][j][rg] + bv;
                    if (RELU) v = fmaxf(v, 0.f);
                    u16 bs = f2b(v);
                    out[(size_t)m * 256 + n] = bs;
                    if (out2) out2[(size_t)m * 256 + n] = bs;
                }
            }
        }
    }
}

// generic wrapper (GNN layers), 528-block 1-D grid with XCD pair affinity
template <bool CONV, bool RELU>
__global__ __launch_bounds__(256) void gemm_kernel(
    const u16* __restrict__ A, int lda,
    const u16* __restrict__ Bt, int ldb,
    const u16* __restrict__ bias,
    const u16* __restrict__ zp,
    u16* __restrict__ out, u16* __restrict__ out2,
    int M, int K, int H, int W) {
    __shared__ __align__(16) u16 lds[4][4096];
    int p, x;
    if (!xcd_pair_decode(blockIdx.x, p, x)) return;
    gemm_body<CONV, RELU>(lds, A, lda, Bt, ldb, bias, zp, out, out2, M, K, H, W,
                          p * 128, x * 128);
}

// all 3 lateral 1x1 GEMMs, one launch; p-range selects level (K differs per level)
__global__ __launch_bounds__(256) void lat_all_kernel(
    const u16* __restrict__ Xt3, const u16* __restrict__ Xt4, const u16* __restrict__ Xt5,
    const u16* __restrict__ W1, const u16* __restrict__ BB, const u16* __restrict__ zp,
    u16* __restrict__ P, u16* __restrict__ Ha) {
    __shared__ __align__(16) u16 lds[4][4096];
    int p, x;
    if (!xcd_pair_decode(blockIdx.x, p, x)) return;
    const u16* A; const u16* Bt; const u16* bias;
    int K, Ml, m0; size_t off;
    if (p < 200)      { A = Xt3; Bt = W1;          bias = BB;       K = 256; Ml = N3i; off = 0;                          m0 = p * 128; }
    else if (p < 250) { A = Xt4; Bt = W1 + 65536;  bias = BB + 256; K = 512; Ml = N4i; off = (size_t)N3i * 256;          m0 = (p - 200) * 128; }
    else              { A = Xt5; Bt = W1 + 196608; bias = BB + 512; K = 512; Ml = N5i; off = (size_t)(N3i + N4i) * 256;  m0 = (p - 250) * 128; }
    gemm_body<false, false>(lds, A, K, Bt, K, bias, zp, P + off, Ha + off, Ml, K, 0, 0,
                            m0, x * 128);
}

// all 3 output 3x3 convs, one launch (526 equal-cost blocks, XCD pair affinity)
__global__ __launch_bounds__(256) void conv_gemm_all(
    const u16* __restrict__ Pc, const u16* __restrict__ WtC,
    const u16* __restrict__ BB, const u16* __restrict__ zp, u16* __restrict__ OutT) {
    __shared__ __align__(16) u16 lds[4][4096];
    int p, x;
    if (!xcd_pair_decode(blockIdx.x, p, x)) return;
    int lvl, yl, Hd, Ml; size_t base;
    if (p < 200)      { lvl = 0; yl = p;       Hd = 80; Ml = N3i; base = 0; }
    else if (p < 250) { lvl = 1; yl = p - 200; Hd = 40; Ml = N4i; base = (size_t)N3i * 256; }
    else              { lvl = 2; yl = p - 250; Hd = 20; Ml = N5i; base = (size_t)(N3i + N4i) * 256; }
    gemm_body<true, false>(lds, Pc + base, 256, WtC + (size_t)lvl * 256 * 2304, 2304,
                           BB + 3072 + lvl * 256, zp, OutT + base, nullptr,
                           Ml, 2304, Hd, Hd, yl * 128, x * 128);
}

// ---------------- fused pyramid composition: Pc = compose(P, Hf) ----------------
__global__ void pyr_kernel(const u16* __restrict__ P, const u16* __restrict__ Hf,
                           u16* __restrict__ Pc) {
    int i = blockIdx.x * 256 + threadIdx.x;
    if (i >= NNi * 64) return;
    int node = i >> 6, c = (i & 63) * 4;
    size_t bi = (size_t)node * 256 + c;
    ushort4 pv = *(const ushort4*)(P + bi);
    ushort4 hv = *(const ushort4*)(Hf + bi);
    float v0 = b2f(pv.x) + b2f(hv.x);
    float v1 = b2f(pv.y) + b2f(hv.y);
    float v2 = b2f(pv.z) + b2f(hv.z);
    float v3 = b2f(pv.w) + b2f(hv.w);
    if (node < N3i) {
        int b = node / 6400, rem = node - b * 6400;
        int y = rem / 80, x = rem - y * 80;
        size_t s4 = ((size_t)N3i + b * 1600 + (y >> 1) * 40 + (x >> 1)) * 256 + c;
        size_t s5 = ((size_t)(N3i + N4i) + b * 400 + (y >> 2) * 20 + (x >> 2)) * 256 + c;
        ushort4 p4 = *(const ushort4*)(P + s4), h4 = *(const ushort4*)(Hf + s4);
        ushort4 p5 = *(const ushort4*)(P + s5), h5 = *(const ushort4*)(Hf + s5);
        v0 += b2f(p4.x) + b2f(h4.x) + b2f(p5.x) + b2f(h5.x);
        v1 += b2f(p4.y) + b2f(h4.y) + b2f(p5.y) + b2f(h5.y);
        v2 += b2f(p4.z) + b2f(h4.z) + b2f(p5.z) + b2f(h5.z);
        v3 += b2f(p4.w) + b2f(h4.w) + b2f(p5.w) + b2f(h5.w);
    } else if (node < N3i + N4i) {
        int n4 = node - N3i;
        int b = n4 / 1600, rem = n4 - b * 1600;
        int y = rem / 40, x = rem - y * 40;
        size_t s5 = ((size_t)(N3i + N4i) + b * 400 + (y >> 1) * 20 + (x >> 1)) * 256 + c;
        ushort4 p5 = *(const ushort4*)(P + s5), h5 = *(const ushort4*)(Hf + s5);
        v0 += b2f(p5.x) + b2f(h5.x);
        v1 += b2f(p5.y) + b2f(h5.y);
        v2 += b2f(p5.z) + b2f(h5.z);
        v3 += b2f(p5.w) + b2f(h5.w);
    }
    ushort4 o;
    o.x = f2b(v0); o.y = f2b(v1); o.z = f2b(v2); o.w = f2b(v3);
    *(ushort4*)(Pc + bi) = o;
}

// ---------------- host ----------------
extern "C" void kernel_launch(void* const* d_in, const int* in_sizes, int n_in,
                              void* d_out, int out_size, void* d_ws, size_t ws_size,
                              hipStream_t stream) {
    (void)in_sizes; (void)n_in; (void)out_size; (void)ws_size;
    const void* c3 = d_in[0];
    const void* c4 = d_in[1];
    const void* c5 = d_in[2];
    const void* w3_1 = d_in[3];
    const void* b3_1 = d_in[4];
    const void* w4_1 = d_in[5];
    const void* b4_1 = d_in[6];
    const void* w5_1 = d_in[7];
    const void* b5_1 = d_in[8];
    const void* w3_3 = d_in[9];
    const void* b3_3 = d_in[10];
    const void* w4_3 = d_in[11];
    const void* b4_3 = d_in[12];
    const void* w5_3 = d_in[13];
    const void* b5_3 = d_in[14];
    const void* Wc = d_in[15];
    const void* bc = d_in[16];
    const void* Wh = d_in[17];
    const void* bh = d_in[18];
    const int* src_c = (const int*)d_in[19];
    const int* dst_c = (const int*)d_in[20];
    const int* src_h = (const int*)d_in[21];
    const int* dst_h = (const int*)d_in[22];

    char* w = (char*)d_ws;
    auto alloc = [&](size_t bytes) -> void* {
        void* p = (void*)w;
        w += (bytes + 255) & ~(size_t)255;
        return p;
    };
    u16* XT  = (u16*)alloc(((size_t)N3i * 256 + (size_t)N4i * 512 + (size_t)N5i * 512) * 2);
    u16* Xt3 = XT;
    u16* Xt4 = XT + (size_t)N3i * 256;
    u16* Xt5 = Xt4 + (size_t)N4i * 512;
    u16* T   = XT;                          // alias (17.2 MB <= 21.3 MB region)
    u16* Pc  = XT;                          // pyramid output aliases T (free after GNN)
    u16* WtC = XT + (size_t)NNi * 256;      // alias, starts right after T (3.54 MB fits)
    u16* WtG = (u16*)alloc((size_t)9 * 65536 * 2);
    u16* W1  = (u16*)alloc((size_t)(65536 + 131072 + 131072) * 2);
    u16* BB  = (u16*)alloc((size_t)3840 * 2);
    u16* P   = (u16*)alloc((size_t)NNi * 256 * 2);
    u16* Ha  = (u16*)alloc((size_t)NNi * 256 * 2);
    u16* Hb  = (u16*)d_out;                 // alias d_out as scratch
    int* csr_c = (int*)alloc((size_t)ECi * 4);
    int* csr_h = (int*)alloc((size_t)EHi * 4);
    int* cnt2  = (int*)alloc((size_t)2 * NNi * 4);
    int* cnt_c = cnt2;
    int* cnt_h = cnt2 + NNi;
    int* rs_c  = (int*)alloc((size_t)(NNi + 1) * 4);
    int* rs_h  = (int*)alloc((size_t)(NNi + 1) * 4);
    int* cur_c = (int*)alloc((size_t)NNi * 4);
    int* cur_h = (int*)alloc((size_t)NNi * 4);
    float* inv_c = (float*)alloc((size_t)NNi * 4);
    float* inv_h = (float*)alloc((size_t)NNi * 4);
    int* ps_c  = (int*)alloc((size_t)NNi * 4);   // scan partials
    int* ps_h  = (int*)alloc((size_t)NNi * 4);
    int* bsum  = (int*)alloc((size_t)132 * 4);
    int* flag  = (int*)alloc(256);
    u16* zp    = (u16*)alloc(256);          // zero page for masked GEMM staging

    // ---- dtype detection + zero-pad init ----
    detect_kernel<<<1, 64, 0, stream>>>(c3, flag, (uint32_t*)zp);

    // ---- CSR build (3-pass parallel scan) ----
    zero_i32<<<(2 * NNi + 255) / 256, 256, 0, stream>>>(cnt2, 2 * NNi);
    hist2_kernel<<<(ECi + EHi + 255) / 256, 256, 0, stream>>>(dst_c, dst_h, cnt_c, cnt_h);
    scan_part<<<132, 256, 0, stream>>>(cnt_c, cnt_h, ps_c, ps_h, bsum);
    scan_sums<<<1, 256, 0, stream>>>(bsum);
    scan_final<<<132, 256, 0, stream>>>(ps_c, ps_h, bsum, cnt_c, cnt_h,
                                        rs_c, cur_c, inv_c, rs_h, cur_h, inv_h);
    fill2_kernel<<<(ECi + EHi + 255) / 256, 256, 0, stream>>>(
        src_c, dst_c, cur_c, csr_c, src_h, dst_h, cur_h, csr_h);

    // ---- convert small tensors (one launch) ----
    CvtJobs cj;
    cj.src[0] = w3_1; cj.dst[0] = W1;          cj.n[0] = 65536;
    cj.src[1] = w4_1; cj.dst[1] = W1 + 65536;  cj.n[1] = 131072;
    cj.src[2] = w5_1; cj.dst[2] = W1 + 196608; cj.n[2] = 131072;
    cj.src[3] = b3_1; cj.dst[3] = BB;          cj.n[3] = 256;
    cj.src[4] = b4_1; cj.dst[4] = BB + 256;    cj.n[4] = 256;
    cj.src[5] = b5_1; cj.dst[5] = BB + 512;    cj.n[5] = 256;
    cj.src[6] = bc;   cj.dst[6] = BB + 768;    cj.n[6] = 1536;
    cj.src[7] = bh;   cj.dst[7] = BB + 2304;   cj.n[7] = 768;
    cj.src[8] = b3_3; cj.dst[8] = BB + 3072;   cj.n[8] = 256;
    cj.src[9] = b4_3; cj.dst[9] = BB + 3328;   cj.n[9] = 256;
    cj.src[10] = b5_3; cj.dst[10] = BB + 3584; cj.n[10] = 256;
    cvt_all_kernel<<<dim3(512, 11), 256, 0, stream>>>(cj, flag);

    // ---- input transposes + GNN weight transposes ----
    transpose_in3<<<dim3(263, 16, 4), dim3(32, 8), 0, stream>>>(c3, c4, c5, Xt3, Xt4, Xt5, flag);
    transpose_w<<<dim3(8, 8, 9), dim3(32, 8), 0, stream>>>(Wc, Wh, WtG, flag);

    // ---- lateral 1x1 convs -> P (and H0 = Ha), one launch ----
    lat_all_kernel<<<528, 256, 0, stream>>>(Xt3, Xt4, Xt5, W1, BB, zp, P, Ha);

    // ---- conv weights AFTER laterals (WtC aliases Xt4/Xt5 tail) ----
    convw3_kernel<<<dim3(2304, 3), 256, 0, stream>>>(w3_3, w4_3, w5_3, WtC, flag);

    // ---- 9 GNN layers ----
    u16* Hcur = Ha;
    u16* Hnxt = Hb;
    for (int l = 0; l < 9; l++) {
        bool ctx = (l < 3) || (l >= 6);
        const int* csr = ctx ? csr_c : csr_h;
        const int* rs = ctx ? rs_c : rs_h;
        const float* inv = ctx ? inv_c : inv_h;
        int ecap = ctx ? ECi : EHi;
        int wi = (l < 3) ? l : (l < 6 ? 6 + (l - 3) : l - 3);
        const u16* bias = (l < 3) ? BB + 768 + l * 256
                        : (l < 6 ? BB + 2304 + (l - 3) * 256 : BB + 768 + (l - 3) * 256);
        gather_kernel<<<NNi / 8, 256, 0, stream>>>(Hcur, csr, rs, inv, T, ecap);
        gemm_kernel<false, true><<<528, 256, 0, stream>>>(
            T, 256, WtG + (size_t)wi * 65536, 256, bias, zp, Hnxt, nullptr, NNi, 256, 0, 0);
        u16* tmp = Hcur; Hcur = Hnxt; Hnxt = tmp;
    }
    u16* OutT = Hnxt;  // = Ha

    // ---- fused pyramid composition -> Pc ----
    pyr_kernel<<<(NNi * 64 + 255) / 256, 256, 0, stream>>>(P, Hcur, Pc);

    // ---- 3x3 convs (9-tap gathered GEMM), one launch ----
    conv_gemm_all<<<528, 256, 0, stream>>>(Pc, WtC, BB, zp, OutT);

    // ---- node-major -> NCHW output (one launch) ----
    transpose_out3<<<dim3(8, 263, 4), dim3(32, 8), 0, stream>>>(OutT, d_out, flag);
}

// Round 8
// 621.552 us; speedup vs baseline: 1.7022x; 1.0020x over previous
//
#include <hip/hip_runtime.h>
#include <stdint.h>

#define N3i 25600
#define N4i 6400
#define N5i 1600
#define NNi 33600
#define ECi 260000
#define EHi 120000

typedef unsigned short u16;
typedef __bf16 bf16x8 __attribute__((ext_vector_type(8)));
typedef float f32x4 __attribute__((ext_vector_type(4)));
typedef unsigned short u16x8 __attribute__((ext_vector_type(8)));

__device__ __forceinline__ float b2f(u16 u) {
    union { float f; uint32_t i; } v; v.i = ((uint32_t)u) << 16; return v.f;
}
__device__ __forceinline__ u16 f2b(float f) {
    union { float f; uint32_t i; } v; v.f = f;
    uint32_t x = v.i;
    uint32_t r = (x + 0x7FFFu + ((x >> 16) & 1u)) >> 16;  // RNE
    return (u16)r;
}

// async global->LDS, 16B per lane. LDS dest must be wave-uniform base (+lane*16 by HW);
// global source is per-lane (rule #21: swizzle via source address, keep LDS linear).
__device__ __forceinline__ void gll16(const u16* g, u16* l) {
    __builtin_amdgcn_global_load_lds((const __attribute__((address_space(1))) void*)g,
                                     (__attribute__((address_space(3))) void*)l, 16, 0, 0);
}

// XCD pair-affinity decode: 528-block 1-D grid -> (p: row-tile 0..262, x: col-half 0..1)
// with both members of a pair on the SAME XCD (xcd = bid % 8 round-robin -- CONFIRMED
// round 6: conv FETCH 110MB -> 14.5MB). Pair members are 8 ids apart; each XCD owns a
// contiguous band of row-tiles (tap-overlap locality).
__device__ __forceinline__ bool xcd_pair_decode(int pid, int& p, int& x) {
    int g = pid & 7;
    int s = pid >> 3;
    x = s & 1;
    p = g * 33 + (s >> 1);
    return p < 263;
}

// ---------------- dtype detection: flag=1 if inputs are bf16, 0 if fp32 ----------------
// also zeroes the 512B zero-row used by masked GEMM staging and gather dead-loads
__global__ void detect_kernel(const void* __restrict__ c3raw, int* __restrict__ flag,
                              uint32_t* __restrict__ zp) {
    const uint32_t* p = (const uint32_t*)c3raw;
    int t = threadIdx.x;
    zp[t] = 0;           // 128 * 4B = 512B zero row (one full bf16 feature row)
    zp[t + 64] = 0;
    int vote = 0;
    for (int i = t; i < 256; i += 64) {
        uint32_t w = p[i];
        uint32_t lo = w & 0xFFFFu;
        uint32_t e = (lo >> 7) & 0xFFu;
        if (lo == 0u || (e >= 100u && e <= 127u)) vote++;
    }
#pragma unroll
    for (int d = 32; d >= 1; d >>= 1) vote += __shfl_down(vote, d, 64);
    if (t == 0) flag[0] = (vote >= 192) ? 1 : 0;
}

// ---------------- utility kernels ----------------
__global__ void zero_i32(int* p, int n) {
    int i = blockIdx.x * 256 + threadIdx.x;
    if (i < n) p[i] = 0;
}

__global__ void hist2_kernel(const int* __restrict__ dst_c, const int* __restrict__ dst_h,
                             int* __restrict__ cnt_c, int* __restrict__ cnt_h) {
    int i = blockIdx.x * 256 + threadIdx.x;
    if (i < ECi) {
        int d = dst_c[i];
        if ((unsigned)d < (unsigned)NNi) atomicAdd(&cnt_c[d], 1);
    } else {
        int j = i - ECi;
        if (j < EHi) {
            int d = dst_h[j];
            if ((unsigned)d < (unsigned)NNi) atomicAdd(&cnt_h[d], 1);
        }
    }
}

// ---------------- 3-pass parallel scan ----------------
__global__ __launch_bounds__(256) void scan_part(
    const int* __restrict__ cnt_c, const int* __restrict__ cnt_h,
    int* __restrict__ ps_c, int* __restrict__ ps_h, int* __restrict__ bsum) {
    int b = blockIdx.x;
    bool hier = b >= 66;
    const int* cnt = hier ? cnt_h : cnt_c;
    int* ps = hier ? ps_h : ps_c;
    int base = (hier ? b - 66 : b) * 512;
    int t = threadIdx.x, lane = t & 63, wid = t >> 6;
    int i0 = base + 2 * t;
    int v0 = (i0 < NNi) ? cnt[i0] : 0;
    int v1 = (i0 + 1 < NNi) ? cnt[i0 + 1] : 0;
    int s = v0 + v1;
    int x = s;
#pragma unroll
    for (int d = 1; d < 64; d <<= 1) {
        int y = __shfl_up(x, d, 64);
        if (lane >= d) x += y;
    }
    __shared__ int ws[4];
    if (lane == 63) ws[wid] = x;
    __syncthreads();
    int w0 = ws[0], w1 = ws[1], w2 = ws[2], w3 = ws[3];
    int woff = (wid == 1) ? w0 : (wid == 2) ? (w0 + w1) : (wid == 3) ? (w0 + w1 + w2) : 0;
    int incl = x + woff;
    int excl = incl - s;
    if (i0 < NNi) ps[i0] = excl + v0;
    if (i0 + 1 < NNi) ps[i0 + 1] = excl + v0 + v1;
    if (t == 0) bsum[b] = w0 + w1 + w2 + w3;
}

__global__ __launch_bounds__(256) void scan_sums(int* __restrict__ bsum) {
    __shared__ int s[132];
    int t = threadIdx.x;
    int orig = 0;
    if (t < 132) { orig = bsum[t]; s[t] = orig; }
    __syncthreads();
    for (int d = 1; d < 66; d <<= 1) {
        int v = 0;
        if (t < 132) {
            int seg = (t < 66) ? 0 : 1;
            int loc = t - seg * 66;
            if (loc >= d) v = s[t - d];
        }
        __syncthreads();
        if (t < 132) s[t] += v;
        __syncthreads();
    }
    if (t < 132) bsum[t] = s[t] - orig;  // exclusive segment offset
}

__global__ __launch_bounds__(256) void scan_final(
    const int* __restrict__ ps_c, const int* __restrict__ ps_h, const int* __restrict__ bsum,
    const int* __restrict__ cnt_c, const int* __restrict__ cnt_h,
    int* __restrict__ rs_c, int* __restrict__ cur_c, float* __restrict__ inv_c,
    int* __restrict__ rs_h, int* __restrict__ cur_h, float* __restrict__ inv_h) {
    int b = blockIdx.x;
    bool hier = b >= 66;
    int lb = hier ? b - 66 : b;
    const int* ps = hier ? ps_h : ps_c;
    const int* cnt = hier ? cnt_h : cnt_c;
    int* rs = hier ? rs_h : rs_c;
    int* cur = hier ? cur_h : cur_c;
    float* inv = hier ? inv_h : inv_c;
    int off = bsum[b];
    int t = threadIdx.x;
#pragma unroll
    for (int k = 0; k < 2; k++) {
        int i = lb * 512 + t + k * 256;
        if (i < NNi) {
            int incl = ps[i] + off;
            int v = cnt[i];
            rs[i + 1] = incl;
            cur[i] = incl - v;
            inv[i] = 1.0f / (float)(v < 1 ? 1 : v);
        }
    }
    if (b == 0 && t == 0) rs_c[0] = 0;
    if (b == 66 && t == 0) rs_h[0] = 0;
}

__global__ void fill2_kernel(const int* __restrict__ src_c, const int* __restrict__ dst_c,
                             int* __restrict__ cur_c, int* __restrict__ csr_c,
                             const int* __restrict__ src_h, const int* __restrict__ dst_h,
                             int* __restrict__ cur_h, int* __restrict__ csr_h) {
    int i = blockIdx.x * 256 + threadIdx.x;
    if (i < ECi) {
        int d = dst_c[i];
        if ((unsigned)d < (unsigned)NNi) {
            int p = atomicAdd(&cur_c[d], 1);
            if ((unsigned)p < (unsigned)ECi) csr_c[p] = src_c[i];
        }
    } else {
        int j = i - ECi;
        if (j < EHi) {
            int d = dst_h[j];
            if ((unsigned)d < (unsigned)NNi) {
                int p = atomicAdd(&cur_h[d], 1);
                if ((unsigned)p < (unsigned)EHi) csr_h[p] = src_h[j];
            }
        }
    }
}

// all 11 small conversions in one launch (grid.y = job id)
struct CvtJobs { const void* src[11]; u16* dst[11]; int n[11]; };

__global__ void cvt_all_kernel(CvtJobs j, const int* __restrict__ flag) {
    int job = blockIdx.y;
    int i = blockIdx.x * 256 + threadIdx.x;
    if (i >= j.n[job]) return;
    const void* s = j.src[job];
    j.dst[job][i] = flag[0] ? ((const u16*)s)[i] : f2b(((const float*)s)[i]);
}

// ---------------- transposes ----------------
__device__ __forceinline__ void tin_body(const void* in, size_t ioff, u16* outp, int R, int C,
                                         int isb, int c0, int r0, u16 (*tile)[33]) {
    const u16* inb = (const u16*)in + ioff;
    const float* inf_ = (const float*)in + ioff;
    int tx = threadIdx.x, ty = threadIdx.y;  // block (32,8)
#pragma unroll
    for (int i = 0; i < 4; i++) {
        int r = r0 + ty + i * 8, c = c0 + tx;
        if (r < R && c < C) {
            size_t idx = (size_t)r * C + c;
            tile[ty + i * 8][tx] = isb ? inb[idx] : f2b(inf_[idx]);
        }
    }
    __syncthreads();
#pragma unroll
    for (int i = 0; i < 4; i++) {
        int c = c0 + ty + i * 8, r = r0 + tx;
        if (c < C && r < R) outp[(size_t)c * R + r] = tile[tx][ty + i * 8];
    }
}

__global__ void transpose_in3(const void* __restrict__ c3, const void* __restrict__ c4,
                              const void* __restrict__ c5, u16* __restrict__ Xt3,
                              u16* __restrict__ Xt4, u16* __restrict__ Xt5,
                              const int* __restrict__ flag) {
    __shared__ u16 tile[32][33];
    int bx = blockIdx.x;
    const void* in; u16* outb; int R, C, xb;
    if (bx < 200)      { in = c3; outb = Xt3; R = 256; C = 6400; xb = bx; }
    else if (bx < 250) { in = c4; outb = Xt4; R = 512; C = 1600; xb = bx - 200; }
    else               { in = c5; outb = Xt5; R = 512; C = 400;  xb = bx - 250; }
    int r0 = blockIdx.y * 32;
    if (r0 >= R) return;
    size_t boff = (size_t)blockIdx.z * R * C;
    tin_body(in, boff, outb + boff, R, C, flag[0], xb * 32, r0, tile);
}

__global__ void transpose_w(const void* __restrict__ Wc, const void* __restrict__ Wh,
                            u16* __restrict__ WtG, const int* __restrict__ flag) {
    __shared__ u16 tile[32][33];
    int z = blockIdx.z;
    const void* in = (z < 6) ? Wc : Wh;
    int zi = (z < 6) ? z : z - 6;
    tin_body(in, (size_t)zi * 65536, WtG + (size_t)z * 65536, 256, 256, flag[0],
             blockIdx.x * 32, blockIdx.y * 32, tile);
}

__global__ void transpose_out3(const u16* __restrict__ OutT, void* __restrict__ outv,
                               const int* __restrict__ flag) {
    __shared__ u16 tile[32][33];
    int by = blockIdx.y;
    const u16* inb; size_t out_off; int R, yb;
    if (by < 200)      { inb = OutT; out_off = 0; R = 6400; yb = by; }
    else if (by < 250) { inb = OutT + (size_t)N3i * 256; out_off = (size_t)4 * 256 * 6400; R = 1600; yb = by - 200; }
    else               { inb = OutT + (size_t)(N3i + N4i) * 256; out_off = (size_t)4 * 256 * 8000; R = 400; yb = by - 250; }
    int r0 = yb * 32;
    if (r0 >= R) return;
    const int C = 256;
    int isb = flag[0];
    int c0 = blockIdx.x * 32;
    size_t boff = (size_t)blockIdx.z * R * C;
    const u16* inp = inb + boff;
    int tx = threadIdx.x, ty = threadIdx.y;
#pragma unroll
    for (int i = 0; i < 4; i++) {
        int r = r0 + ty + i * 8, c = c0 + tx;
        if (r < R && c < C) tile[ty + i * 8][tx] = inp[(size_t)r * C + c];
    }
    __syncthreads();
#pragma unroll
    for (int i = 0; i < 4; i++) {
        int c = c0 + ty + i * 8, r = r0 + tx;
        if (c < C && r < R) {
            size_t o = out_off + boff + (size_t)c * R + r;
            u16 v = tile[tx][ty + i * 8];
            if (isb) ((u16*)outv)[o] = v;
            else ((float*)outv)[o] = b2f(v);
        }
    }
}

// conv weight transform for all 3 levels: wt[n][tap*256+ci] = w[n][ci*9+tap]
__global__ void convw3_kernel(const void* __restrict__ w0, const void* __restrict__ w1,
                              const void* __restrict__ w2, u16* __restrict__ WtC,
                              const int* __restrict__ flag) {
    int lvl = blockIdx.y;
    const void* w = (lvl == 0) ? w0 : (lvl == 1) ? w1 : w2;
    u16* wt = WtC + (size_t)lvl * 256 * 2304;
    int i = blockIdx.x * 256 + threadIdx.x;
    if (i >= 256 * 2304) return;
    int n = i / 2304;
    int k = i - n * 2304;
    int tap = k >> 8, ci = k & 255;
    int si = n * 2304 + ci * 9 + tap;
    wt[i] = flag[0] ? ((const u16*)w)[si] : f2b(((const float*)w)[si]);
}

// ---------------- GNN gather: T = bf16(H + segsum(H[src]) * invdeg) ----------------
// Half-wave (32 lanes x 16B) owns one FULL node row; 32 edge indices prefetched in one
// coalesced load and shfl-broadcast. NEW: uniform 8-deep load batches -- out-of-range
// slots read a 512B zero row, so every batch issues 8 loads in flight with no 4/2/1
// tail ladder. Degree <= 8 (the common case, mean 7.7) = ONE L2 round-trip instead of
// three sequential. XCD-chunked block remap keeps each XCD's H-slice L2-resident.
__global__ __launch_bounds__(256) void gather_kernel(
    const u16* __restrict__ H, const int* __restrict__ csr, const int* __restrict__ rs,
    const float* __restrict__ invdeg, u16* __restrict__ T, const u16* __restrict__ zp,
    int ecap) {
    int bid = blockIdx.x;                       // 4200 blocks
    int nb = (bid & 7) * 525 + (bid >> 3);      // XCD-chunked remap (4200 = 8*525)
    int node = nb * 8 + (threadIdx.x >> 5);
    if (node >= NNi) return;
    int L = threadIdx.x & 31;
    int c = L * 8;
    int e0 = rs[node], e1 = rs[node + 1];
    e0 = e0 < 0 ? 0 : e0;
    e1 = e1 > ecap ? ecap : e1;
    u16x8 self = *(const u16x8*)(H + (size_t)node * 256 + c);  // issued early
    const u16* zrow = zp + c;                   // zero row slice for dead loads
    float a0 = 0.f, a1 = 0.f, a2 = 0.f, a3 = 0.f, a4 = 0.f, a5 = 0.f, a6 = 0.f, a7 = 0.f;
    for (int base = e0; base < e1; base += 32) {
        int ee = base + L;
        int iv = -1;
        if (ee < e1) {
            iv = csr[ee];                       // one coalesced 128B load per half-wave
            if ((unsigned)iv >= (unsigned)NNi) iv = -1;
        }
        int cnt = e1 - base;
        cnt = cnt > 32 ? 32 : cnt;
        for (int k = 0; k < cnt; k += 8) {      // 8 row loads in flight, zero-row padded
            u16x8 hv[8];
#pragma unroll
            for (int u = 0; u < 8; u++) {
                int j = __shfl(iv, k + u, 32);
                bool val = (k + u < cnt) && (j >= 0);
                const u16* ptr = val ? (H + (size_t)j * 256 + c) : zrow;
                hv[u] = *(const u16x8*)ptr;
            }
#pragma unroll
            for (int u = 0; u < 8; u++) {
                a0 += b2f(hv[u][0]); a1 += b2f(hv[u][1]);
                a2 += b2f(hv[u][2]); a3 += b2f(hv[u][3]);
                a4 += b2f(hv[u][4]); a5 += b2f(hv[u][5]);
                a6 += b2f(hv[u][6]); a7 += b2f(hv[u][7]);
            }
        }
    }
    float inv = invdeg[node];
    u16x8 o;
    o[0] = f2b(b2f(self[0]) + a0 * inv); o[1] = f2b(b2f(self[1]) + a1 * inv);
    o[2] = f2b(b2f(self[2]) + a2 * inv); o[3] = f2b(b2f(self[3]) + a3 * inv);
    o[4] = f2b(b2f(self[4]) + a4 * inv); o[5] = f2b(b2f(self[5]) + a5 * inv);
    o[6] = f2b(b2f(self[6]) + a6 * inv); o[7] = f2b(b2f(self[7]) + a7 * inv);
    *(u16x8*)(T + (size_t)node * 256 + c) = o;
}

// ---------------- MFMA GEMM body (round-2 proven): gll + 2-buffer, 1 drain/K-step ----
// Chunk XOR-swizzle on BOTH global source and ds_read address (rule #21) -> conflict-free.
template <bool CONV, bool RELU>
__device__ __forceinline__ void gemm_body(
    u16 (* __restrict__ lds)[4096],
    const u16* __restrict__ A, int lda,
    const u16* __restrict__ Bt, int ldb,
    const u16* __restrict__ bias,
    const u16* __restrict__ zp,
    u16* __restrict__ out, u16* __restrict__ out2,
    int M, int K, int H, int W, int m0, int n0) {
    int t = threadIdx.x;
    int w = t >> 6, lane = t & 63;
    int wm = w & 1, wn = w >> 1;
    f32x4 acc[4][4] = {};

    int g0 = w * 128 + lane;
    int g1 = g0 + 64;
    int row0 = g0 >> 2, c0 = g0 & 3;
    int row1 = g1 >> 2, c1 = g1 & 3;
    int ss0 = ((c0 ^ ((row0 >> 1) & 3)) << 3);
    int ss1 = ((c1 ^ ((row1 >> 1) & 3)) << 3);

    int ar0 = m0 + row0, ar1 = m0 + row1;
    bool aok0 = ar0 < M, aok1 = ar1 < M;
    int y0_ = 0, x0_ = 0, y1_ = 0, x1_ = 0;
    if (CONV) {
        int HW = H * W;
        if (aok0) { int b = ar0 / HW; int rem = ar0 - b * HW; y0_ = rem / W; x0_ = rem - y0_ * W; }
        if (aok1) { int b = ar1 / HW; int rem = ar1 - b * HW; y1_ = rem / W; x1_ = rem - y1_ * W; }
    }
    const u16* aP0 = A + (size_t)ar0 * lda + ss0;
    const u16* aP1 = A + (size_t)ar1 * lda + ss1;
    const u16* bP0 = Bt + (size_t)(n0 + row0) * ldb + ss0;
    const u16* bP1 = Bt + (size_t)(n0 + row1) * ldb + ss1;

    int lbase = w * 1024;

    auto stage = [&](int bf, int k0) {
        u16* LA = lds[bf * 2];
        u16* LB = lds[bf * 2 + 1];
        const u16* sa0;
        const u16* sa1;
        if (!CONV) {
            sa0 = aok0 ? aP0 + k0 : zp;
            sa1 = aok1 ? aP1 + k0 : zp;
        } else {
            int tap = k0 >> 8;
            int t3 = tap / 3;
            int dy = t3 - 1, dx = tap - t3 * 3 - 1;
            int off = (dy * W + dx) * lda + (k0 & 255);
            int yy0 = y0_ + dy, xx0 = x0_ + dx;
            int yy1 = y1_ + dy, xx1 = x1_ + dx;
            sa0 = (aok0 && (unsigned)yy0 < (unsigned)H && (unsigned)xx0 < (unsigned)W) ? aP0 + off : zp;
            sa1 = (aok1 && (unsigned)yy1 < (unsigned)H && (unsigned)xx1 < (unsigned)W) ? aP1 + off : zp;
        }
        gll16(sa0, LA + lbase);
        gll16(sa1, LA + lbase + 512);
        gll16(bP0 + k0, LB + lbase);
        gll16(bP1 + k0, LB + lbase + 512);
    };

    int nst = K >> 5;
    int fm = lane & 15;
    int co = (((lane >> 4) ^ ((fm >> 1) & 3)) << 3);

    stage(0, 0);
    __syncthreads();  // implicit vmcnt(0) drain -> buf0 ready
    for (int s = 0; s < nst; s++) {
        int bf = s & 1;
        if (s + 1 < nst) stage(bf ^ 1, (s + 1) << 5);  // in flight during compute
        const u16* LA = lds[bf * 2];
        const u16* LB = lds[bf * 2 + 1];
        bf16x8 af[4], bfv[4];
#pragma unroll
        for (int i = 0; i < 4; i++) af[i] = *(const bf16x8*)&LA[(wm * 64 + i * 16 + fm) * 32 + co];
#pragma unroll
        for (int j = 0; j < 4; j++) bfv[j] = *(const bf16x8*)&LB[(wn * 64 + j * 16 + fm) * 32 + co];
#pragma unroll
        for (int i = 0; i < 4; i++)
#pragma unroll
            for (int j = 0; j < 4; j++)
                acc[i][j] = __builtin_amdgcn_mfma_f32_16x16x32_bf16(af[i], bfv[j], acc[i][j], 0, 0, 0);
        __syncthreads();  // drains stage loads (next buf ready) + guards buf reuse
    }

    int q = lane >> 4, nl = lane & 15;
#pragma unroll
    for (int j = 0; j < 4; j++) {
        int n = n0 + wn * 64 + j * 16 + nl;
        float bv = b2f(bias[n]);
#pragma unroll
        for (int i = 0; i < 4; i++) {
            int mbase = m0 + wm * 64 + i * 16 + q * 4;
#pragma unroll
            for (int rg = 0; rg < 4; rg++) {
                int m = mbase + rg;
                if (m < M) {
                    float v = acc[i][j][rg] + bv;
                    if (RELU) v = fmaxf(v, 0.f);
                    u16 bs = f2b(v);
                    out[(size_t)m * 256 + n] = bs;
                    if (out2) out2[(size_t)m * 256 + n] = bs;
                }
            }
        }
    }
}

// generic wrapper (GNN layers), 528-block 1-D grid with XCD pair affinity
template <bool CONV, bool RELU>
__global__ __launch_bounds__(256) void gemm_kernel(
    const u16* __restrict__ A, int lda,
    const u16* __restrict__ Bt, int ldb,
    const u16* __restrict__ bias,
    const u16* __restrict__ zp,
    u16* __restrict__ out, u16* __restrict__ out2,
    int M, int K, int H, int W) {
    __shared__ __align__(16) u16 lds[4][4096];
    int p, x;
    if (!xcd_pair_decode(blockIdx.x, p, x)) return;
    gemm_body<CONV, RELU>(lds, A, lda, Bt, ldb, bias, zp, out, out2, M, K, H, W,
                          p * 128, x * 128);
}

// all 3 lateral 1x1 GEMMs, one launch; p-range selects level (K differs per level)
__global__ __launch_bounds__(256) void lat_all_kernel(
    const u16* __restrict__ Xt3, const u16* __restrict__ Xt4, const u16* __restrict__ Xt5,
    const u16* __restrict__ W1, const u16* __restrict__ BB, const u16* __restrict__ zp,
    u16* __restrict__ P, u16* __restrict__ Ha) {
    __shared__ __align__(16) u16 lds[4][4096];
    int p, x;
    if (!xcd_pair_decode(blockIdx.x, p, x)) return;
    const u16* A; const u16* Bt; const u16* bias;
    int K, Ml, m0; size_t off;
    if (p < 200)      { A = Xt3; Bt = W1;          bias = BB;       K = 256; Ml = N3i; off = 0;                          m0 = p * 128; }
    else if (p < 250) { A = Xt4; Bt = W1 + 65536;  bias = BB + 256; K = 512; Ml = N4i; off = (size_t)N3i * 256;          m0 = (p - 200) * 128; }
    else              { A = Xt5; Bt = W1 + 196608; bias = BB + 512; K = 512; Ml = N5i; off = (size_t)(N3i + N4i) * 256;  m0 = (p - 250) * 128; }
    gemm_body<false, false>(lds, A, K, Bt, K, bias, zp, P + off, Ha + off, Ml, K, 0, 0,
                            m0, x * 128);
}

// all 3 output 3x3 convs, one launch (526 equal-cost blocks, XCD pair affinity)
__global__ __launch_bounds__(256) void conv_gemm_all(
    const u16* __restrict__ Pc, const u16* __restrict__ WtC,
    const u16* __restrict__ BB, const u16* __restrict__ zp, u16* __restrict__ OutT) {
    __shared__ __align__(16) u16 lds[4][4096];
    int p, x;
    if (!xcd_pair_decode(blockIdx.x, p, x)) return;
    int lvl, yl, Hd, Ml; size_t base;
    if (p < 200)      { lvl = 0; yl = p;       Hd = 80; Ml = N3i; base = 0; }
    else if (p < 250) { lvl = 1; yl = p - 200; Hd = 40; Ml = N4i; base = (size_t)N3i * 256; }
    else              { lvl = 2; yl = p - 250; Hd = 20; Ml = N5i; base = (size_t)(N3i + N4i) * 256; }
    gemm_body<true, false>(lds, Pc + base, 256, WtC + (size_t)lvl * 256 * 2304, 2304,
                           BB + 3072 + lvl * 256, zp, OutT + base, nullptr,
                           Ml, 2304, Hd, Hd, yl * 128, x * 128);
}

// ---------------- fused pyramid composition: Pc = compose(P, Hf) ----------------
__global__ void pyr_kernel(const u16* __restrict__ P, const u16* __restrict__ Hf,
                           u16* __restrict__ Pc) {
    int i = blockIdx.x * 256 + threadIdx.x;
    if (i >= NNi * 64) return;
    int node = i >> 6, c = (i & 63) * 4;
    size_t bi = (size_t)node * 256 + c;
    ushort4 pv = *(const ushort4*)(P + bi);
    ushort4 hv = *(const ushort4*)(Hf + bi);
    float v0 = b2f(pv.x) + b2f(hv.x);
    float v1 = b2f(pv.y) + b2f(hv.y);
    float v2 = b2f(pv.z) + b2f(hv.z);
    float v3 = b2f(pv.w) + b2f(hv.w);
    if (node < N3i) {
        int b = node / 6400, rem = node - b * 6400;
        int y = rem / 80, x = rem - y * 80;
        size_t s4 = ((size_t)N3i + b * 1600 + (y >> 1) * 40 + (x >> 1)) * 256 + c;
        size_t s5 = ((size_t)(N3i + N4i) + b * 400 + (y >> 2) * 20 + (x >> 2)) * 256 + c;
        ushort4 p4 = *(const ushort4*)(P + s4), h4 = *(const ushort4*)(Hf + s4);
        ushort4 p5 = *(const ushort4*)(P + s5), h5 = *(const ushort4*)(Hf + s5);
        v0 += b2f(p4.x) + b2f(h4.x) + b2f(p5.x) + b2f(h5.x);
        v1 += b2f(p4.y) + b2f(h4.y) + b2f(p5.y) + b2f(h5.y);
        v2 += b2f(p4.z) + b2f(h4.z) + b2f(p5.z) + b2f(h5.z);
        v3 += b2f(p4.w) + b2f(h4.w) + b2f(p5.w) + b2f(h5.w);
    } else if (node < N3i + N4i) {
        int n4 = node - N3i;
        int b = n4 / 1600, rem = n4 - b * 1600;
        int y = rem / 40, x = rem - y * 40;
        size_t s5 = ((size_t)(N3i + N4i) + b * 400 + (y >> 1) * 20 + (x >> 1)) * 256 + c;
        ushort4 p5 = *(const ushort4*)(P + s5), h5 = *(const ushort4*)(Hf + s5);
        v0 += b2f(p5.x) + b2f(h5.x);
        v1 += b2f(p5.y) + b2f(h5.y);
        v2 += b2f(p5.z) + b2f(h5.z);
        v3 += b2f(p5.w) + b2f(h5.w);
    }
    ushort4 o;
    o.x = f2b(v0); o.y = f2b(v1); o.z = f2b(v2); o.w = f2b(v3);
    *(ushort4*)(Pc + bi) = o;
}

// ---------------- host ----------------
extern "C" void kernel_launch(void* const* d_in, const int* in_sizes, int n_in,
                              void* d_out, int out_size, void* d_ws, size_t ws_size,
                              hipStream_t stream) {
    (void)in_sizes; (void)n_in; (void)out_size; (void)ws_size;
    const void* c3 = d_in[0];
    const void* c4 = d_in[1];
    const void* c5 = d_in[2];
    const void* w3_1 = d_in[3];
    const void* b3_1 = d_in[4];
    const void* w4_1 = d_in[5];
    const void* b4_1 = d_in[6];
    const void* w5_1 = d_in[7];
    const void* b5_1 = d_in[8];
    const void* w3_3 = d_in[9];
    const void* b3_3 = d_in[10];
    const void* w4_3 = d_in[11];
    const void* b4_3 = d_in[12];
    const void* w5_3 = d_in[13];
    const void* b5_3 = d_in[14];
    const void* Wc = d_in[15];
    const void* bc = d_in[16];
    const void* Wh = d_in[17];
    const void* bh = d_in[18];
    const int* src_c = (const int*)d_in[19];
    const int* dst_c = (const int*)d_in[20];
    const int* src_h = (const int*)d_in[21];
    const int* dst_h = (const int*)d_in[22];

    char* w = (char*)d_ws;
    auto alloc = [&](size_t bytes) -> void* {
        void* p = (void*)w;
        w += (bytes + 255) & ~(size_t)255;
        return p;
    };
    u16* XT  = (u16*)alloc(((size_t)N3i * 256 + (size_t)N4i * 512 + (size_t)N5i * 512) * 2);
    u16* Xt3 = XT;
    u16* Xt4 = XT + (size_t)N3i * 256;
    u16* Xt5 = Xt4 + (size_t)N4i * 512;
    u16* T   = XT;                          // alias (17.2 MB <= 21.3 MB region)
    u16* Pc  = XT;                          // pyramid output aliases T (free after GNN)
    u16* WtC = XT + (size_t)NNi * 256;      // alias, starts right after T (3.54 MB fits)
    u16* WtG = (u16*)alloc((size_t)9 * 65536 * 2);
    u16* W1  = (u16*)alloc((size_t)(65536 + 131072 + 131072) * 2);
    u16* BB  = (u16*)alloc((size_t)3840 * 2);
    u16* P   = (u16*)alloc((size_t)NNi * 256 * 2);
    u16* Ha  = (u16*)alloc((size_t)NNi * 256 * 2);
    u16* Hb  = (u16*)d_out;                 // alias d_out as scratch
    int* csr_c = (int*)alloc((size_t)ECi * 4);
    int* csr_h = (int*)alloc((size_t)EHi * 4);
    int* cnt2  = (int*)alloc((size_t)2 * NNi * 4);
    int* cnt_c = cnt2;
    int* cnt_h = cnt2 + NNi;
    int* rs_c  = (int*)alloc((size_t)(NNi + 1) * 4);
    int* rs_h  = (int*)alloc((size_t)(NNi + 1) * 4);
    int* cur_c = (int*)alloc((size_t)NNi * 4);
    int* cur_h = (int*)alloc((size_t)NNi * 4);
    float* inv_c = (float*)alloc((size_t)NNi * 4);
    float* inv_h = (float*)alloc((size_t)NNi * 4);
    int* ps_c  = (int*)alloc((size_t)NNi * 4);   // scan partials
    int* ps_h  = (int*)alloc((size_t)NNi * 4);
    int* bsum  = (int*)alloc((size_t)132 * 4);
    int* flag  = (int*)alloc(256);
    u16* zp    = (u16*)alloc(512);          // 512B zero row (GEMM mask + gather dead-loads)

    // ---- dtype detection + zero-row init ----
    detect_kernel<<<1, 64, 0, stream>>>(c3, flag, (uint32_t*)zp);

    // ---- CSR build (3-pass parallel scan) ----
    zero_i32<<<(2 * NNi + 255) / 256, 256, 0, stream>>>(cnt2, 2 * NNi);
    hist2_kernel<<<(ECi + EHi + 255) / 256, 256, 0, stream>>>(dst_c, dst_h, cnt_c, cnt_h);
    scan_part<<<132, 256, 0, stream>>>(cnt_c, cnt_h, ps_c, ps_h, bsum);
    scan_sums<<<1, 256, 0, stream>>>(bsum);
    scan_final<<<132, 256, 0, stream>>>(ps_c, ps_h, bsum, cnt_c, cnt_h,
                                        rs_c, cur_c, inv_c, rs_h, cur_h, inv_h);
    fill2_kernel<<<(ECi + EHi + 255) / 256, 256, 0, stream>>>(
        src_c, dst_c, cur_c, csr_c, src_h, dst_h, cur_h, csr_h);

    // ---- convert small tensors (one launch) ----
    CvtJobs cj;
    cj.src[0] = w3_1; cj.dst[0] = W1;          cj.n[0] = 65536;
    cj.src[1] = w4_1; cj.dst[1] = W1 + 65536;  cj.n[1] = 131072;
    cj.src[2] = w5_1; cj.dst[2] = W1 + 196608; cj.n[2] = 131072;
    cj.src[3] = b3_1; cj.dst[3] = BB;          cj.n[3] = 256;
    cj.src[4] = b4_1; cj.dst[4] = BB + 256;    cj.n[4] = 256;
    cj.src[5] = b5_1; cj.dst[5] = BB + 512;    cj.n[5] = 256;
    cj.src[6] = bc;   cj.dst[6] = BB + 768;    cj.n[6] = 1536;
    cj.src[7] = bh;   cj.dst[7] = BB + 2304;   cj.n[7] = 768;
    cj.src[8] = b3_3; cj.dst[8] = BB + 3072;   cj.n[8] = 256;
    cj.src[9] = b4_3; cj.dst[9] = BB + 3328;   cj.n[9] = 256;
    cj.src[10] = b5_3; cj.dst[10] = BB + 3584; cj.n[10] = 256;
    cvt_all_kernel<<<dim3(512, 11), 256, 0, stream>>>(cj, flag);

    // ---- input transposes + GNN weight transposes ----
    transpose_in3<<<dim3(263, 16, 4), dim3(32, 8), 0, stream>>>(c3, c4, c5, Xt3, Xt4, Xt5, flag);
    transpose_w<<<dim3(8, 8, 9), dim3(32, 8), 0, stream>>>(Wc, Wh, WtG, flag);

    // ---- lateral 1x1 convs -> P (and H0 = Ha), one launch ----
    lat_all_kernel<<<528, 256, 0, stream>>>(Xt3, Xt4, Xt5, W1, BB, zp, P, Ha);

    // ---- conv weights AFTER laterals (WtC aliases Xt4/Xt5 tail) ----
    convw3_kernel<<<dim3(2304, 3), 256, 0, stream>>>(w3_3, w4_3, w5_3, WtC, flag);

    // ---- 9 GNN layers ----
    u16* Hcur = Ha;
    u16* Hnxt = Hb;
    for (int l = 0; l < 9; l++) {
        bool ctx = (l < 3) || (l >= 6);
        const int* csr = ctx ? csr_c : csr_h;
        const int* rs = ctx ? rs_c : rs_h;
        const float* inv = ctx ? inv_c : inv_h;
        int ecap = ctx ? ECi : EHi;
        int wi = (l < 3) ? l : (l < 6 ? 6 + (l - 3) : l - 3);
        const u16* bias = (l < 3) ? BB + 768 + l * 256
                        : (l < 6 ? BB + 2304 + (l - 3) * 256 : BB + 768 + (l - 3) * 256);
        gather_kernel<<<NNi / 8, 256, 0, stream>>>(Hcur, csr, rs, inv, T, zp, ecap);
        gemm_kernel<false, true><<<528, 256, 0, stream>>>(
            T, 256, WtG + (size_t)wi * 65536, 256, bias, zp, Hnxt, nullptr, NNi, 256, 0, 0);
        u16* tmp = Hcur; Hcur = Hnxt; Hnxt = tmp;
    }
    u16* OutT = Hnxt;  // = Ha

    // ---- fused pyramid composition -> Pc ----
    pyr_kernel<<<(NNi * 64 + 255) / 256, 256, 0, stream>>>(P, Hcur, Pc);

    // ---- 3x3 convs (9-tap gathered GEMM), one launch ----
    conv_gemm_all<<<528, 256, 0, stream>>>(Pc, WtC, BB, zp, OutT);

    // ---- node-major -> NCHW output (one launch) ----
    transpose_out3<<<dim3(8, 263, 4), dim3(32, 8), 0, stream>>>(OutT, d_out, flag);
}

// Round 9
// 619.481 us; speedup vs baseline: 1.7079x; 1.0033x over previous
//
#include <hip/hip_runtime.h>
#include <stdint.h>

#define N3i 25600
#define N4i 6400
#define N5i 1600
#define NNi 33600
#define ECi 260000
#define EHi 120000

typedef unsigned short u16;
typedef __bf16 bf16x8 __attribute__((ext_vector_type(8)));
typedef float f32x4 __attribute__((ext_vector_type(4)));
typedef unsigned short u16x8 __attribute__((ext_vector_type(8)));

__device__ __forceinline__ float b2f(u16 u) {
    union { float f; uint32_t i; } v; v.i = ((uint32_t)u) << 16; return v.f;
}
__device__ __forceinline__ u16 f2b(float f) {
    union { float f; uint32_t i; } v; v.f = f;
    uint32_t x = v.i;
    uint32_t r = (x + 0x7FFFu + ((x >> 16) & 1u)) >> 16;  // RNE
    return (u16)r;
}

// async global->LDS, 16B per lane. LDS dest must be wave-uniform base (+lane*16 by HW);
// global source is per-lane (rule #21: swizzle via source address, keep LDS linear).
__device__ __forceinline__ void gll16(const u16* g, u16* l) {
    __builtin_amdgcn_global_load_lds((const __attribute__((address_space(1))) void*)g,
                                     (__attribute__((address_space(3))) void*)l, 16, 0, 0);
}

// XCD pair-affinity decode: 528-block 1-D grid -> (p: row-tile 0..262, x: col-half 0..1)
// with both members of a pair on the SAME XCD (xcd = bid % 8 round-robin -- CONFIRMED
// round 6: conv FETCH 110MB -> 14.5MB). Pair members are 8 ids apart; each XCD owns a
// contiguous band of row-tiles (tap-overlap locality).
__device__ __forceinline__ bool xcd_pair_decode(int pid, int& p, int& x) {
    int g = pid & 7;
    int s = pid >> 3;
    x = s & 1;
    p = g * 33 + (s >> 1);
    return p < 263;
}

// ---------------- prep: zero cnt arrays + (block 0) dtype detect + zero-row init ----------------
__global__ void prep_kernel(int* __restrict__ cnt2, int n, const void* __restrict__ c3raw,
                            int* __restrict__ flag, uint32_t* __restrict__ zp) {
    int i = blockIdx.x * 256 + threadIdx.x;
    if (i < n) cnt2[i] = 0;
    if (blockIdx.x == 0) {
        int t = threadIdx.x;
        if (t < 128) zp[t] = 0;  // 512B zero row (GEMM mask + gather dead-loads)
        if (t < 64) {            // wave 0 only: dtype vote
            const uint32_t* p = (const uint32_t*)c3raw;
            int vote = 0;
            for (int k = t; k < 256; k += 64) {
                uint32_t w = p[k];
                uint32_t lo = w & 0xFFFFu;
                uint32_t e = (lo >> 7) & 0xFFu;
                if (lo == 0u || (e >= 100u && e <= 127u)) vote++;
            }
#pragma unroll
            for (int d = 32; d >= 1; d >>= 1) vote += __shfl_down(vote, d, 64);
            if (t == 0) flag[0] = (vote >= 192) ? 1 : 0;
        }
    }
}

__global__ void hist2_kernel(const int* __restrict__ dst_c, const int* __restrict__ dst_h,
                             int* __restrict__ cnt_c, int* __restrict__ cnt_h) {
    int i = blockIdx.x * 256 + threadIdx.x;
    if (i < ECi) {
        int d = dst_c[i];
        if ((unsigned)d < (unsigned)NNi) atomicAdd(&cnt_c[d], 1);
    } else {
        int j = i - ECi;
        if (j < EHi) {
            int d = dst_h[j];
            if ((unsigned)d < (unsigned)NNi) atomicAdd(&cnt_h[d], 1);
        }
    }
}

// ---------------- 2-pass parallel scan (bsum scan folded into final pass) ----------------
__global__ __launch_bounds__(256) void scan_part(
    const int* __restrict__ cnt_c, const int* __restrict__ cnt_h,
    int* __restrict__ ps_c, int* __restrict__ ps_h, int* __restrict__ bsum) {
    int b = blockIdx.x;
    bool hier = b >= 66;
    const int* cnt = hier ? cnt_h : cnt_c;
    int* ps = hier ? ps_h : ps_c;
    int base = (hier ? b - 66 : b) * 512;
    int t = threadIdx.x, lane = t & 63, wid = t >> 6;
    int i0 = base + 2 * t;
    int v0 = (i0 < NNi) ? cnt[i0] : 0;
    int v1 = (i0 + 1 < NNi) ? cnt[i0 + 1] : 0;
    int s = v0 + v1;
    int x = s;
#pragma unroll
    for (int d = 1; d < 64; d <<= 1) {
        int y = __shfl_up(x, d, 64);
        if (lane >= d) x += y;
    }
    __shared__ int ws[4];
    if (lane == 63) ws[wid] = x;
    __syncthreads();
    int w0 = ws[0], w1 = ws[1], w2 = ws[2], w3 = ws[3];
    int woff = (wid == 1) ? w0 : (wid == 2) ? (w0 + w1) : (wid == 3) ? (w0 + w1 + w2) : 0;
    int incl = x + woff;
    int excl = incl - s;
    if (i0 < NNi) ps[i0] = excl + v0;
    if (i0 + 1 < NNi) ps[i0 + 1] = excl + v0 + v1;
    if (t == 0) bsum[b] = w0 + w1 + w2 + w3;
}

// final pass: each block scans the 132-entry bsum in LDS (trivial), adds offset,
// emits rs/cur/inv. Saves the separate scan_sums dispatch.
__global__ __launch_bounds__(256) void scan_final(
    const int* __restrict__ ps_c, const int* __restrict__ ps_h, const int* __restrict__ bsum,
    const int* __restrict__ cnt_c, const int* __restrict__ cnt_h,
    int* __restrict__ rs_c, int* __restrict__ cur_c, float* __restrict__ inv_c,
    int* __restrict__ rs_h, int* __restrict__ cur_h, float* __restrict__ inv_h) {
    __shared__ int s[132];
    int t = threadIdx.x;
    if (t < 132) s[t] = bsum[t];
    __syncthreads();
    for (int d = 1; d < 66; d <<= 1) {
        int v = 0;
        if (t < 132) {
            int seg0 = (t < 66) ? 0 : 66;
            if (t - seg0 >= d) v = s[t - d];
        }
        __syncthreads();
        if (t < 132) s[t] += v;
        __syncthreads();
    }
    int b = blockIdx.x;
    bool hier = b >= 66;
    int lb = hier ? b - 66 : b;
    const int* ps = hier ? ps_h : ps_c;
    const int* cnt = hier ? cnt_h : cnt_c;
    int* rs = hier ? rs_h : rs_c;
    int* cur = hier ? cur_h : cur_c;
    float* inv = hier ? inv_h : inv_c;
    int off = s[b] - bsum[b];   // exclusive offset for this block
#pragma unroll
    for (int k = 0; k < 2; k++) {
        int i = lb * 512 + t + k * 256;
        if (i < NNi) {
            int incl = ps[i] + off;
            int v = cnt[i];
            rs[i + 1] = incl;
            cur[i] = incl - v;
            inv[i] = 1.0f / (float)(v < 1 ? 1 : v);
        }
    }
    if (b == 0 && t == 0) rs_c[0] = 0;
    if (b == 66 && t == 0) rs_h[0] = 0;
}

__global__ void fill2_kernel(const int* __restrict__ src_c, const int* __restrict__ dst_c,
                             int* __restrict__ cur_c, int* __restrict__ csr_c,
                             const int* __restrict__ src_h, const int* __restrict__ dst_h,
                             int* __restrict__ cur_h, int* __restrict__ csr_h) {
    int i = blockIdx.x * 256 + threadIdx.x;
    if (i < ECi) {
        int d = dst_c[i];
        if ((unsigned)d < (unsigned)NNi) {
            int p = atomicAdd(&cur_c[d], 1);
            if ((unsigned)p < (unsigned)ECi) csr_c[p] = src_c[i];
        }
    } else {
        int j = i - ECi;
        if (j < EHi) {
            int d = dst_h[j];
            if ((unsigned)d < (unsigned)NNi) {
                int p = atomicAdd(&cur_h[d], 1);
                if ((unsigned)p < (unsigned)EHi) csr_h[p] = src_h[j];
            }
        }
    }
}

// all 11 small conversions in one launch (grid.y = job id)
struct CvtJobs { const void* src[11]; u16* dst[11]; int n[11]; };

__global__ void cvt_all_kernel(CvtJobs j, const int* __restrict__ flag) {
    int job = blockIdx.y;
    int i = blockIdx.x * 256 + threadIdx.x;
    if (i >= j.n[job]) return;
    const void* s = j.src[job];
    j.dst[job][i] = flag[0] ? ((const u16*)s)[i] : f2b(((const float*)s)[i]);
}

// ---------------- transposes (G13: vectorized write phase, 8B/lane) ----------------
// Load phase: coalesced per-element reads (4B fp32 / 2B bf16).
// Write phase: each thread owns column c0+cidx, 4 consecutive rows -> ushort4 store.
// Requires R % 32 == 0 (all tin_body callers: R in {256,512}).
__device__ __forceinline__ void tin_body(const void* in, size_t ioff, u16* outp, int R, int C,
                                         int isb, int c0, int r0, u16 (*tile)[33]) {
    const u16* inb = (const u16*)in + ioff;
    const float* inf_ = (const float*)in + ioff;
    int t = threadIdx.y * 32 + threadIdx.x;  // block (32,8) -> 0..255
    int tx = t & 31, ty = t >> 5;
#pragma unroll
    for (int i = 0; i < 4; i++) {
        int r = r0 + ty + i * 8, c = c0 + tx;
        if (r < R && c < C) {
            size_t idx = (size_t)r * C + c;
            tile[ty + i * 8][tx] = isb ? inb[idx] : f2b(inf_[idx]);
        }
    }
    __syncthreads();
    int cidx = t >> 3, r4 = (t & 7) << 2;
    int c = c0 + cidx;
    if (c < C) {
        ushort4 v;
        v.x = tile[r4][cidx];
        v.y = tile[r4 + 1][cidx];
        v.z = tile[r4 + 2][cidx];
        v.w = tile[r4 + 3][cidx];
        *(ushort4*)&outp[(size_t)c * R + r0 + r4] = v;
    }
}

__global__ void transpose_in3(const void* __restrict__ c3, const void* __restrict__ c4,
                              const void* __restrict__ c5, u16* __restrict__ Xt3,
                              u16* __restrict__ Xt4, u16* __restrict__ Xt5,
                              const int* __restrict__ flag) {
    __shared__ u16 tile[32][33];
    int bx = blockIdx.x;
    const void* in; u16* outb; int R, C, xb;
    if (bx < 200)      { in = c3; outb = Xt3; R = 256; C = 6400; xb = bx; }
    else if (bx < 250) { in = c4; outb = Xt4; R = 512; C = 1600; xb = bx - 200; }
    else               { in = c5; outb = Xt5; R = 512; C = 400;  xb = bx - 250; }
    int r0 = blockIdx.y * 32;
    if (r0 >= R) return;
    size_t boff = (size_t)blockIdx.z * R * C;
    tin_body(in, boff, outb + boff, R, C, flag[0], xb * 32, r0, tile);
}

__global__ void transpose_w(const void* __restrict__ Wc, const void* __restrict__ Wh,
                            u16* __restrict__ WtG, const int* __restrict__ flag) {
    __shared__ u16 tile[32][33];
    int z = blockIdx.z;
    const void* in = (z < 6) ? Wc : Wh;
    int zi = (z < 6) ? z : z - 6;
    tin_body(in, (size_t)zi * 65536, WtG + (size_t)z * 65536, 256, 256, flag[0],
             blockIdx.x * 32, blockIdx.y * 32, tile);
}

// node-major -> NCHW output: vectorized 8B/lane loads, 8B (bf16) / 16B (fp32) stores.
// C = 256 always; R in {6400,1600,400}; masked scalar tail only for R=400 edge tile.
__global__ void transpose_out3(const u16* __restrict__ OutT, void* __restrict__ outv,
                               const int* __restrict__ flag) {
    __shared__ u16 tile[32][33];
    int by = blockIdx.y;
    const u16* inb; size_t out_off; int R, yb;
    if (by < 200)      { inb = OutT; out_off = 0; R = 6400; yb = by; }
    else if (by < 250) { inb = OutT + (size_t)N3i * 256; out_off = (size_t)4 * 256 * 6400; R = 1600; yb = by - 200; }
    else               { inb = OutT + (size_t)(N3i + N4i) * 256; out_off = (size_t)4 * 256 * 8000; R = 400; yb = by - 250; }
    int r0 = yb * 32;
    if (r0 >= R) return;
    const int C = 256;
    int isb = flag[0];
    int c0 = blockIdx.x * 32;
    size_t boff = (size_t)blockIdx.z * R * C;
    const u16* inp = inb + boff;
    int t = threadIdx.y * 32 + threadIdx.x;
    // load: 4 consecutive c per thread (8B)
    int ridx = t >> 3, c4 = (t & 7) << 2;
    if (r0 + ridx < R) {
        ushort4 lv = *(const ushort4*)&inp[(size_t)(r0 + ridx) * C + c0 + c4];
        tile[ridx][c4] = lv.x; tile[ridx][c4 + 1] = lv.y;
        tile[ridx][c4 + 2] = lv.z; tile[ridx][c4 + 3] = lv.w;
    }
    __syncthreads();
    // write: 4 consecutive r per thread
    int cidx = t >> 3, r4 = (t & 7) << 2;
    int c = c0 + cidx;
    size_t obase = out_off + boff + (size_t)c * R + r0 + r4;
    if (r0 + r4 + 3 < R) {
        if (isb) {
            ushort4 v;
            v.x = tile[r4][cidx]; v.y = tile[r4 + 1][cidx];
            v.z = tile[r4 + 2][cidx]; v.w = tile[r4 + 3][cidx];
            *(ushort4*)&((u16*)outv)[obase] = v;
        } else {
            float4 v;
            v.x = b2f(tile[r4][cidx]); v.y = b2f(tile[r4 + 1][cidx]);
            v.z = b2f(tile[r4 + 2][cidx]); v.w = b2f(tile[r4 + 3][cidx]);
            *(float4*)&((float*)outv)[obase] = v;
        }
    } else {
#pragma unroll
        for (int k = 0; k < 4; k++) {
            int r = r0 + r4 + k;
            if (r < R) {
                u16 v = tile[r4 + k][cidx];
                if (isb) ((u16*)outv)[obase + k] = v;
                else ((float*)outv)[obase + k] = b2f(v);
            }
        }
    }
}

// conv weight transform for all 3 levels: wt[n][tap*256+ci] = w[n][ci*9+tap]
__global__ void convw3_kernel(const void* __restrict__ w0, const void* __restrict__ w1,
                              const void* __restrict__ w2, u16* __restrict__ WtC,
                              const int* __restrict__ flag) {
    int lvl = blockIdx.y;
    const void* w = (lvl == 0) ? w0 : (lvl == 1) ? w1 : w2;
    u16* wt = WtC + (size_t)lvl * 256 * 2304;
    int i = blockIdx.x * 256 + threadIdx.x;
    if (i >= 256 * 2304) return;
    int n = i / 2304;
    int k = i - n * 2304;
    int tap = k >> 8, ci = k & 255;
    int si = n * 2304 + ci * 9 + tap;
    wt[i] = flag[0] ? ((const u16*)w)[si] : f2b(((const float*)w)[si]);
}

// ---------------- GNN gather: T = bf16(H + segsum(H[src]) * invdeg) ----------------
// Half-wave (32 lanes x 16B) owns one FULL node row; 32 edge indices prefetched in one
// coalesced load and shfl-broadcast; 8-deep zero-row-padded load batches; XCD-chunked
// block remap. (r8: gathers measured memory-system-bound; structure frozen.)
__global__ __launch_bounds__(256) void gather_kernel(
    const u16* __restrict__ H, const int* __restrict__ csr, const int* __restrict__ rs,
    const float* __restrict__ invdeg, u16* __restrict__ T, const u16* __restrict__ zp,
    int ecap) {
    int bid = blockIdx.x;                       // 4200 blocks
    int nb = (bid & 7) * 525 + (bid >> 3);      // XCD-chunked remap (4200 = 8*525)
    int node = nb * 8 + (threadIdx.x >> 5);
    if (node >= NNi) return;
    int L = threadIdx.x & 31;
    int c = L * 8;
    int e0 = rs[node], e1 = rs[node + 1];
    e0 = e0 < 0 ? 0 : e0;
    e1 = e1 > ecap ? ecap : e1;
    u16x8 self = *(const u16x8*)(H + (size_t)node * 256 + c);  // issued early
    const u16* zrow = zp + c;                   // zero row slice for dead loads
    float a0 = 0.f, a1 = 0.f, a2 = 0.f, a3 = 0.f, a4 = 0.f, a5 = 0.f, a6 = 0.f, a7 = 0.f;
    for (int base = e0; base < e1; base += 32) {
        int ee = base + L;
        int iv = -1;
        if (ee < e1) {
            iv = csr[ee];                       // one coalesced 128B load per half-wave
            if ((unsigned)iv >= (unsigned)NNi) iv = -1;
        }
        int cnt = e1 - base;
        cnt = cnt > 32 ? 32 : cnt;
        for (int k = 0; k < cnt; k += 8) {      // 8 row loads in flight, zero-row padded
            u16x8 hv[8];
#pragma unroll
            for (int u = 0; u < 8; u++) {
                int j = __shfl(iv, k + u, 32);
                bool val = (k + u < cnt) && (j >= 0);
                const u16* ptr = val ? (H + (size_t)j * 256 + c) : zrow;
                hv[u] = *(const u16x8*)ptr;
            }
#pragma unroll
            for (int u = 0; u < 8; u++) {
                a0 += b2f(hv[u][0]); a1 += b2f(hv[u][1]);
                a2 += b2f(hv[u][2]); a3 += b2f(hv[u][3]);
                a4 += b2f(hv[u][4]); a5 += b2f(hv[u][5]);
                a6 += b2f(hv[u][6]); a7 += b2f(hv[u][7]);
            }
        }
    }
    float inv = invdeg[node];
    u16x8 o;
    o[0] = f2b(b2f(self[0]) + a0 * inv); o[1] = f2b(b2f(self[1]) + a1 * inv);
    o[2] = f2b(b2f(self[2]) + a2 * inv); o[3] = f2b(b2f(self[3]) + a3 * inv);
    o[4] = f2b(b2f(self[4]) + a4 * inv); o[5] = f2b(b2f(self[5]) + a5 * inv);
    o[6] = f2b(b2f(self[6]) + a6 * inv); o[7] = f2b(b2f(self[7]) + a7 * inv);
    *(u16x8*)(T + (size_t)node * 256 + c) = o;
}

// ---------------- MFMA GEMM body (round-2 proven): gll + 2-buffer, 1 drain/K-step ----
// Chunk XOR-swizzle on BOTH global source and ds_read address (rule #21) -> conflict-free.
template <bool CONV, bool RELU>
__device__ __forceinline__ void gemm_body(
    u16 (* __restrict__ lds)[4096],
    const u16* __restrict__ A, int lda,
    const u16* __restrict__ Bt, int ldb,
    const u16* __restrict__ bias,
    const u16* __restrict__ zp,
    u16* __restrict__ out, u16* __restrict__ out2,
    int M, int K, int H, int W, int m0, int n0) {
    int t = threadIdx.x;
    int w = t >> 6, lane = t & 63;
    int wm = w & 1, wn = w >> 1;
    f32x4 acc[4][4] = {};

    int g0 = w * 128 + lane;
    int g1 = g0 + 64;
    int row0 = g0 >> 2, c0 = g0 & 3;
    int row1 = g1 >> 2, c1 = g1 & 3;
    int ss0 = ((c0 ^ ((row0 >> 1) & 3)) << 3);
    int ss1 = ((c1 ^ ((row1 >> 1) & 3)) << 3);

    int ar0 = m0 + row0, ar1 = m0 + row1;
    bool aok0 = ar0 < M, aok1 = ar1 < M;
    int y0_ = 0, x0_ = 0, y1_ = 0, x1_ = 0;
    if (CONV) {
        int HW = H * W;
        if (aok0) { int b = ar0 / HW; int rem = ar0 - b * HW; y0_ = rem / W; x0_ = rem - y0_ * W; }
        if (aok1) { int b = ar1 / HW; int rem = ar1 - b * HW; y1_ = rem / W; x1_ = rem - y1_ * W; }
    }
    const u16* aP0 = A + (size_t)ar0 * lda + ss0;
    const u16* aP1 = A + (size_t)ar1 * lda + ss1;
    const u16* bP0 = Bt + (size_t)(n0 + row0) * ldb + ss0;
    const u16* bP1 = Bt + (size_t)(n0 + row1) * ldb + ss1;

    int lbase = w * 1024;

    auto stage = [&](int bf, int k0) {
        u16* LA = lds[bf * 2];
        u16* LB = lds[bf * 2 + 1];
        const u16* sa0;
        const u16* sa1;
        if (!CONV) {
            sa0 = aok0 ? aP0 + k0 : zp;
            sa1 = aok1 ? aP1 + k0 : zp;
        } else {
            int tap = k0 >> 8;
            int t3 = tap / 3;
            int dy = t3 - 1, dx = tap - t3 * 3 - 1;
            int off = (dy * W + dx) * lda + (k0 & 255);
            int yy0 = y0_ + dy, xx0 = x0_ + dx;
            int yy1 = y1_ + dy, xx1 = x1_ + dx;
            sa0 = (aok0 && (unsigned)yy0 < (unsigned)H && (unsigned)xx0 < (unsigned)W) ? aP0 + off : zp;
            sa1 = (aok1 && (unsigned)yy1 < (unsigned)H && (unsigned)xx1 < (unsigned)W) ? aP1 + off : zp;
        }
        gll16(sa0, LA + lbase);
        gll16(sa1, LA + lbase + 512);
        gll16(bP0 + k0, LB + lbase);
        gll16(bP1 + k0, LB + lbase + 512);
    };

    int nst = K >> 5;
    int fm = lane & 15;
    int co = (((lane >> 4) ^ ((fm >> 1) & 3)) << 3);

    stage(0, 0);
    __syncthreads();  // implicit vmcnt(0) drain -> buf0 ready
    for (int s = 0; s < nst; s++) {
        int bf = s & 1;
        if (s + 1 < nst) stage(bf ^ 1, (s + 1) << 5);  // in flight during compute
        const u16* LA = lds[bf * 2];
        const u16* LB = lds[bf * 2 + 1];
        bf16x8 af[4], bfv[4];
#pragma unroll
        for (int i = 0; i < 4; i++) af[i] = *(const bf16x8*)&LA[(wm * 64 + i * 16 + fm) * 32 + co];
#pragma unroll
        for (int j = 0; j < 4; j++) bfv[j] = *(const bf16x8*)&LB[(wn * 64 + j * 16 + fm) * 32 + co];
#pragma unroll
        for (int i = 0; i < 4; i++)
#pragma unroll
            for (int j = 0; j < 4; j++)
                acc[i][j] = __builtin_amdgcn_mfma_f32_16x16x32_bf16(af[i], bfv[j], acc[i][j], 0, 0, 0);
        __syncthreads();  // drains stage loads (next buf ready) + guards buf reuse
    }

    int q = lane >> 4, nl = lane & 15;
#pragma unroll
    for (int j = 0; j < 4; j++) {
        int n = n0 + wn * 64 + j * 16 + nl;
        float bv = b2f(bias[n]);
#pragma unroll
        for (int i = 0; i < 4; i++) {
            int mbase = m0 + wm * 64 + i * 16 + q * 4;
#pragma unroll
            for (int rg = 0; rg < 4; rg++) {
                int m = mbase + rg;
                if (m < M) {
                    float v = acc[i][j][rg] + bv;
                    if (RELU) v = fmaxf(v, 0.f);
                    u16 bs = f2b(v);
                    out[(size_t)m * 256 + n] = bs;
                    if (out2) out2[(size_t)m * 256 + n] = bs;
                }
            }
        }
    }
}

// generic wrapper (GNN layers), 528-block 1-D grid with XCD pair affinity
template <bool CONV, bool RELU>
__global__ __launch_bounds__(256) void gemm_kernel(
    const u16* __restrict__ A, int lda,
    const u16* __restrict__ Bt, int ldb,
    const u16* __restrict__ bias,
    const u16* __restrict__ zp,
    u16* __restrict__ out, u16* __restrict__ out2,
    int M, int K, int H, int W) {
    __shared__ __align__(16) u16 lds[4][4096];
    int p, x;
    if (!xcd_pair_decode(blockIdx.x, p, x)) return;
    gemm_body<CONV, RELU>(lds, A, lda, Bt, ldb, bias, zp, out, out2, M, K, H, W,
                          p * 128, x * 128);
}

// all 3 lateral 1x1 GEMMs, one launch; p-range selects level (K differs per level)
__global__ __launch_bounds__(256) void lat_all_kernel(
    const u16* __restrict__ Xt3, const u16* __restrict__ Xt4, const u16* __restrict__ Xt5,
    const u16* __restrict__ W1, const u16* __restrict__ BB, const u16* __restrict__ zp,
    u16* __restrict__ P, u16* __restrict__ Ha) {
    __shared__ __align__(16) u16 lds[4][4096];
    int p, x;
    if (!xcd_pair_decode(blockIdx.x, p, x)) return;
    const u16* A; const u16* Bt; const u16* bias;
    int K, Ml, m0; size_t off;
    if (p < 200)      { A = Xt3; Bt = W1;          bias = BB;       K = 256; Ml = N3i; off = 0;                          m0 = p * 128; }
    else if (p < 250) { A = Xt4; Bt = W1 + 65536;  bias = BB + 256; K = 512; Ml = N4i; off = (size_t)N3i * 256;          m0 = (p - 200) * 128; }
    else              { A = Xt5; Bt = W1 + 196608; bias = BB + 512; K = 512; Ml = N5i; off = (size_t)(N3i + N4i) * 256;  m0 = (p - 250) * 128; }
    gemm_body<false, false>(lds, A, K, Bt, K, bias, zp, P + off, Ha + off, Ml, K, 0, 0,
                            m0, x * 128);
}

// all 3 output 3x3 convs, one launch (526 equal-cost blocks, XCD pair affinity)
__global__ __launch_bounds__(256) void conv_gemm_all(
    const u16* __restrict__ Pc, const u16* __restrict__ WtC,
    const u16* __restrict__ BB, const u16* __restrict__ zp, u16* __restrict__ OutT) {
    __shared__ __align__(16) u16 lds[4][4096];
    int p, x;
    if (!xcd_pair_decode(blockIdx.x, p, x)) return;
    int lvl, yl, Hd, Ml; size_t base;
    if (p < 200)      { lvl = 0; yl = p;       Hd = 80; Ml = N3i; base = 0; }
    else if (p < 250) { lvl = 1; yl = p - 200; Hd = 40; Ml = N4i; base = (size_t)N3i * 256; }
    else              { lvl = 2; yl = p - 250; Hd = 20; Ml = N5i; base = (size_t)(N3i + N4i) * 256; }
    gemm_body<true, false>(lds, Pc + base, 256, WtC + (size_t)lvl * 256 * 2304, 2304,
                           BB + 3072 + lvl * 256, zp, OutT + base, nullptr,
                           Ml, 2304, Hd, Hd, yl * 128, x * 128);
}

// ---------------- fused pyramid composition: Pc = compose(P, Hf) ----------------
__global__ void pyr_kernel(const u16* __restrict__ P, const u16* __restrict__ Hf,
                           u16* __restrict__ Pc) {
    int i = blockIdx.x * 256 + threadIdx.x;
    if (i >= NNi * 64) return;
    int node = i >> 6, c = (i & 63) * 4;
    size_t bi = (size_t)node * 256 + c;
    ushort4 pv = *(const ushort4*)(P + bi);
    ushort4 hv = *(const ushort4*)(Hf + bi);
    float v0 = b2f(pv.x) + b2f(hv.x);
    float v1 = b2f(pv.y) + b2f(hv.y);
    float v2 = b2f(pv.z) + b2f(hv.z);
    float v3 = b2f(pv.w) + b2f(hv.w);
    if (node < N3i) {
        int b = node / 6400, rem = node - b * 6400;
        int y = rem / 80, x = rem - y * 80;
        size_t s4 = ((size_t)N3i + b * 1600 + (y >> 1) * 40 + (x >> 1)) * 256 + c;
        size_t s5 = ((size_t)(N3i + N4i) + b * 400 + (y >> 2) * 20 + (x >> 2)) * 256 + c;
        ushort4 p4 = *(const ushort4*)(P + s4), h4 = *(const ushort4*)(Hf + s4);
        ushort4 p5 = *(const ushort4*)(P + s5), h5 = *(const ushort4*)(Hf + s5);
        v0 += b2f(p4.x) + b2f(h4.x) + b2f(p5.x) + b2f(h5.x);
        v1 += b2f(p4.y) + b2f(h4.y) + b2f(p5.y) + b2f(h5.y);
        v2 += b2f(p4.z) + b2f(h4.z) + b2f(p5.z) + b2f(h5.z);
        v3 += b2f(p4.w) + b2f(h4.w) + b2f(p5.w) + b2f(h5.w);
    } else if (node < N3i + N4i) {
        int n4 = node - N3i;
        int b = n4 / 1600, rem = n4 - b * 1600;
        int y = rem / 40, x = rem - y * 40;
        size_t s5 = ((size_t)(N3i + N4i) + b * 400 + (y >> 1) * 20 + (x >> 1)) * 256 + c;
        ushort4 p5 = *(const ushort4*)(P + s5), h5 = *(const ushort4*)(Hf + s5);
        v0 += b2f(p5.x) + b2f(h5.x);
        v1 += b2f(p5.y) + b2f(h5.y);
        v2 += b2f(p5.z) + b2f(h5.z);
        v3 += b2f(p5.w) + b2f(h5.w);
    }
    ushort4 o;
    o.x = f2b(v0); o.y = f2b(v1); o.z = f2b(v2); o.w = f2b(v3);
    *(ushort4*)(Pc + bi) = o;
}

// ---------------- host ----------------
extern "C" void kernel_launch(void* const* d_in, const int* in_sizes, int n_in,
                              void* d_out, int out_size, void* d_ws, size_t ws_size,
                              hipStream_t stream) {
    (void)in_sizes; (void)n_in; (void)out_size; (void)ws_size;
    const void* c3 = d_in[0];
    const void* c4 = d_in[1];
    const void* c5 = d_in[2];
    const void* w3_1 = d_in[3];
    const void* b3_1 = d_in[4];
    const void* w4_1 = d_in[5];
    const void* b4_1 = d_in[6];
    const void* w5_1 = d_in[7];
    const void* b5_1 = d_in[8];
    const void* w3_3 = d_in[9];
    const void* b3_3 = d_in[10];
    const void* w4_3 = d_in[11];
    const void* b4_3 = d_in[12];
    const void* w5_3 = d_in[13];
    const void* b5_3 = d_in[14];
    const void* Wc = d_in[15];
    const void* bc = d_in[16];
    const void* Wh = d_in[17];
    const void* bh = d_in[18];
    const int* src_c = (const int*)d_in[19];
    const int* dst_c = (const int*)d_in[20];
    const int* src_h = (const int*)d_in[21];
    const int* dst_h = (const int*)d_in[22];

    char* w = (char*)d_ws;
    auto alloc = [&](size_t bytes) -> void* {
        void* p = (void*)w;
        w += (bytes + 255) & ~(size_t)255;
        return p;
    };
    u16* XT  = (u16*)alloc(((size_t)N3i * 256 + (size_t)N4i * 512 + (size_t)N5i * 512) * 2);
    u16* Xt3 = XT;
    u16* Xt4 = XT + (size_t)N3i * 256;
    u16* Xt5 = Xt4 + (size_t)N4i * 512;
    u16* T   = XT;                          // alias (17.2 MB <= 21.3 MB region)
    u16* Pc  = XT;                          // pyramid output aliases T (free after GNN)
    u16* WtC = XT + (size_t)NNi * 256;      // alias, starts right after T (3.54 MB fits)
    u16* WtG = (u16*)alloc((size_t)9 * 65536 * 2);
    u16* W1  = (u16*)alloc((size_t)(65536 + 131072 + 131072) * 2);
    u16* BB  = (u16*)alloc((size_t)3840 * 2);
    u16* P   = (u16*)alloc((size_t)NNi * 256 * 2);
    u16* Ha  = (u16*)alloc((size_t)NNi * 256 * 2);
    u16* Hb  = (u16*)d_out;                 // alias d_out as scratch
    int* csr_c = (int*)alloc((size_t)ECi * 4);
    int* csr_h = (int*)alloc((size_t)EHi * 4);
    int* cnt2  = (int*)alloc((size_t)2 * NNi * 4);
    int* cnt_c = cnt2;
    int* cnt_h = cnt2 + NNi;
    int* rs_c  = (int*)alloc((size_t)(NNi + 1) * 4);
    int* rs_h  = (int*)alloc((size_t)(NNi + 1) * 4);
    int* cur_c = (int*)alloc((size_t)NNi * 4);
    int* cur_h = (int*)alloc((size_t)NNi * 4);
    float* inv_c = (float*)alloc((size_t)NNi * 4);
    float* inv_h = (float*)alloc((size_t)NNi * 4);
    int* ps_c  = (int*)alloc((size_t)NNi * 4);   // scan partials
    int* ps_h  = (int*)alloc((size_t)NNi * 4);
    int* bsum  = (int*)alloc((size_t)132 * 4);
    int* flag  = (int*)alloc(256);
    u16* zp    = (u16*)alloc(512);          // 512B zero row (GEMM mask + gather dead-loads)

    // ---- prep (zero cnt + dtype detect + zero-row) ----
    prep_kernel<<<(2 * NNi + 255) / 256, 256, 0, stream>>>(cnt2, 2 * NNi, c3, flag,
                                                           (uint32_t*)zp);

    // ---- CSR build (2-pass parallel scan) ----
    hist2_kernel<<<(ECi + EHi + 255) / 256, 256, 0, stream>>>(dst_c, dst_h, cnt_c, cnt_h);
    scan_part<<<132, 256, 0, stream>>>(cnt_c, cnt_h, ps_c, ps_h, bsum);
    scan_final<<<132, 256, 0, stream>>>(ps_c, ps_h, bsum, cnt_c, cnt_h,
                                        rs_c, cur_c, inv_c, rs_h, cur_h, inv_h);
    fill2_kernel<<<(ECi + EHi + 255) / 256, 256, 0, stream>>>(
        src_c, dst_c, cur_c, csr_c, src_h, dst_h, cur_h, csr_h);

    // ---- convert small tensors (one launch) ----
    CvtJobs cj;
    cj.src[0] = w3_1; cj.dst[0] = W1;          cj.n[0] = 65536;
    cj.src[1] = w4_1; cj.dst[1] = W1 + 65536;  cj.n[1] = 131072;
    cj.src[2] = w5_1; cj.dst[2] = W1 + 196608; cj.n[2] = 131072;
    cj.src[3] = b3_1; cj.dst[3] = BB;          cj.n[3] = 256;
    cj.src[4] = b4_1; cj.dst[4] = BB + 256;    cj.n[4] = 256;
    cj.src[5] = b5_1; cj.dst[5] = BB + 512;    cj.n[5] = 256;
    cj.src[6] = bc;   cj.dst[6] = BB + 768;    cj.n[6] = 1536;
    cj.src[7] = bh;   cj.dst[7] = BB + 2304;   cj.n[7] = 768;
    cj.src[8] = b3_3; cj.dst[8] = BB + 3072;   cj.n[8] = 256;
    cj.src[9] = b4_3; cj.dst[9] = BB + 3328;   cj.n[9] = 256;
    cj.src[10] = b5_3; cj.dst[10] = BB + 3584; cj.n[10] = 256;
    cvt_all_kernel<<<dim3(512, 11), 256, 0, stream>>>(cj, flag);

    // ---- input transposes + GNN weight transposes ----
    transpose_in3<<<dim3(263, 16, 4), dim3(32, 8), 0, stream>>>(c3, c4, c5, Xt3, Xt4, Xt5, flag);
    transpose_w<<<dim3(8, 8, 9), dim3(32, 8), 0, stream>>>(Wc, Wh, WtG, flag);

    // ---- lateral 1x1 convs -> P (and H0 = Ha), one launch ----
    lat_all_kernel<<<528, 256, 0, stream>>>(Xt3, Xt4, Xt5, W1, BB, zp, P, Ha);

    // ---- conv weights AFTER laterals (WtC aliases Xt4/Xt5 tail) ----
    convw3_kernel<<<dim3(2304, 3), 256, 0, stream>>>(w3_3, w4_3, w5_3, WtC, flag);

    // ---- 9 GNN layers ----
    u16* Hcur = Ha;
    u16* Hnxt = Hb;
    for (int l = 0; l < 9; l++) {
        bool ctx = (l < 3) || (l >= 6);
        const int* csr = ctx ? csr_c : csr_h;
        const int* rs = ctx ? rs_c : rs_h;
        const float* inv = ctx ? inv_c : inv_h;
        int ecap = ctx ? ECi : EHi;
        int wi = (l < 3) ? l : (l < 6 ? 6 + (l - 3) : l - 3);
        const u16* bias = (l < 3) ? BB + 768 + l * 256
                        : (l < 6 ? BB + 2304 + (l - 3) * 256 : BB + 768 + (l - 3) * 256);
        gather_kernel<<<NNi / 8, 256, 0, stream>>>(Hcur, csr, rs, inv, T, zp, ecap);
        gemm_kernel<false, true><<<528, 256, 0, stream>>>(
            T, 256, WtG + (size_t)wi * 65536, 256, bias, zp, Hnxt, nullptr, NNi, 256, 0, 0);
        u16* tmp = Hcur; Hcur = Hnxt; Hnxt = tmp;
    }
    u16* OutT = Hnxt;  // = Ha

    // ---- fused pyramid composition -> Pc ----
    pyr_kernel<<<(NNi * 64 + 255) / 256, 256, 0, stream>>>(P, Hcur, Pc);

    // ---- 3x3 convs (9-tap gathered GEMM), one launch ----
    conv_gemm_all<<<528, 256, 0, stream>>>(Pc, WtC, BB, zp, OutT);

    // ---- node-major -> NCHW output (one launch) ----
    transpose_out3<<<dim3(8, 263, 4), dim3(32, 8), 0, stream>>>(OutT, d_out, flag);
}